// Round 5
// baseline (331.954 us; speedup 1.0000x reference)
//
#include <hip/hip_runtime.h>
#include <math.h>

// N=768 atoms, T=256 tokens, CA=128, CP=16, CZ=128, CS=384, CT=384, H=4, DH=32
// d_out: a_out[256*384]@0, qout[768*384]@98304, c[768*128]@393216, pair[768*768*16]@491520

__device__ __forceinline__ float sigmoidf_(float v) { return 1.f / (1.f + __expf(-v)); }

// ---------------------------------------------------------------------------
// k_tokatoms: per token: SLN=LN(s); ctv = SLN@W_single (in reg). Then for the
// token's 3 atoms: c = c0+ctv; x = c0 + r@W_noisy; ca/cb = relu(c)@Wca/Wcb.
// grid 256, block 128
__global__ __launch_bounds__(128) void k_tokatoms(
    const float* __restrict__ s, const float* __restrict__ g,
    const float* __restrict__ b, const float* __restrict__ W_single,
    const float* __restrict__ ref_pos, const float* __restrict__ r,
    const float* __restrict__ W_pos, const float* __restrict__ W_noisy,
    const float* __restrict__ Wca, const float* __restrict__ Wcb,
    float* __restrict__ c_out, float* __restrict__ x,
    float* __restrict__ ca, float* __restrict__ cb) {
  int tok = blockIdx.x, t = threadIdx.x;
  __shared__ float sln[384];
  __shared__ float ws[48 * 128];
  __shared__ float red[4];
  __shared__ float rc[128];
  float v0 = s[tok * 384 + t], v1 = s[tok * 384 + 128 + t], v2 = s[tok * 384 + 256 + t];
  float ps = v0 + v1 + v2, pq = v0 * v0 + v1 * v1 + v2 * v2;
#pragma unroll
  for (int o = 1; o < 64; o <<= 1) { ps += __shfl_xor(ps, o); pq += __shfl_xor(pq, o); }
  if ((t & 63) == 0) { red[t >> 6] = ps; red[2 + (t >> 6)] = pq; }
  __syncthreads();
  float mean = (red[0] + red[1]) * (1.f / 384.f);
  float var = (red[2] + red[3]) * (1.f / 384.f) - mean * mean;
  float rstd = rsqrtf(var + 1e-5f);
  sln[t] = (v0 - mean) * rstd * g[t] + b[t];
  sln[128 + t] = (v1 - mean) * rstd * g[128 + t] + b[128 + t];
  sln[256 + t] = (v2 - mean) * rstd * g[256 + t] + b[256 + t];
  float ctv = 0.f;
  for (int c0 = 0; c0 < 384; c0 += 48) {
    __syncthreads();
#pragma unroll
    for (int m = 0; m < 12; m++) {
      int idx = (t + 128 * m) * 4;
      *(float4*)&ws[idx] = *(const float4*)&W_single[c0 * 128 + idx];
    }
    __syncthreads();
#pragma unroll 8
    for (int kk = 0; kk < 48; kk++) ctv += sln[c0 + kk] * ws[kk * 128 + t];
  }
  float wp0 = W_pos[t], wp1 = W_pos[128 + t], wp2 = W_pos[256 + t];
  float wn0 = W_noisy[t], wn1 = W_noisy[128 + t], wn2 = W_noisy[256 + t];
#pragma unroll
  for (int a = 0; a < 3; a++) {
    int i = tok + 256 * a;
    float p0 = ref_pos[i * 3], p1 = ref_pos[i * 3 + 1], p2 = ref_pos[i * 3 + 2];
    float r0 = r[i * 3], r1 = r[i * 3 + 1], r2 = r[i * 3 + 2];
    float c0 = p0 * wp0 + p1 * wp1 + p2 * wp2;
    x[i * 128 + t] = c0 + r0 * wn0 + r1 * wn1 + r2 * wn2;
    float cc = c0 + ctv;
    c_out[i * 128 + t] = cc;
    __syncthreads();
    rc[t] = fmaxf(cc, 0.f);
    __syncthreads();
    int out_id = t >> 2, q = t & 3;
    const float* Wm = (out_id < 16) ? Wca : Wcb;
    int ch = out_id & 15;
    float acc = 0.f;
#pragma unroll
    for (int kk = 0; kk < 32; kk++) { int k = q * 32 + kk; acc += rc[k] * Wm[k * 16 + ch]; }
    acc += __shfl_xor(acc, 1);
    acc += __shfl_xor(acc, 2);
    if (q == 0) { if (out_id < 16) ca[i * 16 + ch] = acc; else cb[i * 16 + ch] = acc; }
  }
}

// ---------------------------------------------------------------------------
// k_zp: zp[65536,16] = LN(z)@W_pair   grid 4096, block 256
__global__ __launch_bounds__(256) void k_zp(
    const float* __restrict__ z, const float* __restrict__ g,
    const float* __restrict__ lb, const float* __restrict__ W_pair,
    float* __restrict__ zp) {
  __shared__ float wT[16][132];
  __shared__ float zs[16][132];
  __shared__ float sWg[16], Bc[16];
  int t = threadIdx.x;
#pragma unroll
  for (int m = 0; m < 8; m++) {
    int e = t + 256 * m;
    int row = e >> 4, ch = e & 15;
    wT[ch][row] = g[row] * W_pair[e];
  }
  __syncthreads();
  if (t < 32) {
    int ch = t & 15;
    float a = 0.f;
    if (t < 16) {
#pragma unroll 8
      for (int k = 0; k < 128; k++) a += wT[ch][k];
      sWg[ch] = a;
    } else {
#pragma unroll 8
      for (int k = 0; k < 128; k++) a += lb[k] * W_pair[k * 16 + ch];
      Bc[ch] = a;
    }
  }
  int row = t >> 4, kk = (t & 15) * 8;
  long base = ((long)blockIdx.x * 16 + row) * 128 + kk;
  float4 a4 = *(const float4*)&z[base];
  float4 b4 = *(const float4*)&z[base + 4];
  *(float4*)&zs[row][kk] = a4;
  *(float4*)&zs[row][kk + 4] = b4;
  float ps = a4.x + a4.y + a4.z + a4.w + b4.x + b4.y + b4.z + b4.w;
  float pq = a4.x * a4.x + a4.y * a4.y + a4.z * a4.z + a4.w * a4.w +
             b4.x * b4.x + b4.y * b4.y + b4.z * b4.z + b4.w * b4.w;
#pragma unroll
  for (int o = 1; o < 16; o <<= 1) { ps += __shfl_xor(ps, o); pq += __shfl_xor(pq, o); }
  float m = ps * (1.f / 128.f);
  float rstd = rsqrtf(pq * (1.f / 128.f) - m * m + 1e-5f);
  __syncthreads();
  int ch = t & 15;
  float dotv = 0.f;
#pragma unroll 8
  for (int k4 = 0; k4 < 32; k4++) {
    float4 zv = *(float4*)&zs[row][k4 * 4];
    float4 wv = *(float4*)&wT[ch][k4 * 4];
    dotv += zv.x * wv.x + zv.y * wv.y + zv.z * wv.z + zv.w * wv.w;
  }
  zp[((long)blockIdx.x * 16 + row) * 16 + ch] = rstd * (dotv - m * sWg[ch]) + Bc[ch];
}

// ---------------------------------------------------------------------------
// k_pair2: 2 rows (i0, i0+1) per block; MLP weight LDS reads amortized 2x.
// grid 1152 (ip*3+jb), block 256 (one j each)
__global__ __launch_bounds__(256) void k_pair2(
    const float* __restrict__ ref_pos, const int* __restrict__ uid,
    const float* __restrict__ Wpo, const float* __restrict__ Wisd,
    const float* __restrict__ Wmask, const float* __restrict__ W1,
    const float* __restrict__ W2, const float* __restrict__ W3,
    const float* __restrict__ zp, const float* __restrict__ ca,
    const float* __restrict__ cb, const float* __restrict__ lnp_g,
    const float* __restrict__ lnp_b, const float* __restrict__ Wb,
    float* __restrict__ pair_out, float* __restrict__ biasA) {
  int ip = blockIdx.x / 3, jb = blockIdx.x % 3, t = threadIdx.x;
  int i0 = ip * 2;
  int j = jb * 256 + t;
  __shared__ float w1s[256], w2s[256], w3s[256];
  __shared__ float wpo[48], wisd[16], wmask[16], cai[32];
  __shared__ float wgb[192];  // [b][k][h]
  __shared__ float kbs[12];   // [b][h]
  w1s[t] = W1[t]; w2s[t] = W2[t]; w3s[t] = W3[t];
  if (t < 48) wpo[t] = Wpo[t];
  if (t < 16) { wisd[t] = Wisd[t]; wmask[t] = Wmask[t]; }
  if (t >= 192 && t < 224) { int e = t - 192; cai[e] = ca[(i0 + (e >> 4)) * 16 + (e & 15)]; }
  if (t >= 64) {
    int e = t - 64;
    if (e < 192) {
      int bq = e >> 6, k = (e >> 2) & 15, h = e & 3;
      wgb[e] = lnp_g[bq * 16 + k] * Wb[bq * 64 + k * 4 + h];
    }
  }
  if (t >= 48 && t < 60) {
    int e = t - 48, bq = e >> 2, h = e & 3;
    float a = 0.f;
#pragma unroll
    for (int c = 0; c < 16; c++) a += lnp_b[bq * 16 + c] * Wb[bq * 64 + c * 4 + h];
    kbs[e] = a;
  }
  __syncthreads();
  float pj0 = ref_pos[j * 3], pj1 = ref_pos[j * 3 + 1], pj2 = ref_pos[j * 3 + 2];
  int uj = uid[j];
  float dA0 = ref_pos[i0 * 3] - pj0;
  float dA1 = ref_pos[i0 * 3 + 1] - pj1;
  float dA2 = ref_pos[i0 * 3 + 2] - pj2;
  float dB0 = ref_pos[i0 * 3 + 3] - pj0;
  float dB1 = ref_pos[i0 * 3 + 4] - pj1;
  float dB2 = ref_pos[i0 * 3 + 5] - pj2;
  float mA = (uid[i0] == uj) ? 1.f : 0.f;
  float mB = (uid[i0 + 1] == uj) ? 1.f : 0.f;
  float ivA = 1.f / (1.f + dA0 * dA0 + dA1 * dA1 + dA2 * dA2);
  float ivB = 1.f / (1.f + dB0 * dB0 + dB1 * dB1 + dB2 * dB2);
  // zp is [256][256][16]; column index is j mod 256 == t
  const float4* zpA = (const float4*)&zp[((long)((i0 & 255) << 8) + t) * 16];
  const float4* zpB = (const float4*)&zp[((long)(((i0 + 1) & 255) << 8) + t) * 16];
  const float4* cbv = (const float4*)&cb[j * 16];
  float pA[16], pB[16];
#pragma unroll
  for (int q = 0; q < 4; q++) {
    float4 bv = cbv[q];
    float4 zA = zpA[q], zB = zpB[q];
    float4 w0 = *(float4*)&wpo[q * 4];
    float4 w1 = *(float4*)&wpo[16 + q * 4];
    float4 w2 = *(float4*)&wpo[32 + q * 4];
    float4 wi = *(float4*)&wisd[q * 4];
    float4 wm = *(float4*)&wmask[q * 4];
    float4 cA = *(float4*)&cai[q * 4];
    float4 cB = *(float4*)&cai[16 + q * 4];
    pA[q * 4 + 0] = mA * (dA0 * w0.x + dA1 * w1.x + dA2 * w2.x + ivA * wi.x + wm.x) + zA.x + bv.x + cA.x;
    pA[q * 4 + 1] = mA * (dA0 * w0.y + dA1 * w1.y + dA2 * w2.y + ivA * wi.y + wm.y) + zA.y + bv.y + cA.y;
    pA[q * 4 + 2] = mA * (dA0 * w0.z + dA1 * w1.z + dA2 * w2.z + ivA * wi.z + wm.z) + zA.z + bv.z + cA.z;
    pA[q * 4 + 3] = mA * (dA0 * w0.w + dA1 * w1.w + dA2 * w2.w + ivA * wi.w + wm.w) + zA.w + bv.w + cA.w;
    pB[q * 4 + 0] = mB * (dB0 * w0.x + dB1 * w1.x + dB2 * w2.x + ivB * wi.x + wm.x) + zB.x + bv.x + cB.x;
    pB[q * 4 + 1] = mB * (dB0 * w0.y + dB1 * w1.y + dB2 * w2.y + ivB * wi.y + wm.y) + zB.y + bv.y + cB.y;
    pB[q * 4 + 2] = mB * (dB0 * w0.z + dB1 * w1.z + dB2 * w2.z + ivB * wi.z + wm.z) + zB.z + bv.z + cB.z;
    pB[q * 4 + 3] = mB * (dB0 * w0.w + dB1 * w1.w + dB2 * w2.w + ivB * wi.w + wm.w) + zB.w + bv.w + cB.w;
  }
  float cA_[16], cB_[16], nA_[16], nB_[16];
#pragma unroll
  for (int c = 0; c < 16; c++) {
    cA_[c] = fmaxf(pA[c], 0.f); cB_[c] = fmaxf(pB[c], 0.f);
    nA_[c] = 0.f; nB_[c] = 0.f;
  }
#pragma unroll
  for (int k = 0; k < 16; k++) {
    float tA = cA_[k], tB = cB_[k];
#pragma unroll
    for (int q = 0; q < 4; q++) {
      float4 w = *(float4*)&w1s[k * 16 + q * 4];
      nA_[q * 4 + 0] += tA * w.x; nA_[q * 4 + 1] += tA * w.y;
      nA_[q * 4 + 2] += tA * w.z; nA_[q * 4 + 3] += tA * w.w;
      nB_[q * 4 + 0] += tB * w.x; nB_[q * 4 + 1] += tB * w.y;
      nB_[q * 4 + 2] += tB * w.z; nB_[q * 4 + 3] += tB * w.w;
    }
  }
#pragma unroll
  for (int c = 0; c < 16; c++) {
    cA_[c] = fmaxf(nA_[c], 0.f); cB_[c] = fmaxf(nB_[c], 0.f);
    nA_[c] = 0.f; nB_[c] = 0.f;
  }
#pragma unroll
  for (int k = 0; k < 16; k++) {
    float tA = cA_[k], tB = cB_[k];
#pragma unroll
    for (int q = 0; q < 4; q++) {
      float4 w = *(float4*)&w2s[k * 16 + q * 4];
      nA_[q * 4 + 0] += tA * w.x; nA_[q * 4 + 1] += tA * w.y;
      nA_[q * 4 + 2] += tA * w.z; nA_[q * 4 + 3] += tA * w.w;
      nB_[q * 4 + 0] += tB * w.x; nB_[q * 4 + 1] += tB * w.y;
      nB_[q * 4 + 2] += tB * w.z; nB_[q * 4 + 3] += tB * w.w;
    }
  }
#pragma unroll
  for (int c = 0; c < 16; c++) {
    cA_[c] = fmaxf(nA_[c], 0.f); cB_[c] = fmaxf(nB_[c], 0.f);
    nA_[c] = pA[c]; nB_[c] = pB[c];
  }
#pragma unroll
  for (int k = 0; k < 16; k++) {
    float tA = cA_[k], tB = cB_[k];
#pragma unroll
    for (int q = 0; q < 4; q++) {
      float4 w = *(float4*)&w3s[k * 16 + q * 4];
      nA_[q * 4 + 0] += tA * w.x; nA_[q * 4 + 1] += tA * w.y;
      nA_[q * 4 + 2] += tA * w.z; nA_[q * 4 + 3] += tA * w.w;
      nB_[q * 4 + 0] += tB * w.x; nB_[q * 4 + 1] += tB * w.y;
      nB_[q * 4 + 2] += tB * w.z; nB_[q * 4 + 3] += tB * w.w;
    }
  }
  long poA = ((long)i0 * 768 + j) * 16;
  long poB = poA + 768 * 16;
  *(float4*)&pair_out[poA]      = make_float4(nA_[0], nA_[1], nA_[2], nA_[3]);
  *(float4*)&pair_out[poA + 4]  = make_float4(nA_[4], nA_[5], nA_[6], nA_[7]);
  *(float4*)&pair_out[poA + 8]  = make_float4(nA_[8], nA_[9], nA_[10], nA_[11]);
  *(float4*)&pair_out[poA + 12] = make_float4(nA_[12], nA_[13], nA_[14], nA_[15]);
  *(float4*)&pair_out[poB]      = make_float4(nB_[0], nB_[1], nB_[2], nB_[3]);
  *(float4*)&pair_out[poB + 4]  = make_float4(nB_[4], nB_[5], nB_[6], nB_[7]);
  *(float4*)&pair_out[poB + 8]  = make_float4(nB_[8], nB_[9], nB_[10], nB_[11]);
  *(float4*)&pair_out[poB + 12] = make_float4(nB_[12], nB_[13], nB_[14], nB_[15]);
  int qb = i0 >> 5;
  int jw = j - (qb * 32 - 48);
  if ((unsigned)jw < 128u) {
    // row A
    {
      float m = 0.f;
#pragma unroll
      for (int c = 0; c < 16; c++) m += nA_[c];
      m *= (1.f / 16.f);
      float vv = 0.f;
#pragma unroll
      for (int c = 0; c < 16; c++) { float d = nA_[c] - m; vv += d * d; }
      float rs = rsqrtf(vv * (1.f / 16.f) + 1e-5f);
#pragma unroll
      for (int c = 0; c < 16; c++) cA_[c] = (nA_[c] - m) * rs;
      int qi = i0 & 31;
#pragma unroll
      for (int bq = 0; bq < 3; bq++) {
        float o0 = kbs[bq * 4 + 0], o1 = kbs[bq * 4 + 1];
        float o2 = kbs[bq * 4 + 2], o3 = kbs[bq * 4 + 3];
#pragma unroll
        for (int k = 0; k < 16; k++) {
          float nv = cA_[k];
          float4 w = *(float4*)&wgb[bq * 64 + k * 4];
          o0 += nv * w.x; o1 += nv * w.y; o2 += nv * w.z; o3 += nv * w.w;
        }
        long base = (long)(bq * 96 + qb * 4) * 4096 + (long)qi * 128 + jw;
        biasA[base] = o0;
        biasA[base + 4096] = o1;
        biasA[base + 2 * 4096] = o2;
        biasA[base + 3 * 4096] = o3;
      }
    }
    // row B
    {
      float m = 0.f;
#pragma unroll
      for (int c = 0; c < 16; c++) m += nB_[c];
      m *= (1.f / 16.f);
      float vv = 0.f;
#pragma unroll
      for (int c = 0; c < 16; c++) { float d = nB_[c] - m; vv += d * d; }
      float rs = rsqrtf(vv * (1.f / 16.f) + 1e-5f);
#pragma unroll
      for (int c = 0; c < 16; c++) cB_[c] = (nB_[c] - m) * rs;
      int qi = (i0 & 31) + 1;
#pragma unroll
      for (int bq = 0; bq < 3; bq++) {
        float o0 = kbs[bq * 4 + 0], o1 = kbs[bq * 4 + 1];
        float o2 = kbs[bq * 4 + 2], o3 = kbs[bq * 4 + 3];
#pragma unroll
        for (int k = 0; k < 16; k++) {
          float nv = cB_[k];
          float4 w = *(float4*)&wgb[bq * 64 + k * 4];
          o0 += nv * w.x; o1 += nv * w.y; o2 += nv * w.z; o3 += nv * w.w;
        }
        long base = (long)(bq * 96 + qb * 4) * 4096 + (long)qi * 128 + jw;
        biasA[base] = o0;
        biasA[base + 4096] = o1;
        biasA[base + 2 * 4096] = o2;
        biasA[base + 3 * 4096] = o3;
      }
    }
  }
}

// ---------------------------------------------------------------------------
// k_qa: fused LN + QKVG + windowed attention per (qb,h).  grid 96, block 512
__global__ __launch_bounds__(512) void k_qa(
    const float* __restrict__ x, const float* __restrict__ lng,
    const float* __restrict__ lnb, const float* __restrict__ Wq,
    const float* __restrict__ Wk, const float* __restrict__ Wv,
    const float* __restrict__ Wg, const float* __restrict__ biasb,
    float* __restrict__ og) {
  int bid = blockIdx.x;
  int qb = bid >> 2, h = bid & 3;
  int i0 = qb * 32, lo = i0 - 48, hd0 = h * 32;
  int t = threadIdx.x;
  __shared__ float b1[128][36];  // wk -> ks
  __shared__ float b2[128][36];  // wv -> vs
  __shared__ float qaL[4224];    // QA[32][132] -> L[32][132]
  __shared__ float qs[32][36];
  __shared__ float gs[32][36];
  int rr = t >> 2, q4 = t & 3;
  int j = lo + rr;
  bool jv = (j >= 0 && j < 768);
  // Phase A: load x row segment, LN, keep in regs; stash q-rows to QA
  float4 av4[8];
  {
    const float4* xr = (const float4*)&x[(long)(jv ? j : 0) * 128 + q4 * 32];
#pragma unroll
    for (int m = 0; m < 8; m++) av4[m] = jv ? xr[m] : make_float4(0.f, 0.f, 0.f, 0.f);
    float ps = 0.f, pq = 0.f;
#pragma unroll
    for (int m = 0; m < 8; m++) {
      ps += av4[m].x + av4[m].y + av4[m].z + av4[m].w;
      pq += av4[m].x * av4[m].x + av4[m].y * av4[m].y + av4[m].z * av4[m].z + av4[m].w * av4[m].w;
    }
    ps += __shfl_xor(ps, 1); ps += __shfl_xor(ps, 2);
    pq += __shfl_xor(pq, 1); pq += __shfl_xor(pq, 2);
    float mn = ps * (1.f / 128.f);
    float rs = rsqrtf(pq * (1.f / 128.f) - mn * mn + 1e-5f);
#pragma unroll
    for (int m = 0; m < 8; m++) {
      int c = q4 * 32 + m * 4;
      float4 g4 = *(const float4*)&lng[c];
      float4 b4 = *(const float4*)&lnb[c];
      float4 a;
      a.x = jv ? (av4[m].x - mn) * rs * g4.x + b4.x : 0.f;
      a.y = jv ? (av4[m].y - mn) * rs * g4.y + b4.y : 0.f;
      a.z = jv ? (av4[m].z - mn) * rs * g4.z + b4.z : 0.f;
      a.w = jv ? (av4[m].w - mn) * rs * g4.w + b4.w : 0.f;
      av4[m] = a;
      if (rr >= 48 && rr < 80) *(float4*)&qaL[(rr - 48) * 132 + c] = a;
    }
  }
  // Phase A2: stage Wk/Wv head slices
  {
    int cw = t >> 2, d8 = (t & 3) * 8;
    *(float4*)&b1[cw][d8]     = *(const float4*)&Wk[cw * 128 + hd0 + d8];
    *(float4*)&b1[cw][d8 + 4] = *(const float4*)&Wk[cw * 128 + hd0 + d8 + 4];
    *(float4*)&b2[cw][d8]     = *(const float4*)&Wv[cw * 128 + hd0 + d8];
    *(float4*)&b2[cw][d8 + 4] = *(const float4*)&Wv[cw * 128 + hd0 + d8 + 4];
  }
  __syncthreads();
  // Phase B: K/V partial GEMM in regs + 4-lane reduce
  float k8[8], v8[8];
  {
    float kp[32];
#pragma unroll
    for (int d = 0; d < 32; d++) kp[d] = 0.f;
#pragma unroll
    for (int mm = 0; mm < 8; mm++) {
#pragma unroll
      for (int e = 0; e < 4; e++) {
        float a = (e == 0) ? av4[mm].x : (e == 1) ? av4[mm].y : (e == 2) ? av4[mm].z : av4[mm].w;
        int row = q4 * 32 + mm * 4 + e;
#pragma unroll
        for (int d4 = 0; d4 < 8; d4++) {
          float4 w = *(float4*)&b1[row][d4 * 4];
          kp[d4 * 4 + 0] += a * w.x; kp[d4 * 4 + 1] += a * w.y;
          kp[d4 * 4 + 2] += a * w.z; kp[d4 * 4 + 3] += a * w.w;
        }
      }
    }
#pragma unroll
    for (int d = 0; d < 32; d++) { kp[d] += __shfl_xor(kp[d], 1); kp[d] += __shfl_xor(kp[d], 2); }
#pragma unroll
    for (int e = 0; e < 8; e++)
      k8[e] = (q4 == 0) ? kp[e] : (q4 == 1) ? kp[8 + e] : (q4 == 2) ? kp[16 + e] : kp[24 + e];
#pragma unroll
    for (int d = 0; d < 32; d++) kp[d] = 0.f;
#pragma unroll
    for (int mm = 0; mm < 8; mm++) {
#pragma unroll
      for (int e = 0; e < 4; e++) {
        float a = (e == 0) ? av4[mm].x : (e == 1) ? av4[mm].y : (e == 2) ? av4[mm].z : av4[mm].w;
        int row = q4 * 32 + mm * 4 + e;
#pragma unroll
        for (int d4 = 0; d4 < 8; d4++) {
          float4 w = *(float4*)&b2[row][d4 * 4];
          kp[d4 * 4 + 0] += a * w.x; kp[d4 * 4 + 1] += a * w.y;
          kp[d4 * 4 + 2] += a * w.z; kp[d4 * 4 + 3] += a * w.w;
        }
      }
    }
#pragma unroll
    for (int d = 0; d < 32; d++) { kp[d] += __shfl_xor(kp[d], 1); kp[d] += __shfl_xor(kp[d], 2); }
#pragma unroll
    for (int e = 0; e < 8; e++)
      v8[e] = (q4 == 0) ? kp[e] : (q4 == 1) ? kp[8 + e] : (q4 == 2) ? kp[16 + e] : kp[24 + e];
  }
  __syncthreads();
  // Phase C: stage Wq/Wg into b1/b2
  {
    int cw = t >> 2, d8 = (t & 3) * 8;
    *(float4*)&b1[cw][d8]     = *(const float4*)&Wq[cw * 128 + hd0 + d8];
    *(float4*)&b1[cw][d8 + 4] = *(const float4*)&Wq[cw * 128 + hd0 + d8 + 4];
    *(float4*)&b2[cw][d8]     = *(const float4*)&Wg[cw * 128 + hd0 + d8];
    *(float4*)&b2[cw][d8 + 4] = *(const float4*)&Wg[cw * 128 + hd0 + d8 + 4];
  }
  __syncthreads();
  // Phase D: Q and G GEMM from QA
  {
    int qi = t >> 4, sel = (t >> 3) & 1, d4 = (t & 7) * 4;
    const float* wbuf = sel ? &b2[0][0] : &b1[0][0];
    float4 acc = {0.f, 0.f, 0.f, 0.f};
    for (int c = 0; c < 128; c++) {
      float a = qaL[qi * 132 + c];
      float4 w = *(const float4*)&wbuf[c * 36 + d4];
      acc.x += a * w.x; acc.y += a * w.y; acc.z += a * w.z; acc.w += a * w.w;
    }
    if (sel) *(float4*)&gs[qi][d4] = acc; else *(float4*)&qs[qi][d4] = acc;
  }
  __syncthreads();
  // Phase E: write ks/vs into b1/b2; load bias into L
  {
    *(float4*)&b1[rr][q4 * 8]     = make_float4(k8[0], k8[1], k8[2], k8[3]);
    *(float4*)&b1[rr][q4 * 8 + 4] = make_float4(k8[4], k8[5], k8[6], k8[7]);
    *(float4*)&b2[rr][q4 * 8]     = make_float4(v8[0], v8[1], v8[2], v8[3]);
    *(float4*)&b2[rr][q4 * 8 + 4] = make_float4(v8[4], v8[5], v8[6], v8[7]);
    int qi = t >> 4, k8b = (t & 15) * 8;
#pragma unroll
    for (int mm = 0; mm < 2; mm++) {
      int k4 = k8b + mm * 4;
      int j4 = lo + k4;
      float4 bv;
      if (j4 >= 0 && j4 <= 764)
        bv = *(const float4*)&biasb[(long)(qb * 4 + h) * 4096 + qi * 128 + k4];
      else
        bv = make_float4(-1e30f, -1e30f, -1e30f, -1e30f);
      *(float4*)&qaL[qi * 132 + k4] = bv;
    }
  }
  __syncthreads();
  // Phase F: QK^T
  {
    const float scale = 0.17677669529663687f;
    int qi = t & 31, kb = t >> 5;
    float4 qr[8];
#pragma unroll
    for (int d4 = 0; d4 < 8; d4++) qr[d4] = *(float4*)&qs[qi][d4 * 4];
#pragma unroll
    for (int kk = 0; kk < 8; kk++) {
      int kj = kb * 8 + kk;
      float acc = 0.f;
#pragma unroll
      for (int d4 = 0; d4 < 8; d4++) {
        float4 kv = *(float4*)&b1[kj][d4 * 4];
        acc += qr[d4].x * kv.x + qr[d4].y * kv.y + qr[d4].z * kv.z + qr[d4].w * kv.w;
      }
      qaL[qi * 132 + kj] += acc * scale;
    }
  }
  __syncthreads();
  // Phase G: softmax (16 threads per row)
  float rden;
  int sqi = t >> 4;
  {
    int sg = t & 15;
    float mx = -1e30f;
#pragma unroll
    for (int k2 = 0; k2 < 8; k2++) mx = fmaxf(mx, qaL[sqi * 132 + sg * 8 + k2]);
#pragma unroll
    for (int o = 1; o < 16; o <<= 1) mx = fmaxf(mx, __shfl_xor(mx, o));
    float sum = 0.f;
#pragma unroll
    for (int k2 = 0; k2 < 8; k2++) {
      int kj = sg * 8 + k2;
      float e = __expf(qaL[sqi * 132 + kj] - mx);
      qaL[sqi * 132 + kj] = e;
      sum += e;
    }
#pragma unroll
    for (int o = 1; o < 16; o <<= 1) sum += __shfl_xor(sum, o);
    rden = 1.f / sum;
  }
  __syncthreads();
  // Phase H: PV + gate
  {
    int d2 = (t & 15) * 2;
    float a0 = 0.f, a1 = 0.f;
#pragma unroll 8
    for (int kj = 0; kj < 128; kj++) {
      float p = qaL[sqi * 132 + kj];
      float2 v = *(float2*)&b2[kj][d2];
      a0 += p * v.x; a1 += p * v.y;
    }
    float2 g2 = *(float2*)&gs[sqi][d2];
    float2 o2;
    o2.x = a0 * rden * sigmoidf_(g2.x);
    o2.y = a1 * rden * sigmoidf_(g2.y);
    *(float2*)&og[(long)(i0 + sqi) * 128 + hd0 + d2] = o2;
  }
}

// ---------------------------------------------------------------------------
// k_fused: x += og@Wo; t=LN(x); x += relu(t@Wt1)@Wt2.  grid 192 (4 rows), block 256
__global__ __launch_bounds__(256) void k_fused(
    const float* __restrict__ og, const float* __restrict__ Wo,
    const float* __restrict__ g2, const float* __restrict__ b2,
    const float* __restrict__ Wt1, const float* __restrict__ Wt2,
    float* __restrict__ x) {
  int t = threadIdx.x;
  int r0 = blockIdx.x * 4;
  __shared__ float os[4][132];
  __shared__ float xn[4][132];
  __shared__ float a4s[4][132];
  __shared__ float hbf[4][516];
  __shared__ float wc[8192];
  if (t < 128) {
    int rr = t >> 5, c4 = (t & 31) * 4;
    *(float4*)&os[rr][c4] = *(const float4*)&og[(r0 + rr) * 128 + c4];
    *(float4*)&xn[rr][c4] = *(const float4*)&x[(r0 + rr) * 128 + c4];
  }
  int c = t & 127, rh = t >> 7;
  float ac[2] = {0.f, 0.f};
  for (int k0 = 0; k0 < 128; k0 += 64) {
    __syncthreads();
#pragma unroll
    for (int m = 0; m < 8; m++) {
      int idx = (t + 256 * m) * 4;
      *(float4*)&wc[idx] = *(const float4*)&Wo[k0 * 128 + idx];
    }
    __syncthreads();
#pragma unroll 8
    for (int kk = 0; kk < 64; kk++) {
      float w = wc[kk * 128 + c];
      int k = k0 + kk;
      ac[0] += os[rh * 2 + 0][k] * w;
      ac[1] += os[rh * 2 + 1][k] * w;
    }
  }
  __syncthreads();
  xn[rh * 2 + 0][c] += ac[0];
  xn[rh * 2 + 1][c] += ac[1];
  __syncthreads();
  if (t < 128) {
    int rr = t >> 5, tt = t & 31;
    float4 xv = *(float4*)&xn[rr][tt * 4];
    float ps = xv.x + xv.y + xv.z + xv.w;
    float pq = xv.x * xv.x + xv.y * xv.y + xv.z * xv.z + xv.w * xv.w;
#pragma unroll
    for (int o = 1; o < 32; o <<= 1) { ps += __shfl_xor(ps, o); pq += __shfl_xor(pq, o); }
    float m = ps * (1.f / 128.f);
    float rstd = rsqrtf(pq * (1.f / 128.f) - m * m + 1e-5f);
    float4 gg = *(const float4*)&g2[tt * 4];
    float4 bb = *(const float4*)&b2[tt * 4];
    float4 av;
    av.x = (xv.x - m) * rstd * gg.x + bb.x;
    av.y = (xv.y - m) * rstd * gg.y + bb.y;
    av.z = (xv.z - m) * rstd * gg.z + bb.z;
    av.w = (xv.w - m) * rstd * gg.w + bb.w;
    *(float4*)&a4s[rr][tt * 4] = av;
  }
  int rr1 = t >> 6, c8 = (t & 63) * 8;
  float acc8[8];
#pragma unroll
  for (int e = 0; e < 8; e++) acc8[e] = 0.f;
  for (int k0 = 0; k0 < 128; k0 += 16) {
    __syncthreads();
#pragma unroll
    for (int m = 0; m < 8; m++) {
      int idx = (t + 256 * m) * 4;
      *(float4*)&wc[idx] = *(const float4*)&Wt1[k0 * 512 + idx];
    }
    __syncthreads();
#pragma unroll 4
    for (int kk = 0; kk < 16; kk++) {
      float av = a4s[rr1][k0 + kk];
      float4 w0 = *(float4*)&wc[kk * 512 + c8];
      float4 w1 = *(float4*)&wc[kk * 512 + c8 + 4];
      acc8[0] += av * w0.x; acc8[1] += av * w0.y; acc8[2] += av * w0.z; acc8[3] += av * w0.w;
      acc8[4] += av * w1.x; acc8[5] += av * w1.y; acc8[6] += av * w1.z; acc8[7] += av * w1.w;
    }
  }
  __syncthreads();
  *(float4*)&hbf[rr1][c8]     = make_float4(fmaxf(acc8[0], 0.f), fmaxf(acc8[1], 0.f),
                                            fmaxf(acc8[2], 0.f), fmaxf(acc8[3], 0.f));
  *(float4*)&hbf[rr1][c8 + 4] = make_float4(fmaxf(acc8[4], 0.f), fmaxf(acc8[5], 0.f),
                                            fmaxf(acc8[6], 0.f), fmaxf(acc8[7], 0.f));
  float ac2[2] = {0.f, 0.f};
  for (int k0 = 0; k0 < 512; k0 += 64) {
    __syncthreads();
#pragma unroll
    for (int m = 0; m < 8; m++) {
      int idx = (t + 256 * m) * 4;
      *(float4*)&wc[idx] = *(const float4*)&Wt2[k0 * 128 + idx];
    }
    __syncthreads();
#pragma unroll 8
    for (int kk = 0; kk < 64; kk++) {
      float w = wc[kk * 128 + c];
      int k = k0 + kk;
      ac2[0] += hbf[rh * 2 + 0][k] * w;
      ac2[1] += hbf[rh * 2 + 1][k] * w;
    }
  }
  x[(r0 + rh * 2 + 0) * 128 + c] = xn[rh * 2 + 0][c] + ac2[0];
  x[(r0 + rh * 2 + 1) * 128 + c] = xn[rh * 2 + 1][c] + ac2[1];
}

// ---------------------------------------------------------------------------
// k_final: qout = relu(x@W_proj); a_out = mean over 3 atoms  grid 256, block 384
__global__ __launch_bounds__(384) void k_final(
    const float* __restrict__ x, const float* __restrict__ W_proj,
    float* __restrict__ out) {
  __shared__ float xs[384];
  int tk = blockIdx.x, t = threadIdx.x;
  xs[t] = x[tk * 384 + t];
  __syncthreads();
  float a0 = 0, a1 = 0, a2 = 0;
#pragma unroll 8
  for (int k = 0; k < 128; k++) {
    float w = W_proj[k * 384 + t];
    a0 += xs[k] * w; a1 += xs[128 + k] * w; a2 += xs[256 + k] * w;
  }
  a0 = fmaxf(a0, 0.f); a1 = fmaxf(a1, 0.f); a2 = fmaxf(a2, 0.f);
  out[98304 + (tk * 3 + 0) * 384 + t] = a0;
  out[98304 + (tk * 3 + 1) * 384 + t] = a1;
  out[98304 + (tk * 3 + 2) * 384 + t] = a2;
  out[tk * 384 + t] = (a0 + a1 + a2) * (1.f / 3.f);
}

// ---------------------------------------------------------------------------
extern "C" void kernel_launch(void* const* d_in, const int* in_sizes, int n_in,
                              void* d_out, int out_size, void* d_ws, size_t ws_size,
                              hipStream_t stream) {
  const float* ref_pos  = (const float*)d_in[0];
  const int*   uid      = (const int*)d_in[1];
  const float* r        = (const float*)d_in[2];
  const float* s        = (const float*)d_in[3];
  const float* z        = (const float*)d_in[4];
  const float* W_pos    = (const float*)d_in[5];
  const float* Wpo      = (const float*)d_in[6];
  const float* Wisd     = (const float*)d_in[7];
  const float* Wmask    = (const float*)d_in[8];
  const float* Wca      = (const float*)d_in[9];
  const float* Wcb      = (const float*)d_in[10];
  const float* ln_s_g   = (const float*)d_in[11];
  const float* ln_s_b   = (const float*)d_in[12];
  const float* W_single = (const float*)d_in[13];
  const float* ln_z_g   = (const float*)d_in[14];
  const float* ln_z_b   = (const float*)d_in[15];
  const float* W_pair   = (const float*)d_in[16];
  const float* W_noisy  = (const float*)d_in[17];
  const float* W_mlp1   = (const float*)d_in[18];
  const float* W_mlp2   = (const float*)d_in[19];
  const float* W_mlp3   = (const float*)d_in[20];
  const float* at_ln_g  = (const float*)d_in[21];
  const float* at_ln_b  = (const float*)d_in[22];
  const float* at_Wq    = (const float*)d_in[23];
  const float* at_Wk    = (const float*)d_in[24];
  const float* at_Wv    = (const float*)d_in[25];
  const float* at_Wg    = (const float*)d_in[26];
  const float* at_lnp_g = (const float*)d_in[27];
  const float* at_lnp_b = (const float*)d_in[28];
  const float* at_Wb    = (const float*)d_in[29];
  const float* at_Wo    = (const float*)d_in[30];
  const float* at_ln2_g = (const float*)d_in[31];
  const float* at_ln2_b = (const float*)d_in[32];
  const float* at_Wt1   = (const float*)d_in[33];
  const float* at_Wt2   = (const float*)d_in[34];
  const float* W_proj   = (const float*)d_in[35];
  float* out = (float*)d_out;
  float* W = (float*)d_ws;
  float* x     = W;                 //   98304
  float* ca    = W + 98304;         //   12288
  float* cb    = W + 110592;        //   12288
  float* zp    = W + 122880;        // 1048576
  float* biasA = W + 1171456;       // 1179648
  float* og    = W + 2351104;       //   98304  (total 2449408 f = 9.8 MB)

  k_zp<<<4096, 256, 0, stream>>>(z, ln_z_g, ln_z_b, W_pair, zp);
  k_tokatoms<<<256, 128, 0, stream>>>(s, ln_s_g, ln_s_b, W_single, ref_pos, r,
                                      W_pos, W_noisy, Wca, Wcb,
                                      out + 393216, x, ca, cb);
  k_pair2<<<1152, 256, 0, stream>>>(ref_pos, uid, Wpo, Wisd, Wmask, W_mlp1, W_mlp2,
                                    W_mlp3, zp, ca, cb, at_lnp_g, at_lnp_b, at_Wb,
                                    out + 491520, biasA);
  for (int b = 0; b < 3; b++) {
    k_qa<<<96, 512, 0, stream>>>(x, at_ln_g + b * 128, at_ln_b + b * 128,
                                 at_Wq + b * 16384, at_Wk + b * 16384,
                                 at_Wv + b * 16384, at_Wg + b * 16384,
                                 biasA + b * 393216, og);
    k_fused<<<192, 256, 0, stream>>>(og, at_Wo + b * 16384, at_ln2_g + b * 128,
                                     at_ln2_b + b * 128, at_Wt1 + b * 65536,
                                     at_Wt2 + b * 65536, x);
  }
  k_final<<<256, 384, 0, stream>>>(x, W_proj, out);
}

// Round 6
// 228.733 us; speedup vs baseline: 1.4513x; 1.4513x over previous
//
#include <hip/hip_runtime.h>
#include <math.h>

// N=768 atoms, T=256 tokens, CA=128, CP=16, CZ=128, CS=384, CT=384, H=4, DH=32
// d_out: a_out[256*384]@0, qout[768*384]@98304, c[768*128]@393216, pair[768*768*16]@491520

__device__ __forceinline__ float sigmoidf_(float v) { return 1.f / (1.f + __expf(-v)); }

typedef __attribute__((ext_vector_type(4))) short s16x4;
typedef __attribute__((ext_vector_type(8))) short s16x8;
typedef __attribute__((ext_vector_type(4))) float f32x4;

__device__ __forceinline__ unsigned bfpack(float a, float b) {
  return (__float_as_uint(a) >> 16) | (__float_as_uint(b) & 0xFFFF0000u);
}
__device__ __forceinline__ short bf1(float a) { return (short)(__float_as_uint(a) >> 16); }

// ---------------------------------------------------------------------------
// k_tokatoms (R3): grid 256, block 128
__global__ __launch_bounds__(128) void k_tokatoms(
    const float* __restrict__ s, const float* __restrict__ g,
    const float* __restrict__ b, const float* __restrict__ W_single,
    const float* __restrict__ ref_pos, const float* __restrict__ r,
    const float* __restrict__ W_pos, const float* __restrict__ W_noisy,
    const float* __restrict__ Wca, const float* __restrict__ Wcb,
    float* __restrict__ c_out, float* __restrict__ x,
    float* __restrict__ ca, float* __restrict__ cb) {
  int tok = blockIdx.x, t = threadIdx.x;
  __shared__ float sln[384];
  __shared__ float ws[48 * 128];
  __shared__ float red[4];
  __shared__ float rc[128];
  float v0 = s[tok * 384 + t], v1 = s[tok * 384 + 128 + t], v2 = s[tok * 384 + 256 + t];
  float ps = v0 + v1 + v2, pq = v0 * v0 + v1 * v1 + v2 * v2;
#pragma unroll
  for (int o = 1; o < 64; o <<= 1) { ps += __shfl_xor(ps, o); pq += __shfl_xor(pq, o); }
  if ((t & 63) == 0) { red[t >> 6] = ps; red[2 + (t >> 6)] = pq; }
  __syncthreads();
  float mean = (red[0] + red[1]) * (1.f / 384.f);
  float var = (red[2] + red[3]) * (1.f / 384.f) - mean * mean;
  float rstd = rsqrtf(var + 1e-5f);
  sln[t] = (v0 - mean) * rstd * g[t] + b[t];
  sln[128 + t] = (v1 - mean) * rstd * g[128 + t] + b[128 + t];
  sln[256 + t] = (v2 - mean) * rstd * g[256 + t] + b[256 + t];
  float ctv = 0.f;
  for (int c0 = 0; c0 < 384; c0 += 48) {
    __syncthreads();
#pragma unroll
    for (int m = 0; m < 12; m++) {
      int idx = (t + 128 * m) * 4;
      *(float4*)&ws[idx] = *(const float4*)&W_single[c0 * 128 + idx];
    }
    __syncthreads();
#pragma unroll 8
    for (int kk = 0; kk < 48; kk++) ctv += sln[c0 + kk] * ws[kk * 128 + t];
  }
  float wp0 = W_pos[t], wp1 = W_pos[128 + t], wp2 = W_pos[256 + t];
  float wn0 = W_noisy[t], wn1 = W_noisy[128 + t], wn2 = W_noisy[256 + t];
#pragma unroll
  for (int a = 0; a < 3; a++) {
    int i = tok + 256 * a;
    float p0 = ref_pos[i * 3], p1 = ref_pos[i * 3 + 1], p2 = ref_pos[i * 3 + 2];
    float r0 = r[i * 3], r1 = r[i * 3 + 1], r2 = r[i * 3 + 2];
    float c0 = p0 * wp0 + p1 * wp1 + p2 * wp2;
    x[i * 128 + t] = c0 + r0 * wn0 + r1 * wn1 + r2 * wn2;
    float cc = c0 + ctv;
    c_out[i * 128 + t] = cc;
    __syncthreads();
    rc[t] = fmaxf(cc, 0.f);
    __syncthreads();
    int out_id = t >> 2, q = t & 3;
    const float* Wm = (out_id < 16) ? Wca : Wcb;
    int ch = out_id & 15;
    float acc = 0.f;
#pragma unroll
    for (int kk = 0; kk < 32; kk++) { int k = q * 32 + kk; acc += rc[k] * Wm[k * 16 + ch]; }
    acc += __shfl_xor(acc, 1);
    acc += __shfl_xor(acc, 2);
    if (q == 0) { if (out_id < 16) ca[i * 16 + ch] = acc; else cb[i * 16 + ch] = acc; }
  }
}

// ---------------------------------------------------------------------------
// k_zp (R3): zp[65536,16] = LN(z)@W_pair   grid 4096, block 256
__global__ __launch_bounds__(256) void k_zp(
    const float* __restrict__ z, const float* __restrict__ g,
    const float* __restrict__ lb, const float* __restrict__ W_pair,
    float* __restrict__ zp) {
  __shared__ float wT[16][132];
  __shared__ float zs[16][132];
  __shared__ float sWg[16], Bc[16];
  int t = threadIdx.x;
#pragma unroll
  for (int m = 0; m < 8; m++) {
    int e = t + 256 * m;
    int row = e >> 4, ch = e & 15;
    wT[ch][row] = g[row] * W_pair[e];
  }
  __syncthreads();
  if (t < 32) {
    int ch = t & 15;
    float a = 0.f;
    if (t < 16) {
#pragma unroll 8
      for (int k = 0; k < 128; k++) a += wT[ch][k];
      sWg[ch] = a;
    } else {
#pragma unroll 8
      for (int k = 0; k < 128; k++) a += lb[k] * W_pair[k * 16 + ch];
      Bc[ch] = a;
    }
  }
  int row = t >> 4, kk = (t & 15) * 8;
  long base = ((long)blockIdx.x * 16 + row) * 128 + kk;
  float4 a4 = *(const float4*)&z[base];
  float4 b4 = *(const float4*)&z[base + 4];
  *(float4*)&zs[row][kk] = a4;
  *(float4*)&zs[row][kk + 4] = b4;
  float ps = a4.x + a4.y + a4.z + a4.w + b4.x + b4.y + b4.z + b4.w;
  float pq = a4.x * a4.x + a4.y * a4.y + a4.z * a4.z + a4.w * a4.w +
             b4.x * b4.x + b4.y * b4.y + b4.z * b4.z + b4.w * b4.w;
#pragma unroll
  for (int o = 1; o < 16; o <<= 1) { ps += __shfl_xor(ps, o); pq += __shfl_xor(pq, o); }
  float m = ps * (1.f / 128.f);
  float rstd = rsqrtf(pq * (1.f / 128.f) - m * m + 1e-5f);
  __syncthreads();
  int ch = t & 15;
  float dotv = 0.f;
#pragma unroll 8
  for (int k4 = 0; k4 < 32; k4++) {
    float4 zv = *(float4*)&zs[row][k4 * 4];
    float4 wv = *(float4*)&wT[ch][k4 * 4];
    dotv += zv.x * wv.x + zv.y * wv.y + zv.z * wv.z + zv.w * wv.w;
  }
  zp[((long)blockIdx.x * 16 + row) * 16 + ch] = rstd * (dotv - m * sWg[ch]) + Bc[ch];
}

// ---------------------------------------------------------------------------
// k_pairM: pair + MFMA MLP + fused window bias.
// grid 2304 (i*3+jb), block 256 (4 waves x 64 j). Lane roles:
//   write/C phase: col c=l&15, rows 4*(l>>4)+r of each 16-j tile.
//   A-frag via ds_read_b64_tr_b16 from col-major bf16 tile (flat = k*16 + j).
__global__ __launch_bounds__(256) void k_pairM(
    const float* __restrict__ ref_pos, const int* __restrict__ uid,
    const float* __restrict__ Wpo, const float* __restrict__ Wisd,
    const float* __restrict__ Wmask, const float* __restrict__ W1,
    const float* __restrict__ W2, const float* __restrict__ W3,
    const float* __restrict__ zp, const float* __restrict__ ca,
    const float* __restrict__ cb, const float* __restrict__ lnp_g,
    const float* __restrict__ lnp_b, const float* __restrict__ Wb,
    float* __restrict__ pair_out, float* __restrict__ biasA) {
  int i = blockIdx.x / 3, jb = blockIdx.x % 3, t = threadIdx.x;
  __shared__ float jsx[256], jsy[256], jsz[256];
  __shared__ int jsu[256];
  __shared__ __align__(128) short stg[4][1280];   // 4 waves x 4 tiles x 640B
  __shared__ __align__(16) float pfs[4][1056];    // 4 waves x 4 tiles x 264 f32
  __shared__ float wgb[192];
  __shared__ float kbs[12];
  int jg = jb * 256 + t;
  jsx[t] = ref_pos[jg * 3];
  jsy[t] = ref_pos[jg * 3 + 1];
  jsz[t] = ref_pos[jg * 3 + 2];
  jsu[t] = uid[jg];
  if (t >= 64) {
    int e = t - 64;
    if (e < 192) {
      int bq = e >> 6, k = (e >> 2) & 15, h = e & 3;
      wgb[e] = lnp_g[bq * 16 + k] * Wb[bq * 64 + k * 4 + h];
    }
  }
  if (t >= 48 && t < 60) {
    int e = t - 48, bq = e >> 2, h = e & 3;
    float a = 0.f;
#pragma unroll
    for (int cc = 0; cc < 16; cc++) a += lnp_b[bq * 16 + cc] * Wb[bq * 64 + cc * 4 + h];
    kbs[e] = a;
  }
  int w = t >> 6, l = t & 63;
  int c = l & 15, gr = l >> 4;
  float pix = ref_pos[i * 3], piy = ref_pos[i * 3 + 1], piz = ref_pos[i * 3 + 2];
  int ui = uid[i];
  float w0c = Wpo[c], w1c = Wpo[16 + c], w2c = Wpo[32 + c];
  float wic = Wisd[c], wmc = Wmask[c], cac = ca[i * 16 + c];
  // B fragments (W[k][c] at element e -> k = 4*gr + e), upper K half zero
  s16x8 bw0 = {bf1(W1[(4 * gr + 0) * 16 + c]), bf1(W1[(4 * gr + 1) * 16 + c]),
               bf1(W1[(4 * gr + 2) * 16 + c]), bf1(W1[(4 * gr + 3) * 16 + c]),
               (short)0, (short)0, (short)0, (short)0};
  s16x8 bw1 = {bf1(W2[(4 * gr + 0) * 16 + c]), bf1(W2[(4 * gr + 1) * 16 + c]),
               bf1(W2[(4 * gr + 2) * 16 + c]), bf1(W2[(4 * gr + 3) * 16 + c]),
               (short)0, (short)0, (short)0, (short)0};
  s16x8 bw2 = {bf1(W3[(4 * gr + 0) * 16 + c]), bf1(W3[(4 * gr + 1) * 16 + c]),
               bf1(W3[(4 * gr + 2) * 16 + c]), bf1(W3[(4 * gr + 3) * 16 + c]),
               (short)0, (short)0, (short)0, (short)0};
  __syncthreads();
  char* sb = (char*)&stg[w][0];
  unsigned sbase = (unsigned)(uintptr_t)sb;
  f32x4 z4 = {0.f, 0.f, 0.f, 0.f};
#pragma unroll
  for (int g = 0; g < 4; g++) {
    // p in C-frag layout
    float p0_, p1_, p2_, p3_;
    {
      int jl0 = w * 64 + g * 16 + 4 * gr;
#pragma unroll
      for (int r = 0; r < 4; r++) {
        int jloc = jl0 + r;
        int j = jb * 256 + jloc;
        float d0 = pix - jsx[jloc], d1 = piy - jsy[jloc], d2 = piz - jsz[jloc];
        float mk = (ui == jsu[jloc]) ? 1.f : 0.f;
        float inv = 1.f / (1.f + d0 * d0 + d1 * d1 + d2 * d2);
        float zv = zp[((long)((i & 255) << 8) + jloc) * 16 + c];
        float cbv = cb[j * 16 + c];
        float pv = mk * (d0 * w0c + d1 * w1c + d2 * w2c + inv * wic + wmc) + zv + cbv + cac;
        if (r == 0) p0_ = pv; else if (r == 1) p1_ = pv; else if (r == 2) p2_ = pv; else p3_ = pv;
      }
    }
    char* wp = sb + g * 640 + c * 32 + gr * 8;
    unsigned ra = sbase + (unsigned)(g * 640 + c * 8 + gr * 128);
    // stage relu(p)
    *(uint2*)wp = make_uint2(bfpack(fmaxf(p0_, 0.f), fmaxf(p1_, 0.f)),
                             bfpack(fmaxf(p2_, 0.f), fmaxf(p3_, 0.f)));
    s16x4 tr0;
    asm volatile("s_waitcnt lgkmcnt(0)\n\tds_read_b64_tr_b16 %0, %1\n\ts_waitcnt lgkmcnt(0)"
                 : "=v"(tr0) : "v"(ra) : "memory");
    s16x8 a8 = {tr0[0], tr0[1], tr0[2], tr0[3], (short)0, (short)0, (short)0, (short)0};
    f32x4 h1 = __builtin_amdgcn_mfma_f32_16x16x32_bf16(a8, bw0, z4, 0, 0, 0);
    *(uint2*)wp = make_uint2(bfpack(fmaxf(h1[0], 0.f), fmaxf(h1[1], 0.f)),
                             bfpack(fmaxf(h1[2], 0.f), fmaxf(h1[3], 0.f)));
    s16x4 tr1;
    asm volatile("s_waitcnt lgkmcnt(0)\n\tds_read_b64_tr_b16 %0, %1\n\ts_waitcnt lgkmcnt(0)"
                 : "=v"(tr1) : "v"(ra) : "memory");
    s16x8 a8b = {tr1[0], tr1[1], tr1[2], tr1[3], (short)0, (short)0, (short)0, (short)0};
    f32x4 h2 = __builtin_amdgcn_mfma_f32_16x16x32_bf16(a8b, bw1, z4, 0, 0, 0);
    *(uint2*)wp = make_uint2(bfpack(fmaxf(h2[0], 0.f), fmaxf(h2[1], 0.f)),
                             bfpack(fmaxf(h2[2], 0.f), fmaxf(h2[3], 0.f)));
    s16x4 tr2;
    asm volatile("s_waitcnt lgkmcnt(0)\n\tds_read_b64_tr_b16 %0, %1\n\ts_waitcnt lgkmcnt(0)"
                 : "=v"(tr2) : "v"(ra) : "memory");
    s16x8 a8c = {tr2[0], tr2[1], tr2[2], tr2[3], (short)0, (short)0, (short)0, (short)0};
    f32x4 h3 = __builtin_amdgcn_mfma_f32_16x16x32_bf16(a8c, bw2, z4, 0, 0, 0);
    float f0 = p0_ + h3[0], f1 = p1_ + h3[1], f2 = p2_ + h3[2], f3 = p3_ + h3[3];
    // pair stores (lanes 0..15 contiguous 64B per (g,r))
    {
      int jl0 = w * 64 + g * 16 + 4 * gr;
      long pb = ((long)i * 768 + (long)(jb * 256 + jl0)) * 16 + c;
      pair_out[pb] = f0;
      pair_out[pb + 16] = f1;
      pair_out[pb + 32] = f2;
      pair_out[pb + 48] = f3;
    }
    *(float4*)&pfs[w][g * 264 + c * 16 + 4 * gr] = make_float4(f0, f1, f2, f3);
  }
  asm volatile("s_waitcnt lgkmcnt(0)" ::: "memory");
  // window bias pass: lane owns j = jb*256 + t
  int qb = i >> 5;
  int j = jb * 256 + t;
  unsigned jw = (unsigned)(j - (qb * 32 - 48));
  if (jw < 128u) {
    int gt = (t >> 4) & 3, jr = t & 15;
    float v[16];
#pragma unroll
    for (int cc = 0; cc < 16; cc++) v[cc] = pfs[w][gt * 264 + cc * 16 + jr];
    float m = 0.f;
#pragma unroll
    for (int cc = 0; cc < 16; cc++) m += v[cc];
    m *= (1.f / 16.f);
    float vv = 0.f;
#pragma unroll
    for (int cc = 0; cc < 16; cc++) { float d = v[cc] - m; vv += d * d; }
    float rs = rsqrtf(vv * (1.f / 16.f) + 1e-5f);
    float nrm[16];
#pragma unroll
    for (int cc = 0; cc < 16; cc++) nrm[cc] = (v[cc] - m) * rs;
    int qi = i & 31;
#pragma unroll
    for (int bq = 0; bq < 3; bq++) {
      float o0 = kbs[bq * 4 + 0], o1 = kbs[bq * 4 + 1];
      float o2 = kbs[bq * 4 + 2], o3 = kbs[bq * 4 + 3];
#pragma unroll
      for (int k = 0; k < 16; k++) {
        float nv = nrm[k];
        float4 wv = *(float4*)&wgb[bq * 64 + k * 4];
        o0 += nv * wv.x; o1 += nv * wv.y; o2 += nv * wv.z; o3 += nv * wv.w;
      }
      long base = (long)(bq * 96 + qb * 4) * 4096 + (long)qi * 128 + jw;
      biasA[base] = o0;
      biasA[base + 4096] = o1;
      biasA[base + 2 * 4096] = o2;
      biasA[base + 3 * 4096] = o3;
    }
  }
}

// ---------------------------------------------------------------------------
// k_qkvg (R3): grid 384 (rb*8+bn), block 256
__global__ __launch_bounds__(256) void k_qkvg(
    const float* __restrict__ x, const float* __restrict__ lng,
    const float* __restrict__ lnb, const float* __restrict__ Wq,
    const float* __restrict__ Wk, const float* __restrict__ Wv,
    const float* __restrict__ Wg, float* __restrict__ qkvg) {
  __shared__ float As[128][18];
  __shared__ float Ws[128][66];
  int t = threadIdx.x;
  int rb = blockIdx.x >> 3, bn = blockIdx.x & 7;
  int r0 = rb * 16;
  const float* Wm = (bn < 2) ? Wq : (bn < 4) ? Wk : (bn < 6) ? Wv : Wg;
  int c0 = (bn & 1) * 64;
  int ncol0 = (bn >> 1) * 128 + c0;
#pragma unroll
  for (int m = 0; m < 8; m++) {
    int idx = t + 256 * m;
    int row = idx >> 4, c4 = (idx & 15) * 4;
    *(float4*)&Ws[row][c4] = *(const float4*)&Wm[row * 128 + c0 + c4];
  }
  {
    int rr = t >> 4, tt = t & 15;
    int row = r0 + rr;
    float4 x0 = *(const float4*)&x[row * 128 + tt * 8];
    float4 x1 = *(const float4*)&x[row * 128 + tt * 8 + 4];
    float ps = x0.x + x0.y + x0.z + x0.w + x1.x + x1.y + x1.z + x1.w;
    float pq = x0.x * x0.x + x0.y * x0.y + x0.z * x0.z + x0.w * x0.w +
               x1.x * x1.x + x1.y * x1.y + x1.z * x1.z + x1.w * x1.w;
#pragma unroll
    for (int o = 1; o < 16; o <<= 1) { ps += __shfl_xor(ps, o); pq += __shfl_xor(pq, o); }
    float m = ps * (1.f / 128.f);
    float rstd = rsqrtf(pq * (1.f / 128.f) - m * m + 1e-5f);
    float4 g0 = *(const float4*)&lng[tt * 8], g1 = *(const float4*)&lng[tt * 8 + 4];
    float4 b0 = *(const float4*)&lnb[tt * 8], b1 = *(const float4*)&lnb[tt * 8 + 4];
    As[tt * 8 + 0][rr] = (x0.x - m) * rstd * g0.x + b0.x;
    As[tt * 8 + 1][rr] = (x0.y - m) * rstd * g0.y + b0.y;
    As[tt * 8 + 2][rr] = (x0.z - m) * rstd * g0.z + b0.z;
    As[tt * 8 + 3][rr] = (x0.w - m) * rstd * g0.w + b0.w;
    As[tt * 8 + 4][rr] = (x1.x - m) * rstd * g1.x + b1.x;
    As[tt * 8 + 5][rr] = (x1.y - m) * rstd * g1.y + b1.y;
    As[tt * 8 + 6][rr] = (x1.z - m) * rstd * g1.z + b1.z;
    As[tt * 8 + 7][rr] = (x1.w - m) * rstd * g1.w + b1.w;
  }
  __syncthreads();
  int ty = t >> 5, tx = t & 31;
  float a00 = 0, a01 = 0, a10 = 0, a11 = 0;
#pragma unroll 8
  for (int k = 0; k < 128; k++) {
    float2 a2 = *(float2*)&As[k][ty * 2];
    float2 w2 = *(float2*)&Ws[k][tx * 2];
    a00 += a2.x * w2.x; a01 += a2.x * w2.y;
    a10 += a2.y * w2.x; a11 += a2.y * w2.y;
  }
  int row = r0 + ty * 2;
  float2 o0 = {a00, a01}, o1 = {a10, a11};
  *(float2*)&qkvg[row * 512 + ncol0 + tx * 2] = o0;
  *(float2*)&qkvg[(row + 1) * 512 + ncol0 + tx * 2] = o1;
}

// ---------------------------------------------------------------------------
// k_attn (R3): grid 96, block 256
__global__ __launch_bounds__(256) void k_attn(
    const float* __restrict__ qkvg, const float* __restrict__ biasb,
    float* __restrict__ og) {
  int qb = blockIdx.x >> 2, h = blockIdx.x & 3, t = threadIdx.x;
  int i0 = qb * 32, lo = i0 - 48;
  __shared__ float qs[32][36];
  __shared__ float ks[128][36];
  __shared__ float vs[128][36];
  __shared__ float L[32][132];
#pragma unroll
  for (int m = 0; m < 4; m++) {
    int idx = t + 256 * m;
    int qi = idx >> 5, k4 = (idx & 31) * 4;
    int j = lo + k4;
    float4 bv;
    if (j >= 0 && j < 768) bv = *(const float4*)&biasb[(qb * 4 + h) * 4096 + qi * 128 + k4];
    else bv = make_float4(-1e30f, -1e30f, -1e30f, -1e30f);
    *(float4*)&L[qi][k4] = bv;
  }
  {
    int qi = t >> 3, dq = (t & 7) * 4;
    *(float4*)&qs[qi][dq] = *(const float4*)&qkvg[(i0 + qi) * 512 + h * 32 + dq];
  }
  {
    int kj = t >> 1, dh = (t & 1) * 16;
    int j = lo + kj;
    if (j >= 0 && j < 768) {
      const float4* sk = (const float4*)&qkvg[j * 512 + 128 + h * 32 + dh];
      const float4* sv = (const float4*)&qkvg[j * 512 + 256 + h * 32 + dh];
#pragma unroll
      for (int m = 0; m < 4; m++) {
        *(float4*)&ks[kj][dh + 4 * m] = sk[m];
        *(float4*)&vs[kj][dh + 4 * m] = sv[m];
      }
    } else {
      float4 zz = {0, 0, 0, 0};
#pragma unroll
      for (int m = 0; m < 4; m++) {
        *(float4*)&ks[kj][dh + 4 * m] = zz;
        *(float4*)&vs[kj][dh + 4 * m] = zz;
      }
    }
  }
  __syncthreads();
  const float scale = 0.17677669529663687f;
  {
    int qi = t & 31, kb = t >> 5;
    float4 qr[8];
#pragma unroll
    for (int m = 0; m < 8; m++) qr[m] = *(float4*)&qs[qi][m * 4];
#pragma unroll 2
    for (int kk = 0; kk < 16; kk++) {
      int kj = kb * 16 + kk;
      float acc = 0.f;
#pragma unroll
      for (int m = 0; m < 8; m++) {
        float4 kv = *(float4*)&ks[kj][m * 4];
        acc += qr[m].x * kv.x + qr[m].y * kv.y + qr[m].z * kv.z + qr[m].w * kv.w;
      }
      L[qi][kj] += acc * scale;
    }
  }
  __syncthreads();
  int qi = t >> 3, sg = t & 7;
  float mx = -1e30f;
#pragma unroll
  for (int k2 = 0; k2 < 16; k2++) mx = fmaxf(mx, L[qi][sg * 16 + k2]);
#pragma unroll
  for (int o = 1; o < 8; o <<= 1) mx = fmaxf(mx, __shfl_xor(mx, o));
  float sum = 0.f;
#pragma unroll
  for (int k2 = 0; k2 < 16; k2++) {
    int kj = sg * 16 + k2;
    float e = __expf(L[qi][kj] - mx);
    L[qi][kj] = e;
    sum += e;
  }
#pragma unroll
  for (int o = 1; o < 8; o <<= 1) sum += __shfl_xor(sum, o);
  float rden = 1.f / sum;
  __syncthreads();
  int d0 = (t & 7) * 4;
  float4 acc = {0, 0, 0, 0};
#pragma unroll 4
  for (int kj = 0; kj < 128; kj++) {
    float p = L[qi][kj];
    float4 v = *(const float4*)&vs[kj][d0];
    acc.x += p * v.x; acc.y += p * v.y; acc.z += p * v.z; acc.w += p * v.w;
  }
  int i = i0 + qi;
  float4 gr = *(const float4*)&qkvg[i * 512 + 384 + h * 32 + d0];
  float4 o4;
  o4.x = acc.x * rden * sigmoidf_(gr.x);
  o4.y = acc.y * rden * sigmoidf_(gr.y);
  o4.z = acc.z * rden * sigmoidf_(gr.z);
  o4.w = acc.w * rden * sigmoidf_(gr.w);
  *(float4*)&og[i * 128 + h * 32 + d0] = o4;
}

// ---------------------------------------------------------------------------
// k_fused (R3): grid 96 (8 rows), block 256
__global__ __launch_bounds__(256) void k_fused(
    const float* __restrict__ og, const float* __restrict__ Wo,
    const float* __restrict__ g2, const float* __restrict__ b2,
    const float* __restrict__ Wt1, const float* __restrict__ Wt2,
    float* __restrict__ x) {
  int t = threadIdx.x;
  int r0 = blockIdx.x * 8;
  __shared__ float os[8][132];
  __shared__ float xn[8][132];
  __shared__ float a[8][132];
  __shared__ float h[8][516];
  __shared__ float wc[8192];
  {
    int rr = t >> 5, c4 = (t & 31) * 4;
    *(float4*)&os[rr][c4] = *(const float4*)&og[(r0 + rr) * 128 + c4];
    *(float4*)&xn[rr][c4] = *(const float4*)&x[(r0 + rr) * 128 + c4];
  }
  int c = t & 127, rh = t >> 7;
  float ac[4] = {0, 0, 0, 0};
  for (int k0 = 0; k0 < 128; k0 += 64) {
    __syncthreads();
#pragma unroll
    for (int m = 0; m < 8; m++) {
      int idx = (t + 256 * m) * 4;
      *(float4*)&wc[idx] = *(const float4*)&Wo[k0 * 128 + idx];
    }
    __syncthreads();
#pragma unroll 4
    for (int kk = 0; kk < 64; kk++) {
      float w = wc[kk * 128 + c];
      int k = k0 + kk;
      ac[0] += os[rh * 4 + 0][k] * w; ac[1] += os[rh * 4 + 1][k] * w;
      ac[2] += os[rh * 4 + 2][k] * w; ac[3] += os[rh * 4 + 3][k] * w;
    }
  }
  __syncthreads();
#pragma unroll
  for (int rr = 0; rr < 4; rr++) xn[rh * 4 + rr][c] += ac[rr];
  __syncthreads();
  {
    int rr = t >> 5, tt = t & 31;
    float4 xv = *(float4*)&xn[rr][tt * 4];
    float ps = xv.x + xv.y + xv.z + xv.w;
    float pq = xv.x * xv.x + xv.y * xv.y + xv.z * xv.z + xv.w * xv.w;
#pragma unroll
    for (int o = 1; o < 32; o <<= 1) { ps += __shfl_xor(ps, o); pq += __shfl_xor(pq, o); }
    float m = ps * (1.f / 128.f);
    float rstd = rsqrtf(pq * (1.f / 128.f) - m * m + 1e-5f);
    float4 gg = *(const float4*)&g2[tt * 4];
    float4 bb = *(const float4*)&b2[tt * 4];
    float4 av;
    av.x = (xv.x - m) * rstd * gg.x + bb.x;
    av.y = (xv.y - m) * rstd * gg.y + bb.y;
    av.z = (xv.z - m) * rstd * gg.z + bb.z;
    av.w = (xv.w - m) * rstd * gg.w + bb.w;
    *(float4*)&a[rr][tt * 4] = av;
  }
  int rr3 = t >> 5, cg = t & 31;
  float acc16[16];
#pragma unroll
  for (int e = 0; e < 16; e++) acc16[e] = 0.f;
  for (int k0 = 0; k0 < 128; k0 += 16) {
    __syncthreads();
#pragma unroll
    for (int m = 0; m < 8; m++) {
      int idx = (t + 256 * m) * 4;
      *(float4*)&wc[idx] = *(const float4*)&Wt1[k0 * 512 + idx];
    }
    __syncthreads();
#pragma unroll 2
    for (int kk = 0; kk < 16; kk++) {
      float av = a[rr3][k0 + kk];
#pragma unroll
      for (int q = 0; q < 4; q++) {
        float4 w4 = *(float4*)&wc[kk * 512 + q * 128 + cg * 4];
        acc16[q * 4 + 0] += av * w4.x; acc16[q * 4 + 1] += av * w4.y;
        acc16[q * 4 + 2] += av * w4.z; acc16[q * 4 + 3] += av * w4.w;
      }
    }
  }
  __syncthreads();
#pragma unroll
  for (int q = 0; q < 4; q++) {
    float4 hv = {fmaxf(acc16[q * 4 + 0], 0.f), fmaxf(acc16[q * 4 + 1], 0.f),
                 fmaxf(acc16[q * 4 + 2], 0.f), fmaxf(acc16[q * 4 + 3], 0.f)};
    *(float4*)&h[rr3][q * 128 + cg * 4] = hv;
  }
  float ac2[4] = {0, 0, 0, 0};
  for (int k0 = 0; k0 < 512; k0 += 64) {
    __syncthreads();
#pragma unroll
    for (int m = 0; m < 8; m++) {
      int idx = (t + 256 * m) * 4;
      *(float4*)&wc[idx] = *(const float4*)&Wt2[k0 * 128 + idx];
    }
    __syncthreads();
#pragma unroll 4
    for (int kk = 0; kk < 64; kk++) {
      float w = wc[kk * 128 + c];
      int k = k0 + kk;
      ac2[0] += h[rh * 4 + 0][k] * w; ac2[1] += h[rh * 4 + 1][k] * w;
      ac2[2] += h[rh * 4 + 2][k] * w; ac2[3] += h[rh * 4 + 3][k] * w;
    }
  }
#pragma unroll
  for (int rr = 0; rr < 4; rr++)
    x[(r0 + rh * 4 + rr) * 128 + c] = xn[rh * 4 + rr][c] + ac2[rr];
}

// ---------------------------------------------------------------------------
// k_final (R3): grid 256, block 384
__global__ __launch_bounds__(384) void k_final(
    const float* __restrict__ x, const float* __restrict__ W_proj,
    float* __restrict__ out) {
  __shared__ float xs[384];
  int tk = blockIdx.x, t = threadIdx.x;
  xs[t] = x[tk * 384 + t];
  __syncthreads();
  float a0 = 0, a1 = 0, a2 = 0;
#pragma unroll 8
  for (int k = 0; k < 128; k++) {
    float w = W_proj[k * 384 + t];
    a0 += xs[k] * w; a1 += xs[128 + k] * w; a2 += xs[256 + k] * w;
  }
  a0 = fmaxf(a0, 0.f); a1 = fmaxf(a1, 0.f); a2 = fmaxf(a2, 0.f);
  out[98304 + (tk * 3 + 0) * 384 + t] = a0;
  out[98304 + (tk * 3 + 1) * 384 + t] = a1;
  out[98304 + (tk * 3 + 2) * 384 + t] = a2;
  out[tk * 384 + t] = (a0 + a1 + a2) * (1.f / 3.f);
}

// ---------------------------------------------------------------------------
extern "C" void kernel_launch(void* const* d_in, const int* in_sizes, int n_in,
                              void* d_out, int out_size, void* d_ws, size_t ws_size,
                              hipStream_t stream) {
  const float* ref_pos  = (const float*)d_in[0];
  const int*   uid      = (const int*)d_in[1];
  const float* r        = (const float*)d_in[2];
  const float* s        = (const float*)d_in[3];
  const float* z        = (const float*)d_in[4];
  const float* W_pos    = (const float*)d_in[5];
  const float* Wpo      = (const float*)d_in[6];
  const float* Wisd     = (const float*)d_in[7];
  const float* Wmask    = (const float*)d_in[8];
  const float* Wca      = (const float*)d_in[9];
  const float* Wcb      = (const float*)d_in[10];
  const float* ln_s_g   = (const float*)d_in[11];
  const float* ln_s_b   = (const float*)d_in[12];
  const float* W_single = (const float*)d_in[13];
  const float* ln_z_g   = (const float*)d_in[14];
  const float* ln_z_b   = (const float*)d_in[15];
  const float* W_pair   = (const float*)d_in[16];
  const float* W_noisy  = (const float*)d_in[17];
  const float* W_mlp1   = (const float*)d_in[18];
  const float* W_mlp2   = (const float*)d_in[19];
  const float* W_mlp3   = (const float*)d_in[20];
  const float* at_ln_g  = (const float*)d_in[21];
  const float* at_ln_b  = (const float*)d_in[22];
  const float* at_Wq    = (const float*)d_in[23];
  const float* at_Wk    = (const float*)d_in[24];
  const float* at_Wv    = (const float*)d_in[25];
  const float* at_Wg    = (const float*)d_in[26];
  const float* at_lnp_g = (const float*)d_in[27];
  const float* at_lnp_b = (const float*)d_in[28];
  const float* at_Wb    = (const float*)d_in[29];
  const float* at_Wo    = (const float*)d_in[30];
  const float* at_ln2_g = (const float*)d_in[31];
  const float* at_ln2_b = (const float*)d_in[32];
  const float* at_Wt1   = (const float*)d_in[33];
  const float* at_Wt2   = (const float*)d_in[34];
  const float* W_proj   = (const float*)d_in[35];
  float* out = (float*)d_out;
  float* W = (float*)d_ws;
  float* x     = W;                 //   98304
  float* ca    = W + 98304;         //   12288
  float* cb    = W + 110592;        //   12288
  float* zp    = W + 122880;        // 1048576
  float* biasA = W + 1171456;       // 1179648
  float* qkvg  = W + 2351104;       //  393216
  float* og    = W + 2744320;       //   98304

  k_zp<<<4096, 256, 0, stream>>>(z, ln_z_g, ln_z_b, W_pair, zp);
  k_tokatoms<<<256, 128, 0, stream>>>(s, ln_s_g, ln_s_b, W_single, ref_pos, r,
                                      W_pos, W_noisy, Wca, Wcb,
                                      out + 393216, x, ca, cb);
  k_pairM<<<2304, 256, 0, stream>>>(ref_pos, uid, Wpo, Wisd, Wmask, W_mlp1, W_mlp2,
                                    W_mlp3, zp, ca, cb, at_lnp_g, at_lnp_b, at_Wb,
                                    out + 491520, biasA);
  for (int b = 0; b < 3; b++) {
    k_qkvg<<<384, 256, 0, stream>>>(x, at_ln_g + b * 128, at_ln_b + b * 128,
                                    at_Wq + b * 16384, at_Wk + b * 16384,
                                    at_Wv + b * 16384, at_Wg + b * 16384, qkvg);
    k_attn<<<96, 256, 0, stream>>>(qkvg, biasA + b * 393216, og);
    k_fused<<<96, 256, 0, stream>>>(og, at_Wo + b * 16384, at_ln2_g + b * 128,
                                    at_ln2_b + b * 128, at_Wt1 + b * 65536,
                                    at_Wt2 + b * 65536, x);
  }
  k_final<<<256, 384, 0, stream>>>(x, W_proj, out);
}

// Round 9
// 197.446 us; speedup vs baseline: 1.6812x; 1.1585x over previous
//
#include <hip/hip_runtime.h>
#include <math.h>

// N=768 atoms, T=256 tokens, CA=128, CP=16, CZ=128, CS=384, CT=384, H=4, DH=32
// d_out: a_out[256*384]@0, qout[768*384]@98304, c[768*128]@393216, pair[768*768*16]@491520

__device__ __forceinline__ float sigmoidf_(float v) { return 1.f / (1.f + __expf(-v)); }

typedef __attribute__((ext_vector_type(4))) short s16x4;
typedef __attribute__((ext_vector_type(8))) short s16x8;
typedef __attribute__((ext_vector_type(4))) float f32x4;

__device__ __forceinline__ unsigned bfpack(float a, float b) {
  return (__float_as_uint(a) >> 16) | (__float_as_uint(b) & 0xFFFF0000u);
}
__device__ __forceinline__ short bf1(float a) { return (short)(__float_as_uint(a) >> 16); }

// ---------------------------------------------------------------------------
// k_tokatoms: grid 256, block 128
__global__ __launch_bounds__(128) void k_tokatoms(
    const float* __restrict__ s, const float* __restrict__ g,
    const float* __restrict__ b, const float* __restrict__ W_single,
    const float* __restrict__ ref_pos, const float* __restrict__ r,
    const float* __restrict__ W_pos, const float* __restrict__ W_noisy,
    const float* __restrict__ Wca, const float* __restrict__ Wcb,
    float* __restrict__ c_out, float* __restrict__ x,
    float* __restrict__ ca, float* __restrict__ cb) {
  int tok = blockIdx.x, t = threadIdx.x;
  __shared__ float sln[384];
  __shared__ float ws[48 * 128];
  __shared__ float red[4];
  __shared__ float rc[128];
  float v0 = s[tok * 384 + t], v1 = s[tok * 384 + 128 + t], v2 = s[tok * 384 + 256 + t];
  float ps = v0 + v1 + v2, pq = v0 * v0 + v1 * v1 + v2 * v2;
#pragma unroll
  for (int o = 1; o < 64; o <<= 1) { ps += __shfl_xor(ps, o); pq += __shfl_xor(pq, o); }
  if ((t & 63) == 0) { red[t >> 6] = ps; red[2 + (t >> 6)] = pq; }
  __syncthreads();
  float mean = (red[0] + red[1]) * (1.f / 384.f);
  float var = (red[2] + red[3]) * (1.f / 384.f) - mean * mean;
  float rstd = rsqrtf(var + 1e-5f);
  sln[t] = (v0 - mean) * rstd * g[t] + b[t];
  sln[128 + t] = (v1 - mean) * rstd * g[128 + t] + b[128 + t];
  sln[256 + t] = (v2 - mean) * rstd * g[256 + t] + b[256 + t];
  float ctv = 0.f;
  for (int c0 = 0; c0 < 384; c0 += 48) {
    __syncthreads();
#pragma unroll
    for (int m = 0; m < 12; m++) {
      int idx = (t + 128 * m) * 4;
      *(float4*)&ws[idx] = *(const float4*)&W_single[c0 * 128 + idx];
    }
    __syncthreads();
#pragma unroll 8
    for (int kk = 0; kk < 48; kk++) ctv += sln[c0 + kk] * ws[kk * 128 + t];
  }
  float wp0 = W_pos[t], wp1 = W_pos[128 + t], wp2 = W_pos[256 + t];
  float wn0 = W_noisy[t], wn1 = W_noisy[128 + t], wn2 = W_noisy[256 + t];
#pragma unroll
  for (int a = 0; a < 3; a++) {
    int i = tok + 256 * a;
    float p0 = ref_pos[i * 3], p1 = ref_pos[i * 3 + 1], p2 = ref_pos[i * 3 + 2];
    float r0 = r[i * 3], r1 = r[i * 3 + 1], r2 = r[i * 3 + 2];
    float c0 = p0 * wp0 + p1 * wp1 + p2 * wp2;
    x[i * 128 + t] = c0 + r0 * wn0 + r1 * wn1 + r2 * wn2;
    float cc = c0 + ctv;
    c_out[i * 128 + t] = cc;
    __syncthreads();
    rc[t] = fmaxf(cc, 0.f);
    __syncthreads();
    int out_id = t >> 2, q = t & 3;
    const float* Wm = (out_id < 16) ? Wca : Wcb;
    int ch = out_id & 15;
    float acc = 0.f;
#pragma unroll
    for (int kk = 0; kk < 32; kk++) { int k = q * 32 + kk; acc += rc[k] * Wm[k * 16 + ch]; }
    acc += __shfl_xor(acc, 1);
    acc += __shfl_xor(acc, 2);
    if (q == 0) { if (out_id < 16) ca[i * 16 + ch] = acc; else cb[i * 16 + ch] = acc; }
  }
}

// ---------------------------------------------------------------------------
// k_zp: zp[65536,16] = LN(z)@W_pair   grid 4096, block 256
__global__ __launch_bounds__(256) void k_zp(
    const float* __restrict__ z, const float* __restrict__ g,
    const float* __restrict__ lb, const float* __restrict__ W_pair,
    float* __restrict__ zp) {
  __shared__ float wT[16][132];
  __shared__ float zs[16][132];
  __shared__ float sWg[16], Bc[16];
  int t = threadIdx.x;
#pragma unroll
  for (int m = 0; m < 8; m++) {
    int e = t + 256 * m;
    int row = e >> 4, ch = e & 15;
    wT[ch][row] = g[row] * W_pair[e];
  }
  __syncthreads();
  if (t < 32) {
    int ch = t & 15;
    float a = 0.f;
    if (t < 16) {
#pragma unroll 8
      for (int k = 0; k < 128; k++) a += wT[ch][k];
      sWg[ch] = a;
    } else {
#pragma unroll 8
      for (int k = 0; k < 128; k++) a += lb[k] * W_pair[k * 16 + ch];
      Bc[ch] = a;
    }
  }
  int row = t >> 4, kk = (t & 15) * 8;
  long base = ((long)blockIdx.x * 16 + row) * 128 + kk;
  float4 a4 = *(const float4*)&z[base];
  float4 b4 = *(const float4*)&z[base + 4];
  *(float4*)&zs[row][kk] = a4;
  *(float4*)&zs[row][kk + 4] = b4;
  float ps = a4.x + a4.y + a4.z + a4.w + b4.x + b4.y + b4.z + b4.w;
  float pq = a4.x * a4.x + a4.y * a4.y + a4.z * a4.z + a4.w * a4.w +
             b4.x * b4.x + b4.y * b4.y + b4.z * b4.z + b4.w * b4.w;
#pragma unroll
  for (int o = 1; o < 16; o <<= 1) { ps += __shfl_xor(ps, o); pq += __shfl_xor(pq, o); }
  float m = ps * (1.f / 128.f);
  float rstd = rsqrtf(pq * (1.f / 128.f) - m * m + 1e-5f);
  __syncthreads();
  int ch = t & 15;
  float dotv = 0.f;
#pragma unroll 8
  for (int k4 = 0; k4 < 32; k4++) {
    float4 zv = *(float4*)&zs[row][k4 * 4];
    float4 wv = *(float4*)&wT[ch][k4 * 4];
    dotv += zv.x * wv.x + zv.y * wv.y + zv.z * wv.z + zv.w * wv.w;
  }
  zp[((long)blockIdx.x * 16 + row) * 16 + ch] = rstd * (dotv - m * sWg[ch]) + Bc[ch];
}

// ---------------------------------------------------------------------------
// k_pairM: pair + MFMA MLP + fused window bias.  grid 2304, block 256
__global__ __launch_bounds__(256) void k_pairM(
    const float* __restrict__ ref_pos, const int* __restrict__ uid,
    const float* __restrict__ Wpo, const float* __restrict__ Wisd,
    const float* __restrict__ Wmask, const float* __restrict__ W1,
    const float* __restrict__ W2, const float* __restrict__ W3,
    const float* __restrict__ zp, const float* __restrict__ ca,
    const float* __restrict__ cb, const float* __restrict__ lnp_g,
    const float* __restrict__ lnp_b, const float* __restrict__ Wb,
    float* __restrict__ pair_out, float* __restrict__ biasA) {
  int i = blockIdx.x / 3, jb = blockIdx.x % 3, t = threadIdx.x;
  __shared__ float jsx[256], jsy[256], jsz[256];
  __shared__ int jsu[256];
  __shared__ __align__(128) short stg[4][1280];
  __shared__ __align__(16) float pfs[4][1056];
  __shared__ float wgb[192];
  __shared__ float kbs[12];
  int jg = jb * 256 + t;
  jsx[t] = ref_pos[jg * 3];
  jsy[t] = ref_pos[jg * 3 + 1];
  jsz[t] = ref_pos[jg * 3 + 2];
  jsu[t] = uid[jg];
  if (t >= 64) {
    int e = t - 64;
    if (e < 192) {
      int bq = e >> 6, k = (e >> 2) & 15, h = e & 3;
      wgb[e] = lnp_g[bq * 16 + k] * Wb[bq * 64 + k * 4 + h];
    }
  }
  if (t >= 48 && t < 60) {
    int e = t - 48, bq = e >> 2, h = e & 3;
    float a = 0.f;
#pragma unroll
    for (int cc = 0; cc < 16; cc++) a += lnp_b[bq * 16 + cc] * Wb[bq * 64 + cc * 4 + h];
    kbs[e] = a;
  }
  int w = t >> 6, l = t & 63;
  int c = l & 15, gr = l >> 4;
  float pix = ref_pos[i * 3], piy = ref_pos[i * 3 + 1], piz = ref_pos[i * 3 + 2];
  int ui = uid[i];
  float w0c = Wpo[c], w1c = Wpo[16 + c], w2c = Wpo[32 + c];
  float wic = Wisd[c], wmc = Wmask[c], cac = ca[i * 16 + c];
  s16x8 bw0 = {bf1(W1[(4 * gr + 0) * 16 + c]), bf1(W1[(4 * gr + 1) * 16 + c]),
               bf1(W1[(4 * gr + 2) * 16 + c]), bf1(W1[(4 * gr + 3) * 16 + c]),
               (short)0, (short)0, (short)0, (short)0};
  s16x8 bw1 = {bf1(W2[(4 * gr + 0) * 16 + c]), bf1(W2[(4 * gr + 1) * 16 + c]),
               bf1(W2[(4 * gr + 2) * 16 + c]), bf1(W2[(4 * gr + 3) * 16 + c]),
               (short)0, (short)0, (short)0, (short)0};
  s16x8 bw2 = {bf1(W3[(4 * gr + 0) * 16 + c]), bf1(W3[(4 * gr + 1) * 16 + c]),
               bf1(W3[(4 * gr + 2) * 16 + c]), bf1(W3[(4 * gr + 3) * 16 + c]),
               (short)0, (short)0, (short)0, (short)0};
  __syncthreads();
  char* sb = (char*)&stg[w][0];
  unsigned sbase = (unsigned)(uintptr_t)sb;
  f32x4 z4 = {0.f, 0.f, 0.f, 0.f};
#pragma unroll
  for (int g = 0; g < 4; g++) {
    float p0_, p1_, p2_, p3_;
    {
      int jl0 = w * 64 + g * 16 + 4 * gr;
#pragma unroll
      for (int r = 0; r < 4; r++) {
        int jloc = jl0 + r;
        int j = jb * 256 + jloc;
        float d0 = pix - jsx[jloc], d1 = piy - jsy[jloc], d2 = piz - jsz[jloc];
        float mk = (ui == jsu[jloc]) ? 1.f : 0.f;
        float inv = 1.f / (1.f + d0 * d0 + d1 * d1 + d2 * d2);
        float zv = zp[((long)((i & 255) << 8) + jloc) * 16 + c];
        float cbv = cb[j * 16 + c];
        float pv = mk * (d0 * w0c + d1 * w1c + d2 * w2c + inv * wic + wmc) + zv + cbv + cac;
        if (r == 0) p0_ = pv; else if (r == 1) p1_ = pv; else if (r == 2) p2_ = pv; else p3_ = pv;
      }
    }
    char* wp = sb + g * 640 + c * 32 + gr * 8;
    unsigned ra = sbase + (unsigned)(g * 640 + c * 8 + gr * 128);
    *(uint2*)wp = make_uint2(bfpack(fmaxf(p0_, 0.f), fmaxf(p1_, 0.f)),
                             bfpack(fmaxf(p2_, 0.f), fmaxf(p3_, 0.f)));
    s16x4 tr0;
    asm volatile("s_waitcnt lgkmcnt(0)\n\tds_read_b64_tr_b16 %0, %1\n\ts_waitcnt lgkmcnt(0)"
                 : "=v"(tr0) : "v"(ra) : "memory");
    s16x8 a8 = {tr0[0], tr0[1], tr0[2], tr0[3], (short)0, (short)0, (short)0, (short)0};
    f32x4 h1 = __builtin_amdgcn_mfma_f32_16x16x32_bf16(a8, bw0, z4, 0, 0, 0);
    *(uint2*)wp = make_uint2(bfpack(fmaxf(h1[0], 0.f), fmaxf(h1[1], 0.f)),
                             bfpack(fmaxf(h1[2], 0.f), fmaxf(h1[3], 0.f)));
    s16x4 tr1;
    asm volatile("s_waitcnt lgkmcnt(0)\n\tds_read_b64_tr_b16 %0, %1\n\ts_waitcnt lgkmcnt(0)"
                 : "=v"(tr1) : "v"(ra) : "memory");
    s16x8 a8b = {tr1[0], tr1[1], tr1[2], tr1[3], (short)0, (short)0, (short)0, (short)0};
    f32x4 h2 = __builtin_amdgcn_mfma_f32_16x16x32_bf16(a8b, bw1, z4, 0, 0, 0);
    *(uint2*)wp = make_uint2(bfpack(fmaxf(h2[0], 0.f), fmaxf(h2[1], 0.f)),
                             bfpack(fmaxf(h2[2], 0.f), fmaxf(h2[3], 0.f)));
    s16x4 tr2;
    asm volatile("s_waitcnt lgkmcnt(0)\n\tds_read_b64_tr_b16 %0, %1\n\ts_waitcnt lgkmcnt(0)"
                 : "=v"(tr2) : "v"(ra) : "memory");
    s16x8 a8c = {tr2[0], tr2[1], tr2[2], tr2[3], (short)0, (short)0, (short)0, (short)0};
    f32x4 h3 = __builtin_amdgcn_mfma_f32_16x16x32_bf16(a8c, bw2, z4, 0, 0, 0);
    float f0 = p0_ + h3[0], f1 = p1_ + h3[1], f2 = p2_ + h3[2], f3 = p3_ + h3[3];
    {
      int jl0 = w * 64 + g * 16 + 4 * gr;
      long pb = ((long)i * 768 + (long)(jb * 256 + jl0)) * 16 + c;
      pair_out[pb] = f0;
      pair_out[pb + 16] = f1;
      pair_out[pb + 32] = f2;
      pair_out[pb + 48] = f3;
    }
    *(float4*)&pfs[w][g * 264 + c * 16 + 4 * gr] = make_float4(f0, f1, f2, f3);
  }
  asm volatile("s_waitcnt lgkmcnt(0)" ::: "memory");
  int qb = i >> 5;
  int j = jb * 256 + t;
  unsigned jw = (unsigned)(j - (qb * 32 - 48));
  if (jw < 128u) {
    int gt = (t >> 4) & 3, jr = t & 15;
    float v[16];
#pragma unroll
    for (int cc = 0; cc < 16; cc++) v[cc] = pfs[w][gt * 264 + cc * 16 + jr];
    float m = 0.f;
#pragma unroll
    for (int cc = 0; cc < 16; cc++) m += v[cc];
    m *= (1.f / 16.f);
    float vv = 0.f;
#pragma unroll
    for (int cc = 0; cc < 16; cc++) { float d = v[cc] - m; vv += d * d; }
    float rs = rsqrtf(vv * (1.f / 16.f) + 1e-5f);
    float nrm[16];
#pragma unroll
    for (int cc = 0; cc < 16; cc++) nrm[cc] = (v[cc] - m) * rs;
    int qi = i & 31;
#pragma unroll
    for (int bq = 0; bq < 3; bq++) {
      float o0 = kbs[bq * 4 + 0], o1 = kbs[bq * 4 + 1];
      float o2 = kbs[bq * 4 + 2], o3 = kbs[bq * 4 + 3];
#pragma unroll
      for (int k = 0; k < 16; k++) {
        float nv = nrm[k];
        float4 wv = *(float4*)&wgb[bq * 64 + k * 4];
        o0 += nv * wv.x; o1 += nv * wv.y; o2 += nv * wv.z; o3 += nv * wv.w;
      }
      long base = (long)(bq * 96 + qb * 4) * 4096 + (long)qi * 128 + jw;
      biasA[base] = o0;
      biasA[base + 4096] = o1;
      biasA[base + 2 * 4096] = o2;
      biasA[base + 3 * 4096] = o3;
    }
  }
}

// ---------------------------------------------------------------------------
// k_qkvg: grid 384 (rb*8+bn), block 256
__global__ __launch_bounds__(256) void k_qkvg(
    const float* __restrict__ x, const float* __restrict__ lng,
    const float* __restrict__ lnb, const float* __restrict__ Wq,
    const float* __restrict__ Wk, const float* __restrict__ Wv,
    const float* __restrict__ Wg, float* __restrict__ qkvg) {
  __shared__ float As[128][18];
  __shared__ float Ws[128][66];
  int t = threadIdx.x;
  int rb = blockIdx.x >> 3, bn = blockIdx.x & 7;
  int r0 = rb * 16;
  const float* Wm = (bn < 2) ? Wq : (bn < 4) ? Wk : (bn < 6) ? Wv : Wg;
  int c0 = (bn & 1) * 64;
  int ncol0 = (bn >> 1) * 128 + c0;
#pragma unroll
  for (int m = 0; m < 8; m++) {
    int idx = t + 256 * m;
    int row = idx >> 4, c4 = (idx & 15) * 4;
    *(float4*)&Ws[row][c4] = *(const float4*)&Wm[row * 128 + c0 + c4];
  }
  {
    int rr = t >> 4, tt = t & 15;
    int row = r0 + rr;
    float4 x0 = *(const float4*)&x[row * 128 + tt * 8];
    float4 x1 = *(const float4*)&x[row * 128 + tt * 8 + 4];
    float ps = x0.x + x0.y + x0.z + x0.w + x1.x + x1.y + x1.z + x1.w;
    float pq = x0.x * x0.x + x0.y * x0.y + x0.z * x0.z + x0.w * x0.w +
               x1.x * x1.x + x1.y * x1.y + x1.z * x1.z + x1.w * x1.w;
#pragma unroll
    for (int o = 1; o < 16; o <<= 1) { ps += __shfl_xor(ps, o); pq += __shfl_xor(pq, o); }
    float m = ps * (1.f / 128.f);
    float rstd = rsqrtf(pq * (1.f / 128.f) - m * m + 1e-5f);
    float4 g0 = *(const float4*)&lng[tt * 8], g1 = *(const float4*)&lng[tt * 8 + 4];
    float4 b0 = *(const float4*)&lnb[tt * 8], b1 = *(const float4*)&lnb[tt * 8 + 4];
    As[tt * 8 + 0][rr] = (x0.x - m) * rstd * g0.x + b0.x;
    As[tt * 8 + 1][rr] = (x0.y - m) * rstd * g0.y + b0.y;
    As[tt * 8 + 2][rr] = (x0.z - m) * rstd * g0.z + b0.z;
    As[tt * 8 + 3][rr] = (x0.w - m) * rstd * g0.w + b0.w;
    As[tt * 8 + 4][rr] = (x1.x - m) * rstd * g1.x + b1.x;
    As[tt * 8 + 5][rr] = (x1.y - m) * rstd * g1.y + b1.y;
    As[tt * 8 + 6][rr] = (x1.z - m) * rstd * g1.z + b1.z;
    As[tt * 8 + 7][rr] = (x1.w - m) * rstd * g1.w + b1.w;
  }
  __syncthreads();
  int ty = t >> 5, tx = t & 31;
  float a00 = 0, a01 = 0, a10 = 0, a11 = 0;
#pragma unroll 8
  for (int k = 0; k < 128; k++) {
    float2 a2 = *(float2*)&As[k][ty * 2];
    float2 w2 = *(float2*)&Ws[k][tx * 2];
    a00 += a2.x * w2.x; a01 += a2.x * w2.y;
    a10 += a2.y * w2.x; a11 += a2.y * w2.y;
  }
  int row = r0 + ty * 2;
  float2 o0 = {a00, a01}, o1 = {a10, a11};
  *(float2*)&qkvg[row * 512 + ncol0 + tx * 2] = o0;
  *(float2*)&qkvg[(row + 1) * 512 + ncol0 + tx * 2] = o1;
}

// ---------------------------------------------------------------------------
// k_attn: grid 96, block 256
__global__ __launch_bounds__(256) void k_attn(
    const float* __restrict__ qkvg, const float* __restrict__ biasb,
    float* __restrict__ og) {
  int qb = blockIdx.x >> 2, h = blockIdx.x & 3, t = threadIdx.x;
  int i0 = qb * 32, lo = i0 - 48;
  __shared__ float qs[32][36];
  __shared__ float ks[128][36];
  __shared__ float vs[128][36];
  __shared__ float L[32][132];
#pragma unroll
  for (int m = 0; m < 4; m++) {
    int idx = t + 256 * m;
    int qi = idx >> 5, k4 = (idx & 31) * 4;
    int j = lo + k4;
    float4 bv;
    if (j >= 0 && j < 768) bv = *(const float4*)&biasb[(qb * 4 + h) * 4096 + qi * 128 + k4];
    else bv = make_float4(-1e30f, -1e30f, -1e30f, -1e30f);
    *(float4*)&L[qi][k4] = bv;
  }
  {
    int qi = t >> 3, dq = (t & 7) * 4;
    *(float4*)&qs[qi][dq] = *(const float4*)&qkvg[(i0 + qi) * 512 + h * 32 + dq];
  }
  {
    int kj = t >> 1, dh = (t & 1) * 16;
    int j = lo + kj;
    if (j >= 0 && j < 768) {
      const float4* sk = (const float4*)&qkvg[j * 512 + 128 + h * 32 + dh];
      const float4* sv = (const float4*)&qkvg[j * 512 + 256 + h * 32 + dh];
#pragma unroll
      for (int m = 0; m < 4; m++) {
        *(float4*)&ks[kj][dh + 4 * m] = sk[m];
        *(float4*)&vs[kj][dh + 4 * m] = sv[m];
      }
    } else {
      float4 zz = {0, 0, 0, 0};
#pragma unroll
      for (int m = 0; m < 4; m++) {
        *(float4*)&ks[kj][dh + 4 * m] = zz;
        *(float4*)&vs[kj][dh + 4 * m] = zz;
      }
    }
  }
  __syncthreads();
  const float scale = 0.17677669529663687f;
  {
    int qi = t & 31, kb = t >> 5;
    float4 qr[8];
#pragma unroll
    for (int m = 0; m < 8; m++) qr[m] = *(float4*)&qs[qi][m * 4];
#pragma unroll 2
    for (int kk = 0; kk < 16; kk++) {
      int kj = kb * 16 + kk;
      float acc = 0.f;
#pragma unroll
      for (int m = 0; m < 8; m++) {
        float4 kv = *(float4*)&ks[kj][m * 4];
        acc += qr[m].x * kv.x + qr[m].y * kv.y + qr[m].z * kv.z + qr[m].w * kv.w;
      }
      L[qi][kj] += acc * scale;
    }
  }
  __syncthreads();
  int qi = t >> 3, sg = t & 7;
  float mx = -1e30f;
#pragma unroll
  for (int k2 = 0; k2 < 16; k2++) mx = fmaxf(mx, L[qi][sg * 16 + k2]);
#pragma unroll
  for (int o = 1; o < 8; o <<= 1) mx = fmaxf(mx, __shfl_xor(mx, o));
  float sum = 0.f;
#pragma unroll
  for (int k2 = 0; k2 < 16; k2++) {
    int kj = sg * 16 + k2;
    float e = __expf(L[qi][kj] - mx);
    L[qi][kj] = e;
    sum += e;
  }
#pragma unroll
  for (int o = 1; o < 8; o <<= 1) sum += __shfl_xor(sum, o);
  float rden = 1.f / sum;
  __syncthreads();
  int d0 = (t & 7) * 4;
  float4 acc = {0, 0, 0, 0};
#pragma unroll 4
  for (int kj = 0; kj < 128; kj++) {
    float p = L[qi][kj];
    float4 v = *(const float4*)&vs[kj][d0];
    acc.x += p * v.x; acc.y += p * v.y; acc.z += p * v.z; acc.w += p * v.w;
  }
  int i = i0 + qi;
  float4 gr = *(const float4*)&qkvg[i * 512 + 384 + h * 32 + d0];
  float4 o4;
  o4.x = acc.x * rden * sigmoidf_(gr.x);
  o4.y = acc.y * rden * sigmoidf_(gr.y);
  o4.z = acc.z * rden * sigmoidf_(gr.z);
  o4.w = acc.w * rden * sigmoidf_(gr.w);
  *(float4*)&og[i * 128 + h * 32 + d0] = o4;
}

// ---------------------------------------------------------------------------
// k_fused: x += og@Wo; a=LN(x); x += relu(a@Wt1)@Wt2.
// grid 96 (8 rows), block 512 (8 waves). Register-prefetch double-buffered
// weight streaming; k-split in GEMM3.
__global__ __launch_bounds__(512) void k_fused(
    const float* __restrict__ og, const float* __restrict__ Wo,
    const float* __restrict__ g2, const float* __restrict__ b2,
    const float* __restrict__ Wt1, const float* __restrict__ Wt2,
    float* __restrict__ x) {
  int t = threadIdx.x;
  int r0 = blockIdx.x * 8;
  __shared__ float os[8][132];
  __shared__ float xn[8][132];
  __shared__ float a8[8][132];
  __shared__ float ht[8][520];
  __shared__ float wc[8192];
  float4 pf0, pf1, pf2, pf3;
  float4* wp = (float4*)wc;
#define SLOAD(PTR) { const float4* sp_ = (const float4*)(PTR); \
  pf0 = sp_[t]; pf1 = sp_[t + 512]; pf2 = sp_[t + 1024]; pf3 = sp_[t + 1536]; }
#define SWRITE() { wp[t] = pf0; wp[t + 512] = pf1; wp[t + 1024] = pf2; wp[t + 1536] = pf3; }
  SLOAD(Wo)
  {
    int rr = t >> 6, cc = (t & 63) * 2;
    *(float2*)&os[rr][cc] = *(const float2*)&og[(r0 + rr) * 128 + cc];
    *(float2*)&xn[rr][cc] = *(const float2*)&x[(r0 + rr) * 128 + cc];
  }
  __syncthreads();
  SWRITE()
  SLOAD(Wo + 8192)
  __syncthreads();
  // ---- GEMM1: xn += os @ Wo ----
  int c1 = t & 127, rq = t >> 7;
  float g1a = 0.f, g1b = 0.f;
#pragma unroll 4
  for (int k4 = 0; k4 < 64; k4 += 4) {
    float4 oA = *(float4*)&os[2 * rq][k4];
    float4 oB = *(float4*)&os[2 * rq + 1][k4];
    float w0 = wc[(k4 + 0) * 128 + c1], w1 = wc[(k4 + 1) * 128 + c1];
    float w2v = wc[(k4 + 2) * 128 + c1], w3 = wc[(k4 + 3) * 128 + c1];
    g1a += oA.x * w0 + oA.y * w1 + oA.z * w2v + oA.w * w3;
    g1b += oB.x * w0 + oB.y * w1 + oB.z * w2v + oB.w * w3;
  }
  __syncthreads();
  SWRITE()
  SLOAD(Wt1)
  __syncthreads();
#pragma unroll 4
  for (int k4 = 0; k4 < 64; k4 += 4) {
    float4 oA = *(float4*)&os[2 * rq][64 + k4];
    float4 oB = *(float4*)&os[2 * rq + 1][64 + k4];
    float w0 = wc[(k4 + 0) * 128 + c1], w1 = wc[(k4 + 1) * 128 + c1];
    float w2v = wc[(k4 + 2) * 128 + c1], w3 = wc[(k4 + 3) * 128 + c1];
    g1a += oA.x * w0 + oA.y * w1 + oA.z * w2v + oA.w * w3;
    g1b += oB.x * w0 + oB.y * w1 + oB.z * w2v + oB.w * w3;
  }
  xn[2 * rq][c1] += g1a;
  xn[2 * rq + 1][c1] += g1b;
  __syncthreads();
  // ---- LN ----
  {
    int wv = t >> 6, cc = (t & 63) * 2;
    float2 xv = *(float2*)&xn[wv][cc];
    float ps = xv.x + xv.y, pq = xv.x * xv.x + xv.y * xv.y;
#pragma unroll
    for (int o = 1; o < 64; o <<= 1) { ps += __shfl_xor(ps, o); pq += __shfl_xor(pq, o); }
    float m = ps * (1.f / 128.f);
    float rstd = rsqrtf(pq * (1.f / 128.f) - m * m + 1e-5f);
    float2 gg = *(const float2*)&g2[cc];
    float2 bb = *(const float2*)&b2[cc];
    float2 av;
    av.x = (xv.x - m) * rstd * gg.x + bb.x;
    av.y = (xv.y - m) * rstd * gg.y + bb.y;
    *(float2*)&a8[wv][cc] = av;
  }
  SWRITE()
  SLOAD(Wt1 + 8192)
  __syncthreads();
  // ---- GEMM2: ht = relu(a8 @ Wt1), 8 chunks of 16 k-rows ----
  int co2 = (t & 255) * 2, rh2 = t >> 8;
  float g2acc[8];
#pragma unroll
  for (int e = 0; e < 8; e++) g2acc[e] = 0.f;
#pragma unroll
  for (int mch = 0; mch < 8; mch++) {
    int k0 = mch * 16;
#pragma unroll 4
    for (int kk = 0; kk < 16; kk++) {
      float2 w2 = *(float2*)&wc[kk * 512 + co2];
      float av0 = a8[4 * rh2 + 0][k0 + kk];
      float av1 = a8[4 * rh2 + 1][k0 + kk];
      float av2 = a8[4 * rh2 + 2][k0 + kk];
      float av3 = a8[4 * rh2 + 3][k0 + kk];
      g2acc[0] += av0 * w2.x; g2acc[1] += av0 * w2.y;
      g2acc[2] += av1 * w2.x; g2acc[3] += av1 * w2.y;
      g2acc[4] += av2 * w2.x; g2acc[5] += av2 * w2.y;
      g2acc[6] += av3 * w2.x; g2acc[7] += av3 * w2.y;
    }
    __syncthreads();
    SWRITE()
    if (mch < 6) { SLOAD(Wt1 + (mch + 2) * 8192) }
    else if (mch == 6) { SLOAD(Wt2) }
    else { SLOAD(Wt2 + 8192) }
    __syncthreads();
  }
#pragma unroll
  for (int e = 0; e < 4; e++) {
    *(float2*)&ht[4 * rh2 + e][co2] =
        make_float2(fmaxf(g2acc[2 * e], 0.f), fmaxf(g2acc[2 * e + 1], 0.f));
  }
  __syncthreads();
  // ---- GEMM3: x = xn + ht @ Wt2, k-split across thread halves ----
  int c3 = t & 127, rh3 = (t >> 7) & 1, ksp = t >> 8;
  float g3[4] = {0.f, 0.f, 0.f, 0.f};
#pragma unroll
  for (int mch = 0; mch < 8; mch++) {
    int K0 = mch * 64;
    if (ksp == (mch & 1)) {
#pragma unroll 4
      for (int k4 = 0; k4 < 64; k4 += 4) {
        float w0 = wc[(k4 + 0) * 128 + c3], w1 = wc[(k4 + 1) * 128 + c3];
        float w2v = wc[(k4 + 2) * 128 + c3], w3 = wc[(k4 + 3) * 128 + c3];
        float4 h0 = *(float4*)&ht[4 * rh3 + 0][K0 + k4];
        float4 h1 = *(float4*)&ht[4 * rh3 + 1][K0 + k4];
        float4 h2 = *(float4*)&ht[4 * rh3 + 2][K0 + k4];
        float4 h3 = *(float4*)&ht[4 * rh3 + 3][K0 + k4];
        g3[0] += h0.x * w0 + h0.y * w1 + h0.z * w2v + h0.w * w3;
        g3[1] += h1.x * w0 + h1.y * w1 + h1.z * w2v + h1.w * w3;
        g3[2] += h2.x * w0 + h2.y * w1 + h2.z * w2v + h2.w * w3;
        g3[3] += h3.x * w0 + h3.y * w1 + h3.z * w2v + h3.w * w3;
      }
    }
    __syncthreads();
    if (mch < 7) {
      SWRITE()
      if (mch < 6) { SLOAD(Wt2 + (mch + 2) * 8192) }
      __syncthreads();
    }
  }
  if (ksp == 1) {
#pragma unroll
    for (int e = 0; e < 4; e++) a8[4 * rh3 + e][c3] = g3[e];
  }
  __syncthreads();
  if (ksp == 0) {
#pragma unroll
    for (int e = 0; e < 4; e++) {
      int rr = 4 * rh3 + e;
      x[(r0 + rr) * 128 + c3] = xn[rr][c3] + g3[e] + a8[rr][c3];
    }
  }
#undef SLOAD
#undef SWRITE
}

// ---------------------------------------------------------------------------
// k_final: grid 256, block 384
__global__ __launch_bounds__(384) void k_final(
    const float* __restrict__ x, const float* __restrict__ W_proj,
    float* __restrict__ out) {
  __shared__ float xs[384];
  int tk = blockIdx.x, t = threadIdx.x;
  xs[t] = x[tk * 384 + t];
  __syncthreads();
  float a0 = 0, a1 = 0, a2 = 0;
#pragma unroll 8
  for (int k = 0; k < 128; k++) {
    float w = W_proj[k * 384 + t];
    a0 += xs[k] * w; a1 += xs[128 + k] * w; a2 += xs[256 + k] * w;
  }
  a0 = fmaxf(a0, 0.f); a1 = fmaxf(a1, 0.f); a2 = fmaxf(a2, 0.f);
  out[98304 + (tk * 3 + 0) * 384 + t] = a0;
  out[98304 + (tk * 3 + 1) * 384 + t] = a1;
  out[98304 + (tk * 3 + 2) * 384 + t] = a2;
  out[tk * 384 + t] = (a0 + a1 + a2) * (1.f / 3.f);
}

// ---------------------------------------------------------------------------
extern "C" void kernel_launch(void* const* d_in, const int* in_sizes, int n_in,
                              void* d_out, int out_size, void* d_ws, size_t ws_size,
                              hipStream_t stream) {
  const float* ref_pos  = (const float*)d_in[0];
  const int*   uid      = (const int*)d_in[1];
  const float* r        = (const float*)d_in[2];
  const float* s        = (const float*)d_in[3];
  const float* z        = (const float*)d_in[4];
  const float* W_pos    = (const float*)d_in[5];
  const float* Wpo      = (const float*)d_in[6];
  const float* Wisd     = (const float*)d_in[7];
  const float* Wmask    = (const float*)d_in[8];
  const float* Wca      = (const float*)d_in[9];
  const float* Wcb      = (const float*)d_in[10];
  const float* ln_s_g   = (const float*)d_in[11];
  const float* ln_s_b   = (const float*)d_in[12];
  const float* W_single = (const float*)d_in[13];
  const float* ln_z_g   = (const float*)d_in[14];
  const float* ln_z_b   = (const float*)d_in[15];
  const float* W_pair   = (const float*)d_in[16];
  const float* W_noisy  = (const float*)d_in[17];
  const float* W_mlp1   = (const float*)d_in[18];
  const float* W_mlp2   = (const float*)d_in[19];
  const float* W_mlp3   = (const float*)d_in[20];
  const float* at_ln_g  = (const float*)d_in[21];
  const float* at_ln_b  = (const float*)d_in[22];
  const float* at_Wq    = (const float*)d_in[23];
  const float* at_Wk    = (const float*)d_in[24];
  const float* at_Wv    = (const float*)d_in[25];
  const float* at_Wg    = (const float*)d_in[26];
  const float* at_lnp_g = (const float*)d_in[27];
  const float* at_lnp_b = (const float*)d_in[28];
  const float* at_Wb    = (const float*)d_in[29];
  const float* at_Wo    = (const float*)d_in[30];
  const float* at_ln2_g = (const float*)d_in[31];
  const float* at_ln2_b = (const float*)d_in[32];
  const float* at_Wt1   = (const float*)d_in[33];
  const float* at_Wt2   = (const float*)d_in[34];
  const float* W_proj   = (const float*)d_in[35];
  float* out = (float*)d_out;
  float* W = (float*)d_ws;
  float* x     = W;                 //   98304
  float* ca    = W + 98304;         //   12288
  float* cb    = W + 110592;        //   12288
  float* zp    = W + 122880;        // 1048576
  float* biasA = W + 1171456;       // 1179648
  float* qkvg  = W + 2351104;       //  393216
  float* og    = W + 2744320;       //   98304

  k_zp<<<4096, 256, 0, stream>>>(z, ln_z_g, ln_z_b, W_pair, zp);
  k_tokatoms<<<256, 128, 0, stream>>>(s, ln_s_g, ln_s_b, W_single, ref_pos, r,
                                      W_pos, W_noisy, Wca, Wcb,
                                      out + 393216, x, ca, cb);
  k_pairM<<<2304, 256, 0, stream>>>(ref_pos, uid, Wpo, Wisd, Wmask, W_mlp1, W_mlp2,
                                    W_mlp3, zp, ca, cb, at_lnp_g, at_lnp_b, at_Wb,
                                    out + 491520, biasA);
  for (int b = 0; b < 3; b++) {
    k_qkvg<<<384, 256, 0, stream>>>(x, at_ln_g + b * 128, at_ln_b + b * 128,
                                    at_Wq + b * 16384, at_Wk + b * 16384,
                                    at_Wv + b * 16384, at_Wg + b * 16384, qkvg);
    k_attn<<<96, 256, 0, stream>>>(qkvg, biasA + b * 393216, og);
    k_fused<<<96, 512, 0, stream>>>(og, at_Wo + b * 16384, at_ln2_g + b * 128,
                                    at_ln2_b + b * 128, at_Wt1 + b * 65536,
                                    at_Wt2 + b * 65536, x);
  }
  k_final<<<256, 384, 0, stream>>>(x, W_proj, out);
}

// Round 10
// 188.213 us; speedup vs baseline: 1.7637x; 1.0491x over previous
//
#include <hip/hip_runtime.h>
#include <math.h>

// N=768 atoms, T=256 tokens, CA=128, CP=16, CZ=128, CS=384, CT=384, H=4, DH=32
// d_out: a_out[256*384]@0, qout[768*384]@98304, c[768*128]@393216, pair[768*768*16]@491520

__device__ __forceinline__ float sigmoidf_(float v) { return 1.f / (1.f + __expf(-v)); }

typedef __attribute__((ext_vector_type(4))) short s16x4;
typedef __attribute__((ext_vector_type(8))) short s16x8;
typedef __attribute__((ext_vector_type(4))) float f32x4;

__device__ __forceinline__ unsigned bfpack(float a, float b) {
  return (__float_as_uint(a) >> 16) | (__float_as_uint(b) & 0xFFFF0000u);
}
__device__ __forceinline__ short bf1(float a) { return (short)(__float_as_uint(a) >> 16); }

// ---------------------------------------------------------------------------
// k_tokatoms: grid 256, block 128
__global__ __launch_bounds__(128) void k_tokatoms(
    const float* __restrict__ s, const float* __restrict__ g,
    const float* __restrict__ b, const float* __restrict__ W_single,
    const float* __restrict__ ref_pos, const float* __restrict__ r,
    const float* __restrict__ W_pos, const float* __restrict__ W_noisy,
    const float* __restrict__ Wca, const float* __restrict__ Wcb,
    float* __restrict__ c_out, float* __restrict__ x,
    float* __restrict__ ca, float* __restrict__ cb) {
  int tok = blockIdx.x, t = threadIdx.x;
  __shared__ float sln[384];
  __shared__ float ws[48 * 128];
  __shared__ float red[4];
  __shared__ float rc[128];
  float v0 = s[tok * 384 + t], v1 = s[tok * 384 + 128 + t], v2 = s[tok * 384 + 256 + t];
  float ps = v0 + v1 + v2, pq = v0 * v0 + v1 * v1 + v2 * v2;
#pragma unroll
  for (int o = 1; o < 64; o <<= 1) { ps += __shfl_xor(ps, o); pq += __shfl_xor(pq, o); }
  if ((t & 63) == 0) { red[t >> 6] = ps; red[2 + (t >> 6)] = pq; }
  __syncthreads();
  float mean = (red[0] + red[1]) * (1.f / 384.f);
  float var = (red[2] + red[3]) * (1.f / 384.f) - mean * mean;
  float rstd = rsqrtf(var + 1e-5f);
  sln[t] = (v0 - mean) * rstd * g[t] + b[t];
  sln[128 + t] = (v1 - mean) * rstd * g[128 + t] + b[128 + t];
  sln[256 + t] = (v2 - mean) * rstd * g[256 + t] + b[256 + t];
  float ctv = 0.f;
  for (int c0 = 0; c0 < 384; c0 += 48) {
    __syncthreads();
#pragma unroll
    for (int m = 0; m < 12; m++) {
      int idx = (t + 128 * m) * 4;
      *(float4*)&ws[idx] = *(const float4*)&W_single[c0 * 128 + idx];
    }
    __syncthreads();
#pragma unroll 8
    for (int kk = 0; kk < 48; kk++) ctv += sln[c0 + kk] * ws[kk * 128 + t];
  }
  float wp0 = W_pos[t], wp1 = W_pos[128 + t], wp2 = W_pos[256 + t];
  float wn0 = W_noisy[t], wn1 = W_noisy[128 + t], wn2 = W_noisy[256 + t];
#pragma unroll
  for (int a = 0; a < 3; a++) {
    int i = tok + 256 * a;
    float p0 = ref_pos[i * 3], p1 = ref_pos[i * 3 + 1], p2 = ref_pos[i * 3 + 2];
    float r0 = r[i * 3], r1 = r[i * 3 + 1], r2 = r[i * 3 + 2];
    float c0 = p0 * wp0 + p1 * wp1 + p2 * wp2;
    x[i * 128 + t] = c0 + r0 * wn0 + r1 * wn1 + r2 * wn2;
    float cc = c0 + ctv;
    c_out[i * 128 + t] = cc;
    __syncthreads();
    rc[t] = fmaxf(cc, 0.f);
    __syncthreads();
    int out_id = t >> 2, q = t & 3;
    const float* Wm = (out_id < 16) ? Wca : Wcb;
    int ch = out_id & 15;
    float acc = 0.f;
#pragma unroll
    for (int kk = 0; kk < 32; kk++) { int k = q * 32 + kk; acc += rc[k] * Wm[k * 16 + ch]; }
    acc += __shfl_xor(acc, 1);
    acc += __shfl_xor(acc, 2);
    if (q == 0) { if (out_id < 16) ca[i * 16 + ch] = acc; else cb[i * 16 + ch] = acc; }
  }
}

// ---------------------------------------------------------------------------
// k_zp: zp[65536,16] = LN(z)@W_pair   grid 4096, block 256
__global__ __launch_bounds__(256) void k_zp(
    const float* __restrict__ z, const float* __restrict__ g,
    const float* __restrict__ lb, const float* __restrict__ W_pair,
    float* __restrict__ zp) {
  __shared__ float wT[16][132];
  __shared__ float zs[16][132];
  __shared__ float sWg[16], Bc[16];
  int t = threadIdx.x;
#pragma unroll
  for (int m = 0; m < 8; m++) {
    int e = t + 256 * m;
    int row = e >> 4, ch = e & 15;
    wT[ch][row] = g[row] * W_pair[e];
  }
  __syncthreads();
  if (t < 32) {
    int ch = t & 15;
    float a = 0.f;
    if (t < 16) {
#pragma unroll 8
      for (int k = 0; k < 128; k++) a += wT[ch][k];
      sWg[ch] = a;
    } else {
#pragma unroll 8
      for (int k = 0; k < 128; k++) a += lb[k] * W_pair[k * 16 + ch];
      Bc[ch] = a;
    }
  }
  int row = t >> 4, kk = (t & 15) * 8;
  long base = ((long)blockIdx.x * 16 + row) * 128 + kk;
  float4 a4 = *(const float4*)&z[base];
  float4 b4 = *(const float4*)&z[base + 4];
  *(float4*)&zs[row][kk] = a4;
  *(float4*)&zs[row][kk + 4] = b4;
  float ps = a4.x + a4.y + a4.z + a4.w + b4.x + b4.y + b4.z + b4.w;
  float pq = a4.x * a4.x + a4.y * a4.y + a4.z * a4.z + a4.w * a4.w +
             b4.x * b4.x + b4.y * b4.y + b4.z * b4.z + b4.w * b4.w;
#pragma unroll
  for (int o = 1; o < 16; o <<= 1) { ps += __shfl_xor(ps, o); pq += __shfl_xor(pq, o); }
  float m = ps * (1.f / 128.f);
  float rstd = rsqrtf(pq * (1.f / 128.f) - m * m + 1e-5f);
  __syncthreads();
  int ch = t & 15;
  float dotv = 0.f;
#pragma unroll 8
  for (int k4 = 0; k4 < 32; k4++) {
    float4 zv = *(float4*)&zs[row][k4 * 4];
    float4 wv = *(float4*)&wT[ch][k4 * 4];
    dotv += zv.x * wv.x + zv.y * wv.y + zv.z * wv.z + zv.w * wv.w;
  }
  zp[((long)blockIdx.x * 16 + row) * 16 + ch] = rstd * (dotv - m * sWg[ch]) + Bc[ch];
}

// ---------------------------------------------------------------------------
// k_pairM: pair + MFMA MLP + fused window bias.  grid 2304, block 256
__global__ __launch_bounds__(256) void k_pairM(
    const float* __restrict__ ref_pos, const int* __restrict__ uid,
    const float* __restrict__ Wpo, const float* __restrict__ Wisd,
    const float* __restrict__ Wmask, const float* __restrict__ W1,
    const float* __restrict__ W2, const float* __restrict__ W3,
    const float* __restrict__ zp, const float* __restrict__ ca,
    const float* __restrict__ cb, const float* __restrict__ lnp_g,
    const float* __restrict__ lnp_b, const float* __restrict__ Wb,
    float* __restrict__ pair_out, float* __restrict__ biasA) {
  int i = blockIdx.x / 3, jb = blockIdx.x % 3, t = threadIdx.x;
  __shared__ float jsx[256], jsy[256], jsz[256];
  __shared__ int jsu[256];
  __shared__ __align__(128) short stg[4][1280];
  __shared__ __align__(16) float pfs[4][1056];
  __shared__ float wgb[192];
  __shared__ float kbs[12];
  int jg = jb * 256 + t;
  jsx[t] = ref_pos[jg * 3];
  jsy[t] = ref_pos[jg * 3 + 1];
  jsz[t] = ref_pos[jg * 3 + 2];
  jsu[t] = uid[jg];
  if (t >= 64) {
    int e = t - 64;
    if (e < 192) {
      int bq = e >> 6, k = (e >> 2) & 15, h = e & 3;
      wgb[e] = lnp_g[bq * 16 + k] * Wb[bq * 64 + k * 4 + h];
    }
  }
  if (t >= 48 && t < 60) {
    int e = t - 48, bq = e >> 2, h = e & 3;
    float a = 0.f;
#pragma unroll
    for (int cc = 0; cc < 16; cc++) a += lnp_b[bq * 16 + cc] * Wb[bq * 64 + cc * 4 + h];
    kbs[e] = a;
  }
  int w = t >> 6, l = t & 63;
  int c = l & 15, gr = l >> 4;
  float pix = ref_pos[i * 3], piy = ref_pos[i * 3 + 1], piz = ref_pos[i * 3 + 2];
  int ui = uid[i];
  float w0c = Wpo[c], w1c = Wpo[16 + c], w2c = Wpo[32 + c];
  float wic = Wisd[c], wmc = Wmask[c], cac = ca[i * 16 + c];
  s16x8 bw0 = {bf1(W1[(4 * gr + 0) * 16 + c]), bf1(W1[(4 * gr + 1) * 16 + c]),
               bf1(W1[(4 * gr + 2) * 16 + c]), bf1(W1[(4 * gr + 3) * 16 + c]),
               (short)0, (short)0, (short)0, (short)0};
  s16x8 bw1 = {bf1(W2[(4 * gr + 0) * 16 + c]), bf1(W2[(4 * gr + 1) * 16 + c]),
               bf1(W2[(4 * gr + 2) * 16 + c]), bf1(W2[(4 * gr + 3) * 16 + c]),
               (short)0, (short)0, (short)0, (short)0};
  s16x8 bw2 = {bf1(W3[(4 * gr + 0) * 16 + c]), bf1(W3[(4 * gr + 1) * 16 + c]),
               bf1(W3[(4 * gr + 2) * 16 + c]), bf1(W3[(4 * gr + 3) * 16 + c]),
               (short)0, (short)0, (short)0, (short)0};
  __syncthreads();
  char* sb = (char*)&stg[w][0];
  unsigned sbase = (unsigned)(uintptr_t)sb;
  f32x4 z4 = {0.f, 0.f, 0.f, 0.f};
#pragma unroll
  for (int g = 0; g < 4; g++) {
    float p0_, p1_, p2_, p3_;
    {
      int jl0 = w * 64 + g * 16 + 4 * gr;
#pragma unroll
      for (int r = 0; r < 4; r++) {
        int jloc = jl0 + r;
        int j = jb * 256 + jloc;
        float d0 = pix - jsx[jloc], d1 = piy - jsy[jloc], d2 = piz - jsz[jloc];
        float mk = (ui == jsu[jloc]) ? 1.f : 0.f;
        float inv = 1.f / (1.f + d0 * d0 + d1 * d1 + d2 * d2);
        float zv = zp[((long)((i & 255) << 8) + jloc) * 16 + c];
        float cbv = cb[j * 16 + c];
        float pv = mk * (d0 * w0c + d1 * w1c + d2 * w2c + inv * wic + wmc) + zv + cbv + cac;
        if (r == 0) p0_ = pv; else if (r == 1) p1_ = pv; else if (r == 2) p2_ = pv; else p3_ = pv;
      }
    }
    char* wp = sb + g * 640 + c * 32 + gr * 8;
    unsigned ra = sbase + (unsigned)(g * 640 + c * 8 + gr * 128);
    *(uint2*)wp = make_uint2(bfpack(fmaxf(p0_, 0.f), fmaxf(p1_, 0.f)),
                             bfpack(fmaxf(p2_, 0.f), fmaxf(p3_, 0.f)));
    s16x4 tr0;
    asm volatile("s_waitcnt lgkmcnt(0)\n\tds_read_b64_tr_b16 %0, %1\n\ts_waitcnt lgkmcnt(0)"
                 : "=v"(tr0) : "v"(ra) : "memory");
    s16x8 a8 = {tr0[0], tr0[1], tr0[2], tr0[3], (short)0, (short)0, (short)0, (short)0};
    f32x4 h1 = __builtin_amdgcn_mfma_f32_16x16x32_bf16(a8, bw0, z4, 0, 0, 0);
    *(uint2*)wp = make_uint2(bfpack(fmaxf(h1[0], 0.f), fmaxf(h1[1], 0.f)),
                             bfpack(fmaxf(h1[2], 0.f), fmaxf(h1[3], 0.f)));
    s16x4 tr1;
    asm volatile("s_waitcnt lgkmcnt(0)\n\tds_read_b64_tr_b16 %0, %1\n\ts_waitcnt lgkmcnt(0)"
                 : "=v"(tr1) : "v"(ra) : "memory");
    s16x8 a8b = {tr1[0], tr1[1], tr1[2], tr1[3], (short)0, (short)0, (short)0, (short)0};
    f32x4 h2 = __builtin_amdgcn_mfma_f32_16x16x32_bf16(a8b, bw1, z4, 0, 0, 0);
    *(uint2*)wp = make_uint2(bfpack(fmaxf(h2[0], 0.f), fmaxf(h2[1], 0.f)),
                             bfpack(fmaxf(h2[2], 0.f), fmaxf(h2[3], 0.f)));
    s16x4 tr2;
    asm volatile("s_waitcnt lgkmcnt(0)\n\tds_read_b64_tr_b16 %0, %1\n\ts_waitcnt lgkmcnt(0)"
                 : "=v"(tr2) : "v"(ra) : "memory");
    s16x8 a8c = {tr2[0], tr2[1], tr2[2], tr2[3], (short)0, (short)0, (short)0, (short)0};
    f32x4 h3 = __builtin_amdgcn_mfma_f32_16x16x32_bf16(a8c, bw2, z4, 0, 0, 0);
    float f0 = p0_ + h3[0], f1 = p1_ + h3[1], f2 = p2_ + h3[2], f3 = p3_ + h3[3];
    {
      int jl0 = w * 64 + g * 16 + 4 * gr;
      long pb = ((long)i * 768 + (long)(jb * 256 + jl0)) * 16 + c;
      pair_out[pb] = f0;
      pair_out[pb + 16] = f1;
      pair_out[pb + 32] = f2;
      pair_out[pb + 48] = f3;
    }
    *(float4*)&pfs[w][g * 264 + c * 16 + 4 * gr] = make_float4(f0, f1, f2, f3);
  }
  asm volatile("s_waitcnt lgkmcnt(0)" ::: "memory");
  int qb = i >> 5;
  int j = jb * 256 + t;
  unsigned jw = (unsigned)(j - (qb * 32 - 48));
  if (jw < 128u) {
    int gt = (t >> 4) & 3, jr = t & 15;
    float v[16];
#pragma unroll
    for (int cc = 0; cc < 16; cc++) v[cc] = pfs[w][gt * 264 + cc * 16 + jr];
    float m = 0.f;
#pragma unroll
    for (int cc = 0; cc < 16; cc++) m += v[cc];
    m *= (1.f / 16.f);
    float vv = 0.f;
#pragma unroll
    for (int cc = 0; cc < 16; cc++) { float d = v[cc] - m; vv += d * d; }
    float rs = rsqrtf(vv * (1.f / 16.f) + 1e-5f);
    float nrm[16];
#pragma unroll
    for (int cc = 0; cc < 16; cc++) nrm[cc] = (v[cc] - m) * rs;
    int qi = i & 31;
#pragma unroll
    for (int bq = 0; bq < 3; bq++) {
      float o0 = kbs[bq * 4 + 0], o1 = kbs[bq * 4 + 1];
      float o2 = kbs[bq * 4 + 2], o3 = kbs[bq * 4 + 3];
#pragma unroll
      for (int k = 0; k < 16; k++) {
        float nv = nrm[k];
        float4 wv = *(float4*)&wgb[bq * 64 + k * 4];
        o0 += nv * wv.x; o1 += nv * wv.y; o2 += nv * wv.z; o3 += nv * wv.w;
      }
      long base = (long)(bq * 96 + qb * 4) * 4096 + (long)qi * 128 + jw;
      biasA[base] = o0;
      biasA[base + 4096] = o1;
      biasA[base + 2 * 4096] = o2;
      biasA[base + 3 * 4096] = o3;
    }
  }
}

// ---------------------------------------------------------------------------
// k_qkvg: grid 384 (rb*8+bn), block 256
__global__ __launch_bounds__(256) void k_qkvg(
    const float* __restrict__ x, const float* __restrict__ lng,
    const float* __restrict__ lnb, const float* __restrict__ Wq,
    const float* __restrict__ Wk, const float* __restrict__ Wv,
    const float* __restrict__ Wg, float* __restrict__ qkvg) {
  __shared__ float As[128][18];
  __shared__ float Ws[128][66];
  int t = threadIdx.x;
  int rb = blockIdx.x >> 3, bn = blockIdx.x & 7;
  int r0 = rb * 16;
  const float* Wm = (bn < 2) ? Wq : (bn < 4) ? Wk : (bn < 6) ? Wv : Wg;
  int c0 = (bn & 1) * 64;
  int ncol0 = (bn >> 1) * 128 + c0;
#pragma unroll
  for (int m = 0; m < 8; m++) {
    int idx = t + 256 * m;
    int row = idx >> 4, c4 = (idx & 15) * 4;
    *(float4*)&Ws[row][c4] = *(const float4*)&Wm[row * 128 + c0 + c4];
  }
  {
    int rr = t >> 4, tt = t & 15;
    int row = r0 + rr;
    float4 x0 = *(const float4*)&x[row * 128 + tt * 8];
    float4 x1 = *(const float4*)&x[row * 128 + tt * 8 + 4];
    float ps = x0.x + x0.y + x0.z + x0.w + x1.x + x1.y + x1.z + x1.w;
    float pq = x0.x * x0.x + x0.y * x0.y + x0.z * x0.z + x0.w * x0.w +
               x1.x * x1.x + x1.y * x1.y + x1.z * x1.z + x1.w * x1.w;
#pragma unroll
    for (int o = 1; o < 16; o <<= 1) { ps += __shfl_xor(ps, o); pq += __shfl_xor(pq, o); }
    float m = ps * (1.f / 128.f);
    float rstd = rsqrtf(pq * (1.f / 128.f) - m * m + 1e-5f);
    float4 g0 = *(const float4*)&lng[tt * 8], g1 = *(const float4*)&lng[tt * 8 + 4];
    float4 b0 = *(const float4*)&lnb[tt * 8], b1 = *(const float4*)&lnb[tt * 8 + 4];
    As[tt * 8 + 0][rr] = (x0.x - m) * rstd * g0.x + b0.x;
    As[tt * 8 + 1][rr] = (x0.y - m) * rstd * g0.y + b0.y;
    As[tt * 8 + 2][rr] = (x0.z - m) * rstd * g0.z + b0.z;
    As[tt * 8 + 3][rr] = (x0.w - m) * rstd * g0.w + b0.w;
    As[tt * 8 + 4][rr] = (x1.x - m) * rstd * g1.x + b1.x;
    As[tt * 8 + 5][rr] = (x1.y - m) * rstd * g1.y + b1.y;
    As[tt * 8 + 6][rr] = (x1.z - m) * rstd * g1.z + b1.z;
    As[tt * 8 + 7][rr] = (x1.w - m) * rstd * g1.w + b1.w;
  }
  __syncthreads();
  int ty = t >> 5, tx = t & 31;
  float a00 = 0, a01 = 0, a10 = 0, a11 = 0;
#pragma unroll 8
  for (int k = 0; k < 128; k++) {
    float2 a2 = *(float2*)&As[k][ty * 2];
    float2 w2 = *(float2*)&Ws[k][tx * 2];
    a00 += a2.x * w2.x; a01 += a2.x * w2.y;
    a10 += a2.y * w2.x; a11 += a2.y * w2.y;
  }
  int row = r0 + ty * 2;
  float2 o0 = {a00, a01}, o1 = {a10, a11};
  *(float2*)&qkvg[row * 512 + ncol0 + tx * 2] = o0;
  *(float2*)&qkvg[(row + 1) * 512 + ncol0 + tx * 2] = o1;
}

// ---------------------------------------------------------------------------
// k_attn: grid 96, block 256
__global__ __launch_bounds__(256) void k_attn(
    const float* __restrict__ qkvg, const float* __restrict__ biasb,
    float* __restrict__ og) {
  int qb = blockIdx.x >> 2, h = blockIdx.x & 3, t = threadIdx.x;
  int i0 = qb * 32, lo = i0 - 48;
  __shared__ float qs[32][36];
  __shared__ float ks[128][36];
  __shared__ float vs[128][36];
  __shared__ float L[32][132];
#pragma unroll
  for (int m = 0; m < 4; m++) {
    int idx = t + 256 * m;
    int qi = idx >> 5, k4 = (idx & 31) * 4;
    int j = lo + k4;
    float4 bv;
    if (j >= 0 && j < 768) bv = *(const float4*)&biasb[(qb * 4 + h) * 4096 + qi * 128 + k4];
    else bv = make_float4(-1e30f, -1e30f, -1e30f, -1e30f);
    *(float4*)&L[qi][k4] = bv;
  }
  {
    int qi = t >> 3, dq = (t & 7) * 4;
    *(float4*)&qs[qi][dq] = *(const float4*)&qkvg[(i0 + qi) * 512 + h * 32 + dq];
  }
  {
    int kj = t >> 1, dh = (t & 1) * 16;
    int j = lo + kj;
    if (j >= 0 && j < 768) {
      const float4* sk = (const float4*)&qkvg[j * 512 + 128 + h * 32 + dh];
      const float4* sv = (const float4*)&qkvg[j * 512 + 256 + h * 32 + dh];
#pragma unroll
      for (int m = 0; m < 4; m++) {
        *(float4*)&ks[kj][dh + 4 * m] = sk[m];
        *(float4*)&vs[kj][dh + 4 * m] = sv[m];
      }
    } else {
      float4 zz = {0, 0, 0, 0};
#pragma unroll
      for (int m = 0; m < 4; m++) {
        *(float4*)&ks[kj][dh + 4 * m] = zz;
        *(float4*)&vs[kj][dh + 4 * m] = zz;
      }
    }
  }
  __syncthreads();
  const float scale = 0.17677669529663687f;
  {
    int qi = t & 31, kb = t >> 5;
    float4 qr[8];
#pragma unroll
    for (int m = 0; m < 8; m++) qr[m] = *(float4*)&qs[qi][m * 4];
#pragma unroll 2
    for (int kk = 0; kk < 16; kk++) {
      int kj = kb * 16 + kk;
      float acc = 0.f;
#pragma unroll
      for (int m = 0; m < 8; m++) {
        float4 kv = *(float4*)&ks[kj][m * 4];
        acc += qr[m].x * kv.x + qr[m].y * kv.y + qr[m].z * kv.z + qr[m].w * kv.w;
      }
      L[qi][kj] += acc * scale;
    }
  }
  __syncthreads();
  int qi = t >> 3, sg = t & 7;
  float mx = -1e30f;
#pragma unroll
  for (int k2 = 0; k2 < 16; k2++) mx = fmaxf(mx, L[qi][sg * 16 + k2]);
#pragma unroll
  for (int o = 1; o < 8; o <<= 1) mx = fmaxf(mx, __shfl_xor(mx, o));
  float sum = 0.f;
#pragma unroll
  for (int k2 = 0; k2 < 16; k2++) {
    int kj = sg * 16 + k2;
    float e = __expf(L[qi][kj] - mx);
    L[qi][kj] = e;
    sum += e;
  }
#pragma unroll
  for (int o = 1; o < 8; o <<= 1) sum += __shfl_xor(sum, o);
  float rden = 1.f / sum;
  __syncthreads();
  int d0 = (t & 7) * 4;
  float4 acc = {0, 0, 0, 0};
#pragma unroll 4
  for (int kj = 0; kj < 128; kj++) {
    float p = L[qi][kj];
    float4 v = *(const float4*)&vs[kj][d0];
    acc.x += p * v.x; acc.y += p * v.y; acc.z += p * v.z; acc.w += p * v.w;
  }
  int i = i0 + qi;
  float4 gr = *(const float4*)&qkvg[i * 512 + 384 + h * 32 + d0];
  float4 o4;
  o4.x = acc.x * rden * sigmoidf_(gr.x);
  o4.y = acc.y * rden * sigmoidf_(gr.y);
  o4.z = acc.z * rden * sigmoidf_(gr.z);
  o4.w = acc.w * rden * sigmoidf_(gr.w);
  *(float4*)&og[i * 128 + h * 32 + d0] = o4;
}

// ---------------------------------------------------------------------------
// k_fused3: x += og@Wo; a=LN(x); x += relu(a@Wt1)@Wt2.
// grid 384 (2 rows/block), block 256. Weights direct from global (L2-resident),
// activations in small LDS (broadcast reads). Only ~6 barriers.
__global__ __launch_bounds__(256) void k_fused3(
    const float* __restrict__ og, const float* __restrict__ Wo,
    const float* __restrict__ g2, const float* __restrict__ b2,
    const float* __restrict__ Wt1, const float* __restrict__ Wt2,
    float* __restrict__ x) {
  int t = threadIdx.x;
  int r0 = blockIdx.x * 2;
  __shared__ float osr[2][128];
  __shared__ float xns[2][128];
  __shared__ float asr[2][128];
  __shared__ float hs[2][512];
  __shared__ float part[2][4][128];
  __shared__ float red[8];
  int row = t >> 7, c = t & 127;
  osr[row][c] = og[(r0 + row) * 128 + c];
  xns[row][c] = x[(r0 + row) * 128 + c];
  __syncthreads();
  // ---- GEMM1: acc1 = sum_k osr[row][k] * Wo[k*128+c] ----
  float acc1 = 0.f;
#pragma unroll 8
  for (int k = 0; k < 128; k++) acc1 += osr[row][k] * Wo[k * 128 + c];
  float xv = xns[row][c] + acc1;
  // ---- LN over row (128 threads = 2 waves per row) ----
  {
    float ps = xv, pq = xv * xv;
#pragma unroll
    for (int o = 1; o < 64; o <<= 1) { ps += __shfl_xor(ps, o); pq += __shfl_xor(pq, o); }
    int wv = t >> 6;
    if ((t & 63) == 0) { red[wv] = ps; red[4 + wv] = pq; }
    __syncthreads();
    float mean = (red[2 * row] + red[2 * row + 1]) * (1.f / 128.f);
    float var = (red[4 + 2 * row] + red[4 + 2 * row + 1]) * (1.f / 128.f) - mean * mean;
    float rstd = rsqrtf(var + 1e-5f);
    xns[row][c] = xv;
    asr[row][c] = (xv - mean) * rstd * g2[c] + b2[c];
  }
  __syncthreads();
  // ---- GEMM2: hs[row][512] = relu(asr[row] @ Wt1) ; 4 cols/thread ----
  {
    int c4 = (t & 127) * 4, row2 = t >> 7;
    float a0 = 0.f, a1 = 0.f, a2 = 0.f, a3 = 0.f;
#pragma unroll 8
    for (int k = 0; k < 128; k++) {
      float4 w = *(const float4*)&Wt1[k * 512 + c4];
      float av = asr[row2][k];
      a0 += av * w.x; a1 += av * w.y; a2 += av * w.z; a3 += av * w.w;
    }
    *(float4*)&hs[row2][c4] = make_float4(fmaxf(a0, 0.f), fmaxf(a1, 0.f),
                                          fmaxf(a2, 0.f), fmaxf(a3, 0.f));
  }
  __syncthreads();
  // ---- GEMM3: 4-way k-split; thread: row3 = t>>7, q3 = (t>>5)&3, 4 cols ----
  {
    int row3 = t >> 7, q3 = (t >> 5) & 3, c4 = (t & 31) * 4;
    float a0 = 0.f, a1 = 0.f, a2 = 0.f, a3 = 0.f;
    int k0 = q3 * 128;
#pragma unroll 8
    for (int kk = 0; kk < 128; kk++) {
      int k = k0 + kk;
      float4 w = *(const float4*)&Wt2[k * 128 + c4];
      float hv = hs[row3][k];
      a0 += hv * w.x; a1 += hv * w.y; a2 += hv * w.z; a3 += hv * w.w;
    }
    *(float4*)&part[row3][q3][c4] = make_float4(a0, a1, a2, a3);
  }
  __syncthreads();
  x[(r0 + row) * 128 + c] = xns[row][c] + part[row][0][c] + part[row][1][c] +
                            part[row][2][c] + part[row][3][c];
}

// ---------------------------------------------------------------------------
// k_final: grid 256, block 384
__global__ __launch_bounds__(384) void k_final(
    const float* __restrict__ x, const float* __restrict__ W_proj,
    float* __restrict__ out) {
  __shared__ float xs[384];
  int tk = blockIdx.x, t = threadIdx.x;
  xs[t] = x[tk * 384 + t];
  __syncthreads();
  float a0 = 0, a1 = 0, a2 = 0;
#pragma unroll 8
  for (int k = 0; k < 128; k++) {
    float w = W_proj[k * 384 + t];
    a0 += xs[k] * w; a1 += xs[128 + k] * w; a2 += xs[256 + k] * w;
  }
  a0 = fmaxf(a0, 0.f); a1 = fmaxf(a1, 0.f); a2 = fmaxf(a2, 0.f);
  out[98304 + (tk * 3 + 0) * 384 + t] = a0;
  out[98304 + (tk * 3 + 1) * 384 + t] = a1;
  out[98304 + (tk * 3 + 2) * 384 + t] = a2;
  out[tk * 384 + t] = (a0 + a1 + a2) * (1.f / 3.f);
}

// ---------------------------------------------------------------------------
extern "C" void kernel_launch(void* const* d_in, const int* in_sizes, int n_in,
                              void* d_out, int out_size, void* d_ws, size_t ws_size,
                              hipStream_t stream) {
  const float* ref_pos  = (const float*)d_in[0];
  const int*   uid      = (const int*)d_in[1];
  const float* r        = (const float*)d_in[2];
  const float* s        = (const float*)d_in[3];
  const float* z        = (const float*)d_in[4];
  const float* W_pos    = (const float*)d_in[5];
  const float* Wpo      = (const float*)d_in[6];
  const float* Wisd     = (const float*)d_in[7];
  const float* Wmask    = (const float*)d_in[8];
  const float* Wca      = (const float*)d_in[9];
  const float* Wcb      = (const float*)d_in[10];
  const float* ln_s_g   = (const float*)d_in[11];
  const float* ln_s_b   = (const float*)d_in[12];
  const float* W_single = (const float*)d_in[13];
  const float* ln_z_g   = (const float*)d_in[14];
  const float* ln_z_b   = (const float*)d_in[15];
  const float* W_pair   = (const float*)d_in[16];
  const float* W_noisy  = (const float*)d_in[17];
  const float* W_mlp1   = (const float*)d_in[18];
  const float* W_mlp2   = (const float*)d_in[19];
  const float* W_mlp3   = (const float*)d_in[20];
  const float* at_ln_g  = (const float*)d_in[21];
  const float* at_ln_b  = (const float*)d_in[22];
  const float* at_Wq    = (const float*)d_in[23];
  const float* at_Wk    = (const float*)d_in[24];
  const float* at_Wv    = (const float*)d_in[25];
  const float* at_Wg    = (const float*)d_in[26];
  const float* at_lnp_g = (const float*)d_in[27];
  const float* at_lnp_b = (const float*)d_in[28];
  const float* at_Wb    = (const float*)d_in[29];
  const float* at_Wo    = (const float*)d_in[30];
  const float* at_ln2_g = (const float*)d_in[31];
  const float* at_ln2_b = (const float*)d_in[32];
  const float* at_Wt1   = (const float*)d_in[33];
  const float* at_Wt2   = (const float*)d_in[34];
  const float* W_proj   = (const float*)d_in[35];
  float* out = (float*)d_out;
  float* W = (float*)d_ws;
  float* x     = W;                 //   98304
  float* ca    = W + 98304;         //   12288
  float* cb    = W + 110592;        //   12288
  float* zp    = W + 122880;        // 1048576
  float* biasA = W + 1171456;       // 1179648
  float* qkvg  = W + 2351104;       //  393216
  float* og    = W + 2744320;       //   98304

  k_zp<<<4096, 256, 0, stream>>>(z, ln_z_g, ln_z_b, W_pair, zp);
  k_tokatoms<<<256, 128, 0, stream>>>(s, ln_s_g, ln_s_b, W_single, ref_pos, r,
                                      W_pos, W_noisy, Wca, Wcb,
                                      out + 393216, x, ca, cb);
  k_pairM<<<2304, 256, 0, stream>>>(ref_pos, uid, Wpo, Wisd, Wmask, W_mlp1, W_mlp2,
                                    W_mlp3, zp, ca, cb, at_lnp_g, at_lnp_b, at_Wb,
                                    out + 491520, biasA);
  for (int b = 0; b < 3; b++) {
    k_qkvg<<<384, 256, 0, stream>>>(x, at_ln_g + b * 128, at_ln_b + b * 128,
                                    at_Wq + b * 16384, at_Wk + b * 16384,
                                    at_Wv + b * 16384, at_Wg + b * 16384, qkvg);
    k_attn<<<96, 256, 0, stream>>>(qkvg, biasA + b * 393216, og);
    k_fused3<<<384, 256, 0, stream>>>(og, at_Wo + b * 16384, at_ln2_g + b * 128,
                                      at_ln2_b + b * 128, at_Wt1 + b * 65536,
                                      at_Wt2 + b * 65536, x);
  }
  k_final<<<256, 384, 0, stream>>>(x, W_proj, out);
}

// Round 11
// 171.783 us; speedup vs baseline: 1.9324x; 1.0956x over previous
//
#include <hip/hip_runtime.h>
#include <math.h>

// N=768 atoms, T=256 tokens, CA=128, CP=16, CZ=128, CS=384, CT=384, H=4, DH=32
// d_out: a_out[256*384]@0, qout[768*384]@98304, c[768*128]@393216, pair[768*768*16]@491520

__device__ __forceinline__ float sigmoidf_(float v) { return 1.f / (1.f + __expf(-v)); }

typedef __attribute__((ext_vector_type(4))) short s16x4;
typedef __attribute__((ext_vector_type(8))) short s16x8;
typedef __attribute__((ext_vector_type(4))) float f32x4;

__device__ __forceinline__ unsigned bfpack(float a, float b) {
  return (__float_as_uint(a) >> 16) | (__float_as_uint(b) & 0xFFFF0000u);
}
__device__ __forceinline__ short bf1(float a) { return (short)(__float_as_uint(a) >> 16); }

// ---------------------------------------------------------------------------
// k_tokatoms: grid 256, block 128
__global__ __launch_bounds__(128) void k_tokatoms(
    const float* __restrict__ s, const float* __restrict__ g,
    const float* __restrict__ b, const float* __restrict__ W_single,
    const float* __restrict__ ref_pos, const float* __restrict__ r,
    const float* __restrict__ W_pos, const float* __restrict__ W_noisy,
    const float* __restrict__ Wca, const float* __restrict__ Wcb,
    float* __restrict__ c_out, float* __restrict__ x,
    float* __restrict__ ca, float* __restrict__ cb) {
  int tok = blockIdx.x, t = threadIdx.x;
  __shared__ float sln[384];
  __shared__ float ws[48 * 128];
  __shared__ float red[4];
  __shared__ float rc[128];
  float v0 = s[tok * 384 + t], v1 = s[tok * 384 + 128 + t], v2 = s[tok * 384 + 256 + t];
  float ps = v0 + v1 + v2, pq = v0 * v0 + v1 * v1 + v2 * v2;
#pragma unroll
  for (int o = 1; o < 64; o <<= 1) { ps += __shfl_xor(ps, o); pq += __shfl_xor(pq, o); }
  if ((t & 63) == 0) { red[t >> 6] = ps; red[2 + (t >> 6)] = pq; }
  __syncthreads();
  float mean = (red[0] + red[1]) * (1.f / 384.f);
  float var = (red[2] + red[3]) * (1.f / 384.f) - mean * mean;
  float rstd = rsqrtf(var + 1e-5f);
  sln[t] = (v0 - mean) * rstd * g[t] + b[t];
  sln[128 + t] = (v1 - mean) * rstd * g[128 + t] + b[128 + t];
  sln[256 + t] = (v2 - mean) * rstd * g[256 + t] + b[256 + t];
  float ctv = 0.f;
  for (int c0 = 0; c0 < 384; c0 += 48) {
    __syncthreads();
#pragma unroll
    for (int m = 0; m < 12; m++) {
      int idx = (t + 128 * m) * 4;
      *(float4*)&ws[idx] = *(const float4*)&W_single[c0 * 128 + idx];
    }
    __syncthreads();
#pragma unroll 8
    for (int kk = 0; kk < 48; kk++) ctv += sln[c0 + kk] * ws[kk * 128 + t];
  }
  float wp0 = W_pos[t], wp1 = W_pos[128 + t], wp2 = W_pos[256 + t];
  float wn0 = W_noisy[t], wn1 = W_noisy[128 + t], wn2 = W_noisy[256 + t];
#pragma unroll
  for (int a = 0; a < 3; a++) {
    int i = tok + 256 * a;
    float p0 = ref_pos[i * 3], p1 = ref_pos[i * 3 + 1], p2 = ref_pos[i * 3 + 2];
    float r0 = r[i * 3], r1 = r[i * 3 + 1], r2 = r[i * 3 + 2];
    float c0 = p0 * wp0 + p1 * wp1 + p2 * wp2;
    x[i * 128 + t] = c0 + r0 * wn0 + r1 * wn1 + r2 * wn2;
    float cc = c0 + ctv;
    c_out[i * 128 + t] = cc;
    __syncthreads();
    rc[t] = fmaxf(cc, 0.f);
    __syncthreads();
    int out_id = t >> 2, q = t & 3;
    const float* Wm = (out_id < 16) ? Wca : Wcb;
    int ch = out_id & 15;
    float acc = 0.f;
#pragma unroll
    for (int kk = 0; kk < 32; kk++) { int k = q * 32 + kk; acc += rc[k] * Wm[k * 16 + ch]; }
    acc += __shfl_xor(acc, 1);
    acc += __shfl_xor(acc, 2);
    if (q == 0) { if (out_id < 16) ca[i * 16 + ch] = acc; else cb[i * 16 + ch] = acc; }
  }
}

// ---------------------------------------------------------------------------
// k_zp: zp[65536,16] = LN(z)@W_pair   grid 4096, block 256
__global__ __launch_bounds__(256) void k_zp(
    const float* __restrict__ z, const float* __restrict__ g,
    const float* __restrict__ lb, const float* __restrict__ W_pair,
    float* __restrict__ zp) {
  __shared__ float wT[16][132];
  __shared__ float zs[16][132];
  __shared__ float sWg[16], Bc[16];
  int t = threadIdx.x;
#pragma unroll
  for (int m = 0; m < 8; m++) {
    int e = t + 256 * m;
    int row = e >> 4, ch = e & 15;
    wT[ch][row] = g[row] * W_pair[e];
  }
  __syncthreads();
  if (t < 32) {
    int ch = t & 15;
    float a = 0.f;
    if (t < 16) {
#pragma unroll 8
      for (int k = 0; k < 128; k++) a += wT[ch][k];
      sWg[ch] = a;
    } else {
#pragma unroll 8
      for (int k = 0; k < 128; k++) a += lb[k] * W_pair[k * 16 + ch];
      Bc[ch] = a;
    }
  }
  int row = t >> 4, kk = (t & 15) * 8;
  long base = ((long)blockIdx.x * 16 + row) * 128 + kk;
  float4 a4 = *(const float4*)&z[base];
  float4 b4 = *(const float4*)&z[base + 4];
  *(float4*)&zs[row][kk] = a4;
  *(float4*)&zs[row][kk + 4] = b4;
  float ps = a4.x + a4.y + a4.z + a4.w + b4.x + b4.y + b4.z + b4.w;
  float pq = a4.x * a4.x + a4.y * a4.y + a4.z * a4.z + a4.w * a4.w +
             b4.x * b4.x + b4.y * b4.y + b4.z * b4.z + b4.w * b4.w;
#pragma unroll
  for (int o = 1; o < 16; o <<= 1) { ps += __shfl_xor(ps, o); pq += __shfl_xor(pq, o); }
  float m = ps * (1.f / 128.f);
  float rstd = rsqrtf(pq * (1.f / 128.f) - m * m + 1e-5f);
  __syncthreads();
  int ch = t & 15;
  float dotv = 0.f;
#pragma unroll 8
  for (int k4 = 0; k4 < 32; k4++) {
    float4 zv = *(float4*)&zs[row][k4 * 4];
    float4 wv = *(float4*)&wT[ch][k4 * 4];
    dotv += zv.x * wv.x + zv.y * wv.y + zv.z * wv.z + zv.w * wv.w;
  }
  zp[((long)blockIdx.x * 16 + row) * 16 + ch] = rstd * (dotv - m * sWg[ch]) + Bc[ch];
}

// ---------------------------------------------------------------------------
// k_pairM: pair + MFMA MLP + fused window bias.  grid 2304, block 256
__global__ __launch_bounds__(256) void k_pairM(
    const float* __restrict__ ref_pos, const int* __restrict__ uid,
    const float* __restrict__ Wpo, const float* __restrict__ Wisd,
    const float* __restrict__ Wmask, const float* __restrict__ W1,
    const float* __restrict__ W2, const float* __restrict__ W3,
    const float* __restrict__ zp, const float* __restrict__ ca,
    const float* __restrict__ cb, const float* __restrict__ lnp_g,
    const float* __restrict__ lnp_b, const float* __restrict__ Wb,
    float* __restrict__ pair_out, float* __restrict__ biasA) {
  int i = blockIdx.x / 3, jb = blockIdx.x % 3, t = threadIdx.x;
  __shared__ float jsx[256], jsy[256], jsz[256];
  __shared__ int jsu[256];
  __shared__ __align__(128) short stg[4][1280];
  __shared__ __align__(16) float pfs[4][1056];
  __shared__ float wgb[192];
  __shared__ float kbs[12];
  int jg = jb * 256 + t;
  jsx[t] = ref_pos[jg * 3];
  jsy[t] = ref_pos[jg * 3 + 1];
  jsz[t] = ref_pos[jg * 3 + 2];
  jsu[t] = uid[jg];
  if (t >= 64) {
    int e = t - 64;
    if (e < 192) {
      int bq = e >> 6, k = (e >> 2) & 15, h = e & 3;
      wgb[e] = lnp_g[bq * 16 + k] * Wb[bq * 64 + k * 4 + h];
    }
  }
  if (t >= 48 && t < 60) {
    int e = t - 48, bq = e >> 2, h = e & 3;
    float a = 0.f;
#pragma unroll
    for (int cc = 0; cc < 16; cc++) a += lnp_b[bq * 16 + cc] * Wb[bq * 64 + cc * 4 + h];
    kbs[e] = a;
  }
  int w = t >> 6, l = t & 63;
  int c = l & 15, gr = l >> 4;
  float pix = ref_pos[i * 3], piy = ref_pos[i * 3 + 1], piz = ref_pos[i * 3 + 2];
  int ui = uid[i];
  float w0c = Wpo[c], w1c = Wpo[16 + c], w2c = Wpo[32 + c];
  float wic = Wisd[c], wmc = Wmask[c], cac = ca[i * 16 + c];
  s16x8 bw0 = {bf1(W1[(4 * gr + 0) * 16 + c]), bf1(W1[(4 * gr + 1) * 16 + c]),
               bf1(W1[(4 * gr + 2) * 16 + c]), bf1(W1[(4 * gr + 3) * 16 + c]),
               (short)0, (short)0, (short)0, (short)0};
  s16x8 bw1 = {bf1(W2[(4 * gr + 0) * 16 + c]), bf1(W2[(4 * gr + 1) * 16 + c]),
               bf1(W2[(4 * gr + 2) * 16 + c]), bf1(W2[(4 * gr + 3) * 16 + c]),
               (short)0, (short)0, (short)0, (short)0};
  s16x8 bw2 = {bf1(W3[(4 * gr + 0) * 16 + c]), bf1(W3[(4 * gr + 1) * 16 + c]),
               bf1(W3[(4 * gr + 2) * 16 + c]), bf1(W3[(4 * gr + 3) * 16 + c]),
               (short)0, (short)0, (short)0, (short)0};
  __syncthreads();
  char* sb = (char*)&stg[w][0];
  unsigned sbase = (unsigned)(uintptr_t)sb;
  f32x4 z4 = {0.f, 0.f, 0.f, 0.f};
#pragma unroll
  for (int g = 0; g < 4; g++) {
    float p0_, p1_, p2_, p3_;
    {
      int jl0 = w * 64 + g * 16 + 4 * gr;
#pragma unroll
      for (int r = 0; r < 4; r++) {
        int jloc = jl0 + r;
        int j = jb * 256 + jloc;
        float d0 = pix - jsx[jloc], d1 = piy - jsy[jloc], d2 = piz - jsz[jloc];
        float mk = (ui == jsu[jloc]) ? 1.f : 0.f;
        float inv = 1.f / (1.f + d0 * d0 + d1 * d1 + d2 * d2);
        float zv = zp[((long)((i & 255) << 8) + jloc) * 16 + c];
        float cbv = cb[j * 16 + c];
        float pv = mk * (d0 * w0c + d1 * w1c + d2 * w2c + inv * wic + wmc) + zv + cbv + cac;
        if (r == 0) p0_ = pv; else if (r == 1) p1_ = pv; else if (r == 2) p2_ = pv; else p3_ = pv;
      }
    }
    char* wp = sb + g * 640 + c * 32 + gr * 8;
    unsigned ra = sbase + (unsigned)(g * 640 + c * 8 + gr * 128);
    *(uint2*)wp = make_uint2(bfpack(fmaxf(p0_, 0.f), fmaxf(p1_, 0.f)),
                             bfpack(fmaxf(p2_, 0.f), fmaxf(p3_, 0.f)));
    s16x4 tr0;
    asm volatile("s_waitcnt lgkmcnt(0)\n\tds_read_b64_tr_b16 %0, %1\n\ts_waitcnt lgkmcnt(0)"
                 : "=v"(tr0) : "v"(ra) : "memory");
    s16x8 a8 = {tr0[0], tr0[1], tr0[2], tr0[3], (short)0, (short)0, (short)0, (short)0};
    f32x4 h1 = __builtin_amdgcn_mfma_f32_16x16x32_bf16(a8, bw0, z4, 0, 0, 0);
    *(uint2*)wp = make_uint2(bfpack(fmaxf(h1[0], 0.f), fmaxf(h1[1], 0.f)),
                             bfpack(fmaxf(h1[2], 0.f), fmaxf(h1[3], 0.f)));
    s16x4 tr1;
    asm volatile("s_waitcnt lgkmcnt(0)\n\tds_read_b64_tr_b16 %0, %1\n\ts_waitcnt lgkmcnt(0)"
                 : "=v"(tr1) : "v"(ra) : "memory");
    s16x8 a8b = {tr1[0], tr1[1], tr1[2], tr1[3], (short)0, (short)0, (short)0, (short)0};
    f32x4 h2 = __builtin_amdgcn_mfma_f32_16x16x32_bf16(a8b, bw1, z4, 0, 0, 0);
    *(uint2*)wp = make_uint2(bfpack(fmaxf(h2[0], 0.f), fmaxf(h2[1], 0.f)),
                             bfpack(fmaxf(h2[2], 0.f), fmaxf(h2[3], 0.f)));
    s16x4 tr2;
    asm volatile("s_waitcnt lgkmcnt(0)\n\tds_read_b64_tr_b16 %0, %1\n\ts_waitcnt lgkmcnt(0)"
                 : "=v"(tr2) : "v"(ra) : "memory");
    s16x8 a8c = {tr2[0], tr2[1], tr2[2], tr2[3], (short)0, (short)0, (short)0, (short)0};
    f32x4 h3 = __builtin_amdgcn_mfma_f32_16x16x32_bf16(a8c, bw2, z4, 0, 0, 0);
    float f0 = p0_ + h3[0], f1 = p1_ + h3[1], f2 = p2_ + h3[2], f3 = p3_ + h3[3];
    {
      int jl0 = w * 64 + g * 16 + 4 * gr;
      long pb = ((long)i * 768 + (long)(jb * 256 + jl0)) * 16 + c;
      pair_out[pb] = f0;
      pair_out[pb + 16] = f1;
      pair_out[pb + 32] = f2;
      pair_out[pb + 48] = f3;
    }
    *(float4*)&pfs[w][g * 264 + c * 16 + 4 * gr] = make_float4(f0, f1, f2, f3);
  }
  asm volatile("s_waitcnt lgkmcnt(0)" ::: "memory");
  int qb = i >> 5;
  int j = jb * 256 + t;
  unsigned jw = (unsigned)(j - (qb * 32 - 48));
  if (jw < 128u) {
    int gt = (t >> 4) & 3, jr = t & 15;
    float v[16];
#pragma unroll
    for (int cc = 0; cc < 16; cc++) v[cc] = pfs[w][gt * 264 + cc * 16 + jr];
    float m = 0.f;
#pragma unroll
    for (int cc = 0; cc < 16; cc++) m += v[cc];
    m *= (1.f / 16.f);
    float vv = 0.f;
#pragma unroll
    for (int cc = 0; cc < 16; cc++) { float d = v[cc] - m; vv += d * d; }
    float rs = rsqrtf(vv * (1.f / 16.f) + 1e-5f);
    float nrm[16];
#pragma unroll
    for (int cc = 0; cc < 16; cc++) nrm[cc] = (v[cc] - m) * rs;
    int qi = i & 31;
#pragma unroll
    for (int bq = 0; bq < 3; bq++) {
      float o0 = kbs[bq * 4 + 0], o1 = kbs[bq * 4 + 1];
      float o2 = kbs[bq * 4 + 2], o3 = kbs[bq * 4 + 3];
#pragma unroll
      for (int k = 0; k < 16; k++) {
        float nv = nrm[k];
        float4 wv = *(float4*)&wgb[bq * 64 + k * 4];
        o0 += nv * wv.x; o1 += nv * wv.y; o2 += nv * wv.z; o3 += nv * wv.w;
      }
      long base = (long)(bq * 96 + qb * 4) * 4096 + (long)qi * 128 + jw;
      biasA[base] = o0;
      biasA[base + 4096] = o1;
      biasA[base + 2 * 4096] = o2;
      biasA[base + 3 * 4096] = o3;
    }
  }
}

// ---------------------------------------------------------------------------
// k_qkvg: grid 384 (rb*8+bn), block 256
__global__ __launch_bounds__(256) void k_qkvg(
    const float* __restrict__ x, const float* __restrict__ lng,
    const float* __restrict__ lnb, const float* __restrict__ Wq,
    const float* __restrict__ Wk, const float* __restrict__ Wv,
    const float* __restrict__ Wg, float* __restrict__ qkvg) {
  __shared__ float As[128][18];
  __shared__ float Ws[128][66];
  int t = threadIdx.x;
  int rb = blockIdx.x >> 3, bn = blockIdx.x & 7;
  int r0 = rb * 16;
  const float* Wm = (bn < 2) ? Wq : (bn < 4) ? Wk : (bn < 6) ? Wv : Wg;
  int c0 = (bn & 1) * 64;
  int ncol0 = (bn >> 1) * 128 + c0;
#pragma unroll
  for (int m = 0; m < 8; m++) {
    int idx = t + 256 * m;
    int row = idx >> 4, c4 = (idx & 15) * 4;
    *(float4*)&Ws[row][c4] = *(const float4*)&Wm[row * 128 + c0 + c4];
  }
  {
    int rr = t >> 4, tt = t & 15;
    int row = r0 + rr;
    float4 x0 = *(const float4*)&x[row * 128 + tt * 8];
    float4 x1 = *(const float4*)&x[row * 128 + tt * 8 + 4];
    float ps = x0.x + x0.y + x0.z + x0.w + x1.x + x1.y + x1.z + x1.w;
    float pq = x0.x * x0.x + x0.y * x0.y + x0.z * x0.z + x0.w * x0.w +
               x1.x * x1.x + x1.y * x1.y + x1.z * x1.z + x1.w * x1.w;
#pragma unroll
    for (int o = 1; o < 16; o <<= 1) { ps += __shfl_xor(ps, o); pq += __shfl_xor(pq, o); }
    float m = ps * (1.f / 128.f);
    float rstd = rsqrtf(pq * (1.f / 128.f) - m * m + 1e-5f);
    float4 g0 = *(const float4*)&lng[tt * 8], g1 = *(const float4*)&lng[tt * 8 + 4];
    float4 b0 = *(const float4*)&lnb[tt * 8], b1 = *(const float4*)&lnb[tt * 8 + 4];
    As[tt * 8 + 0][rr] = (x0.x - m) * rstd * g0.x + b0.x;
    As[tt * 8 + 1][rr] = (x0.y - m) * rstd * g0.y + b0.y;
    As[tt * 8 + 2][rr] = (x0.z - m) * rstd * g0.z + b0.z;
    As[tt * 8 + 3][rr] = (x0.w - m) * rstd * g0.w + b0.w;
    As[tt * 8 + 4][rr] = (x1.x - m) * rstd * g1.x + b1.x;
    As[tt * 8 + 5][rr] = (x1.y - m) * rstd * g1.y + b1.y;
    As[tt * 8 + 6][rr] = (x1.z - m) * rstd * g1.z + b1.z;
    As[tt * 8 + 7][rr] = (x1.w - m) * rstd * g1.w + b1.w;
  }
  __syncthreads();
  int ty = t >> 5, tx = t & 31;
  float a00 = 0, a01 = 0, a10 = 0, a11 = 0;
#pragma unroll 8
  for (int k = 0; k < 128; k++) {
    float2 a2 = *(float2*)&As[k][ty * 2];
    float2 w2 = *(float2*)&Ws[k][tx * 2];
    a00 += a2.x * w2.x; a01 += a2.x * w2.y;
    a10 += a2.y * w2.x; a11 += a2.y * w2.y;
  }
  int row = r0 + ty * 2;
  float2 o0 = {a00, a01}, o1 = {a10, a11};
  *(float2*)&qkvg[row * 512 + ncol0 + tx * 2] = o0;
  *(float2*)&qkvg[(row + 1) * 512 + ncol0 + tx * 2] = o1;
}

// ---------------------------------------------------------------------------
// k_attn: grid 96, block 256
__global__ __launch_bounds__(256) void k_attn(
    const float* __restrict__ qkvg, const float* __restrict__ biasb,
    float* __restrict__ og) {
  int qb = blockIdx.x >> 2, h = blockIdx.x & 3, t = threadIdx.x;
  int i0 = qb * 32, lo = i0 - 48;
  __shared__ float qs[32][36];
  __shared__ float ks[128][36];
  __shared__ float vs[128][36];
  __shared__ float L[32][132];
#pragma unroll
  for (int m = 0; m < 4; m++) {
    int idx = t + 256 * m;
    int qi = idx >> 5, k4 = (idx & 31) * 4;
    int j = lo + k4;
    float4 bv;
    if (j >= 0 && j < 768) bv = *(const float4*)&biasb[(qb * 4 + h) * 4096 + qi * 128 + k4];
    else bv = make_float4(-1e30f, -1e30f, -1e30f, -1e30f);
    *(float4*)&L[qi][k4] = bv;
  }
  {
    int qi = t >> 3, dq = (t & 7) * 4;
    *(float4*)&qs[qi][dq] = *(const float4*)&qkvg[(i0 + qi) * 512 + h * 32 + dq];
  }
  {
    int kj = t >> 1, dh = (t & 1) * 16;
    int j = lo + kj;
    if (j >= 0 && j < 768) {
      const float4* sk = (const float4*)&qkvg[j * 512 + 128 + h * 32 + dh];
      const float4* sv = (const float4*)&qkvg[j * 512 + 256 + h * 32 + dh];
#pragma unroll
      for (int m = 0; m < 4; m++) {
        *(float4*)&ks[kj][dh + 4 * m] = sk[m];
        *(float4*)&vs[kj][dh + 4 * m] = sv[m];
      }
    } else {
      float4 zz = {0, 0, 0, 0};
#pragma unroll
      for (int m = 0; m < 4; m++) {
        *(float4*)&ks[kj][dh + 4 * m] = zz;
        *(float4*)&vs[kj][dh + 4 * m] = zz;
      }
    }
  }
  __syncthreads();
  const float scale = 0.17677669529663687f;
  {
    int qi = t & 31, kb = t >> 5;
    float4 qr[8];
#pragma unroll
    for (int m = 0; m < 8; m++) qr[m] = *(float4*)&qs[qi][m * 4];
#pragma unroll 2
    for (int kk = 0; kk < 16; kk++) {
      int kj = kb * 16 + kk;
      float acc = 0.f;
#pragma unroll
      for (int m = 0; m < 8; m++) {
        float4 kv = *(float4*)&ks[kj][m * 4];
        acc += qr[m].x * kv.x + qr[m].y * kv.y + qr[m].z * kv.z + qr[m].w * kv.w;
      }
      L[qi][kj] += acc * scale;
    }
  }
  __syncthreads();
  int qi = t >> 3, sg = t & 7;
  float mx = -1e30f;
#pragma unroll
  for (int k2 = 0; k2 < 16; k2++) mx = fmaxf(mx, L[qi][sg * 16 + k2]);
#pragma unroll
  for (int o = 1; o < 8; o <<= 1) mx = fmaxf(mx, __shfl_xor(mx, o));
  float sum = 0.f;
#pragma unroll
  for (int k2 = 0; k2 < 16; k2++) {
    int kj = sg * 16 + k2;
    float e = __expf(L[qi][kj] - mx);
    L[qi][kj] = e;
    sum += e;
  }
#pragma unroll
  for (int o = 1; o < 8; o <<= 1) sum += __shfl_xor(sum, o);
  float rden = 1.f / sum;
  __syncthreads();
  int d0 = (t & 7) * 4;
  float4 acc = {0, 0, 0, 0};
#pragma unroll 4
  for (int kj = 0; kj < 128; kj++) {
    float p = L[qi][kj];
    float4 v = *(const float4*)&vs[kj][d0];
    acc.x += p * v.x; acc.y += p * v.y; acc.z += p * v.z; acc.w += p * v.w;
  }
  int i = i0 + qi;
  float4 gr = *(const float4*)&qkvg[i * 512 + 384 + h * 32 + d0];
  float4 o4;
  o4.x = acc.x * rden * sigmoidf_(gr.x);
  o4.y = acc.y * rden * sigmoidf_(gr.y);
  o4.z = acc.z * rden * sigmoidf_(gr.z);
  o4.w = acc.w * rden * sigmoidf_(gr.w);
  *(float4*)&og[i * 128 + h * 32 + d0] = o4;
}

// ---------------------------------------------------------------------------
// k_fused4: x += og@Wo; a=LN(x); x += relu(a@Wt1)@Wt2.
// grid 256 (3 rows/block, 1 block/CU), block 384 (6 waves).
// GEMM1/GEMM3: 4-way k-split, float4 weight loads (32/thread) + LDS combine.
// GEMM2: 128 float4 loads/thread, independent (unrolled).
__global__ __launch_bounds__(384) void k_fused4(
    const float* __restrict__ og, const float* __restrict__ Wo,
    const float* __restrict__ g2, const float* __restrict__ b2,
    const float* __restrict__ Wt1, const float* __restrict__ Wt2,
    float* __restrict__ x) {
  int t = threadIdx.x;
  int r0 = blockIdx.x * 3;
  __shared__ float osr[3][128];
  __shared__ float xns[3][128];
  __shared__ float asr[3][128];
  __shared__ float hs[3][512];
  __shared__ float part[4][3][128];
  __shared__ float red[12];
  {
    int rr = t >> 7, c = t & 127;
    osr[rr][c] = og[(r0 + rr) * 128 + c];
    xns[rr][c] = x[(r0 + rr) * 128 + c];
  }
  __syncthreads();
  // ---- GEMM1 (k-split 4): part[q][row][c0..c0+3] = sum_{k in q} osr[row][k]*Wo[k][c] ----
  {
    int c4 = (t & 31) * 4, row = (t >> 5) % 3, q = t / 96;
    int k0 = q * 32;
    float a0 = 0.f, a1 = 0.f, a2 = 0.f, a3 = 0.f;
#pragma unroll 8
    for (int kk = 0; kk < 32; kk++) {
      int k = k0 + kk;
      float4 w = *(const float4*)&Wo[k * 128 + c4];
      float av = osr[row][k];
      a0 += av * w.x; a1 += av * w.y; a2 += av * w.z; a3 += av * w.w;
    }
    *(float4*)&part[q][row][c4] = make_float4(a0, a1, a2, a3);
  }
  __syncthreads();
  // ---- combine + LN (row = t>>7, two waves per row) ----
  float xv;
  {
    int rr = t >> 7, c = t & 127;
    xv = xns[rr][c] + part[0][rr][c] + part[1][rr][c] + part[2][rr][c] + part[3][rr][c];
    float ps = xv, pq = xv * xv;
#pragma unroll
    for (int o = 1; o < 64; o <<= 1) { ps += __shfl_xor(ps, o); pq += __shfl_xor(pq, o); }
    int wv = t >> 6;
    if ((t & 63) == 0) { red[wv] = ps; red[6 + wv] = pq; }
    __syncthreads();
    float mean = (red[2 * rr] + red[2 * rr + 1]) * (1.f / 128.f);
    float var = (red[6 + 2 * rr] + red[6 + 2 * rr + 1]) * (1.f / 128.f) - mean * mean;
    float rstd = rsqrtf(var + 1e-5f);
    xns[rr][c] = xv;
    asr[rr][c] = (xv - mean) * rstd * g2[c] + b2[c];
  }
  __syncthreads();
  // ---- GEMM2: hs[row][512] = relu(asr[row] @ Wt1); thread = (row = t/128, c4 = t%128) ----
  {
    int c4 = (t & 127) * 4, row = t >> 7;
    float a0 = 0.f, a1 = 0.f, a2 = 0.f, a3 = 0.f;
#pragma unroll 8
    for (int k = 0; k < 128; k++) {
      float4 w = *(const float4*)&Wt1[k * 512 + c4];
      float av = asr[row][k];
      a0 += av * w.x; a1 += av * w.y; a2 += av * w.z; a3 += av * w.w;
    }
    *(float4*)&hs[row][c4] = make_float4(fmaxf(a0, 0.f), fmaxf(a1, 0.f),
                                         fmaxf(a2, 0.f), fmaxf(a3, 0.f));
  }
  __syncthreads();
  // ---- GEMM3 (k-split 4): part[q][row][c] = sum_{k in q's 128} hs[row][k]*Wt2[k][c] ----
  {
    int c4 = (t & 31) * 4, row = (t >> 5) % 3, q = t / 96;
    int k0 = q * 128;
    float a0 = 0.f, a1 = 0.f, a2 = 0.f, a3 = 0.f;
#pragma unroll 8
    for (int kk = 0; kk < 128; kk++) {
      int k = k0 + kk;
      float4 w = *(const float4*)&Wt2[k * 128 + c4];
      float hv = hs[row][k];
      a0 += hv * w.x; a1 += hv * w.y; a2 += hv * w.z; a3 += hv * w.w;
    }
    *(float4*)&part[q][row][c4] = make_float4(a0, a1, a2, a3);
  }
  __syncthreads();
  {
    int rr = t >> 7, c = t & 127;
    x[(r0 + rr) * 128 + c] = xns[rr][c] + part[0][rr][c] + part[1][rr][c] +
                             part[2][rr][c] + part[3][rr][c];
  }
}

// ---------------------------------------------------------------------------
// k_final: grid 256, block 384
__global__ __launch_bounds__(384) void k_final(
    const float* __restrict__ x, const float* __restrict__ W_proj,
    float* __restrict__ out) {
  __shared__ float xs[384];
  int tk = blockIdx.x, t = threadIdx.x;
  xs[t] = x[tk * 384 + t];
  __syncthreads();
  float a0 = 0, a1 = 0, a2 = 0;
#pragma unroll 8
  for (int k = 0; k < 128; k++) {
    float w = W_proj[k * 384 + t];
    a0 += xs[k] * w; a1 += xs[128 + k] * w; a2 += xs[256 + k] * w;
  }
  a0 = fmaxf(a0, 0.f); a1 = fmaxf(a1, 0.f); a2 = fmaxf(a2, 0.f);
  out[98304 + (tk * 3 + 0) * 384 + t] = a0;
  out[98304 + (tk * 3 + 1) * 384 + t] = a1;
  out[98304 + (tk * 3 + 2) * 384 + t] = a2;
  out[tk * 384 + t] = (a0 + a1 + a2) * (1.f / 3.f);
}

// ---------------------------------------------------------------------------
extern "C" void kernel_launch(void* const* d_in, const int* in_sizes, int n_in,
                              void* d_out, int out_size, void* d_ws, size_t ws_size,
                              hipStream_t stream) {
  const float* ref_pos  = (const float*)d_in[0];
  const int*   uid      = (const int*)d_in[1];
  const float* r        = (const float*)d_in[2];
  const float* s        = (const float*)d_in[3];
  const float* z        = (const float*)d_in[4];
  const float* W_pos    = (const float*)d_in[5];
  const float* Wpo      = (const float*)d_in[6];
  const float* Wisd     = (const float*)d_in[7];
  const float* Wmask    = (const float*)d_in[8];
  const float* Wca      = (const float*)d_in[9];
  const float* Wcb      = (const float*)d_in[10];
  const float* ln_s_g   = (const float*)d_in[11];
  const float* ln_s_b   = (const float*)d_in[12];
  const float* W_single = (const float*)d_in[13];
  const float* ln_z_g   = (const float*)d_in[14];
  const float* ln_z_b   = (const float*)d_in[15];
  const float* W_pair   = (const float*)d_in[16];
  const float* W_noisy  = (const float*)d_in[17];
  const float* W_mlp1   = (const float*)d_in[18];
  const float* W_mlp2   = (const float*)d_in[19];
  const float* W_mlp3   = (const float*)d_in[20];
  const float* at_ln_g  = (const float*)d_in[21];
  const float* at_ln_b  = (const float*)d_in[22];
  const float* at_Wq    = (const float*)d_in[23];
  const float* at_Wk    = (const float*)d_in[24];
  const float* at_Wv    = (const float*)d_in[25];
  const float* at_Wg    = (const float*)d_in[26];
  const float* at_lnp_g = (const float*)d_in[27];
  const float* at_lnp_b = (const float*)d_in[28];
  const float* at_Wb    = (const float*)d_in[29];
  const float* at_Wo    = (const float*)d_in[30];
  const float* at_ln2_g = (const float*)d_in[31];
  const float* at_ln2_b = (const float*)d_in[32];
  const float* at_Wt1   = (const float*)d_in[33];
  const float* at_Wt2   = (const float*)d_in[34];
  const float* W_proj   = (const float*)d_in[35];
  float* out = (float*)d_out;
  float* W = (float*)d_ws;
  float* x     = W;                 //   98304
  float* ca    = W + 98304;         //   12288
  float* cb    = W + 110592;        //   12288
  float* zp    = W + 122880;        // 1048576
  float* biasA = W + 1171456;       // 1179648
  float* qkvg  = W + 2351104;       //  393216
  float* og    = W + 2744320;       //   98304

  k_zp<<<4096, 256, 0, stream>>>(z, ln_z_g, ln_z_b, W_pair, zp);
  k_tokatoms<<<256, 128, 0, stream>>>(s, ln_s_g, ln_s_b, W_single, ref_pos, r,
                                      W_pos, W_noisy, Wca, Wcb,
                                      out + 393216, x, ca, cb);
  k_pairM<<<2304, 256, 0, stream>>>(ref_pos, uid, Wpo, Wisd, Wmask, W_mlp1, W_mlp2,
                                    W_mlp3, zp, ca, cb, at_lnp_g, at_lnp_b, at_Wb,
                                    out + 491520, biasA);
  for (int b = 0; b < 3; b++) {
    k_qkvg<<<384, 256, 0, stream>>>(x, at_ln_g + b * 128, at_ln_b + b * 128,
                                    at_Wq + b * 16384, at_Wk + b * 16384,
                                    at_Wv + b * 16384, at_Wg + b * 16384, qkvg);
    k_attn<<<96, 256, 0, stream>>>(qkvg, biasA + b * 393216, og);
    k_fused4<<<256, 384, 0, stream>>>(og, at_Wo + b * 16384, at_ln2_g + b * 128,
                                      at_ln2_b + b * 128, at_Wt1 + b * 65536,
                                      at_Wt2 + b * 65536, x);
  }
  k_final<<<256, 384, 0, stream>>>(x, W_proj, out);
}

// Round 12
// 169.269 us; speedup vs baseline: 1.9611x; 1.0148x over previous
//
#include <hip/hip_runtime.h>
#include <math.h>

// N=768 atoms, T=256 tokens, CA=128, CP=16, CZ=128, CS=384, CT=384, H=4, DH=32
// d_out: a_out[256*384]@0, qout[768*384]@98304, c[768*128]@393216, pair[768*768*16]@491520

__device__ __forceinline__ float sigmoidf_(float v) { return 1.f / (1.f + __expf(-v)); }

typedef __attribute__((ext_vector_type(4))) short s16x4;
typedef __attribute__((ext_vector_type(8))) short s16x8;
typedef __attribute__((ext_vector_type(4))) float f32x4;

__device__ __forceinline__ unsigned bfpack(float a, float b) {
  return (__float_as_uint(a) >> 16) | (__float_as_uint(b) & 0xFFFF0000u);
}
__device__ __forceinline__ short bf1(float a) { return (short)(__float_as_uint(a) >> 16); }

// ---------------------------------------------------------------------------
// k_tokatoms: grid 256, block 128
__global__ __launch_bounds__(128) void k_tokatoms(
    const float* __restrict__ s, const float* __restrict__ g,
    const float* __restrict__ b, const float* __restrict__ W_single,
    const float* __restrict__ ref_pos, const float* __restrict__ r,
    const float* __restrict__ W_pos, const float* __restrict__ W_noisy,
    const float* __restrict__ Wca, const float* __restrict__ Wcb,
    float* __restrict__ c_out, float* __restrict__ x,
    float* __restrict__ ca, float* __restrict__ cb) {
  int tok = blockIdx.x, t = threadIdx.x;
  __shared__ float sln[384];
  __shared__ float ws[48 * 128];
  __shared__ float red[4];
  __shared__ float rc[128];
  float v0 = s[tok * 384 + t], v1 = s[tok * 384 + 128 + t], v2 = s[tok * 384 + 256 + t];
  float ps = v0 + v1 + v2, pq = v0 * v0 + v1 * v1 + v2 * v2;
#pragma unroll
  for (int o = 1; o < 64; o <<= 1) { ps += __shfl_xor(ps, o); pq += __shfl_xor(pq, o); }
  if ((t & 63) == 0) { red[t >> 6] = ps; red[2 + (t >> 6)] = pq; }
  __syncthreads();
  float mean = (red[0] + red[1]) * (1.f / 384.f);
  float var = (red[2] + red[3]) * (1.f / 384.f) - mean * mean;
  float rstd = rsqrtf(var + 1e-5f);
  sln[t] = (v0 - mean) * rstd * g[t] + b[t];
  sln[128 + t] = (v1 - mean) * rstd * g[128 + t] + b[128 + t];
  sln[256 + t] = (v2 - mean) * rstd * g[256 + t] + b[256 + t];
  float ctv = 0.f;
  for (int c0 = 0; c0 < 384; c0 += 48) {
    __syncthreads();
#pragma unroll
    for (int m = 0; m < 12; m++) {
      int idx = (t + 128 * m) * 4;
      *(float4*)&ws[idx] = *(const float4*)&W_single[c0 * 128 + idx];
    }
    __syncthreads();
#pragma unroll 8
    for (int kk = 0; kk < 48; kk++) ctv += sln[c0 + kk] * ws[kk * 128 + t];
  }
  float wp0 = W_pos[t], wp1 = W_pos[128 + t], wp2 = W_pos[256 + t];
  float wn0 = W_noisy[t], wn1 = W_noisy[128 + t], wn2 = W_noisy[256 + t];
#pragma unroll
  for (int a = 0; a < 3; a++) {
    int i = tok + 256 * a;
    float p0 = ref_pos[i * 3], p1 = ref_pos[i * 3 + 1], p2 = ref_pos[i * 3 + 2];
    float r0 = r[i * 3], r1 = r[i * 3 + 1], r2 = r[i * 3 + 2];
    float c0 = p0 * wp0 + p1 * wp1 + p2 * wp2;
    x[i * 128 + t] = c0 + r0 * wn0 + r1 * wn1 + r2 * wn2;
    float cc = c0 + ctv;
    c_out[i * 128 + t] = cc;
    __syncthreads();
    rc[t] = fmaxf(cc, 0.f);
    __syncthreads();
    int out_id = t >> 2, q = t & 3;
    const float* Wm = (out_id < 16) ? Wca : Wcb;
    int ch = out_id & 15;
    float acc = 0.f;
#pragma unroll
    for (int kk = 0; kk < 32; kk++) { int k = q * 32 + kk; acc += rc[k] * Wm[k * 16 + ch]; }
    acc += __shfl_xor(acc, 1);
    acc += __shfl_xor(acc, 2);
    if (q == 0) { if (out_id < 16) ca[i * 16 + ch] = acc; else cb[i * 16 + ch] = acc; }
  }
}

// ---------------------------------------------------------------------------
// k_zp: zp[65536,16] = LN(z)@W_pair   grid 4096, block 256
__global__ __launch_bounds__(256) void k_zp(
    const float* __restrict__ z, const float* __restrict__ g,
    const float* __restrict__ lb, const float* __restrict__ W_pair,
    float* __restrict__ zp) {
  __shared__ float wT[16][132];
  __shared__ float zs[16][132];
  __shared__ float sWg[16], Bc[16];
  int t = threadIdx.x;
#pragma unroll
  for (int m = 0; m < 8; m++) {
    int e = t + 256 * m;
    int row = e >> 4, ch = e & 15;
    wT[ch][row] = g[row] * W_pair[e];
  }
  __syncthreads();
  if (t < 32) {
    int ch = t & 15;
    float a = 0.f;
    if (t < 16) {
#pragma unroll 8
      for (int k = 0; k < 128; k++) a += wT[ch][k];
      sWg[ch] = a;
    } else {
#pragma unroll 8
      for (int k = 0; k < 128; k++) a += lb[k] * W_pair[k * 16 + ch];
      Bc[ch] = a;
    }
  }
  int row = t >> 4, kk = (t & 15) * 8;
  long base = ((long)blockIdx.x * 16 + row) * 128 + kk;
  float4 a4 = *(const float4*)&z[base];
  float4 b4 = *(const float4*)&z[base + 4];
  *(float4*)&zs[row][kk] = a4;
  *(float4*)&zs[row][kk + 4] = b4;
  float ps = a4.x + a4.y + a4.z + a4.w + b4.x + b4.y + b4.z + b4.w;
  float pq = a4.x * a4.x + a4.y * a4.y + a4.z * a4.z + a4.w * a4.w +
             b4.x * b4.x + b4.y * b4.y + b4.z * b4.z + b4.w * b4.w;
#pragma unroll
  for (int o = 1; o < 16; o <<= 1) { ps += __shfl_xor(ps, o); pq += __shfl_xor(pq, o); }
  float m = ps * (1.f / 128.f);
  float rstd = rsqrtf(pq * (1.f / 128.f) - m * m + 1e-5f);
  __syncthreads();
  int ch = t & 15;
  float dotv = 0.f;
#pragma unroll 8
  for (int k4 = 0; k4 < 32; k4++) {
    float4 zv = *(float4*)&zs[row][k4 * 4];
    float4 wv = *(float4*)&wT[ch][k4 * 4];
    dotv += zv.x * wv.x + zv.y * wv.y + zv.z * wv.z + zv.w * wv.w;
  }
  zp[((long)blockIdx.x * 16 + row) * 16 + ch] = rstd * (dotv - m * sWg[ch]) + Bc[ch];
}

// ---------------------------------------------------------------------------
// k_pairM: pair + MFMA MLP + fused window bias.  grid 2304, block 256
__global__ __launch_bounds__(256) void k_pairM(
    const float* __restrict__ ref_pos, const int* __restrict__ uid,
    const float* __restrict__ Wpo, const float* __restrict__ Wisd,
    const float* __restrict__ Wmask, const float* __restrict__ W1,
    const float* __restrict__ W2, const float* __restrict__ W3,
    const float* __restrict__ zp, const float* __restrict__ ca,
    const float* __restrict__ cb, const float* __restrict__ lnp_g,
    const float* __restrict__ lnp_b, const float* __restrict__ Wb,
    float* __restrict__ pair_out, float* __restrict__ biasA) {
  int i = blockIdx.x / 3, jb = blockIdx.x % 3, t = threadIdx.x;
  __shared__ float jsx[256], jsy[256], jsz[256];
  __shared__ int jsu[256];
  __shared__ __align__(128) short stg[4][1280];
  __shared__ __align__(16) float pfs[4][1056];
  __shared__ float wgb[192];
  __shared__ float kbs[12];
  int jg = jb * 256 + t;
  jsx[t] = ref_pos[jg * 3];
  jsy[t] = ref_pos[jg * 3 + 1];
  jsz[t] = ref_pos[jg * 3 + 2];
  jsu[t] = uid[jg];
  if (t >= 64) {
    int e = t - 64;
    if (e < 192) {
      int bq = e >> 6, k = (e >> 2) & 15, h = e & 3;
      wgb[e] = lnp_g[bq * 16 + k] * Wb[bq * 64 + k * 4 + h];
    }
  }
  if (t >= 48 && t < 60) {
    int e = t - 48, bq = e >> 2, h = e & 3;
    float a = 0.f;
#pragma unroll
    for (int cc = 0; cc < 16; cc++) a += lnp_b[bq * 16 + cc] * Wb[bq * 64 + cc * 4 + h];
    kbs[e] = a;
  }
  int w = t >> 6, l = t & 63;
  int c = l & 15, gr = l >> 4;
  float pix = ref_pos[i * 3], piy = ref_pos[i * 3 + 1], piz = ref_pos[i * 3 + 2];
  int ui = uid[i];
  float w0c = Wpo[c], w1c = Wpo[16 + c], w2c = Wpo[32 + c];
  float wic = Wisd[c], wmc = Wmask[c], cac = ca[i * 16 + c];
  s16x8 bw0 = {bf1(W1[(4 * gr + 0) * 16 + c]), bf1(W1[(4 * gr + 1) * 16 + c]),
               bf1(W1[(4 * gr + 2) * 16 + c]), bf1(W1[(4 * gr + 3) * 16 + c]),
               (short)0, (short)0, (short)0, (short)0};
  s16x8 bw1 = {bf1(W2[(4 * gr + 0) * 16 + c]), bf1(W2[(4 * gr + 1) * 16 + c]),
               bf1(W2[(4 * gr + 2) * 16 + c]), bf1(W2[(4 * gr + 3) * 16 + c]),
               (short)0, (short)0, (short)0, (short)0};
  s16x8 bw2 = {bf1(W3[(4 * gr + 0) * 16 + c]), bf1(W3[(4 * gr + 1) * 16 + c]),
               bf1(W3[(4 * gr + 2) * 16 + c]), bf1(W3[(4 * gr + 3) * 16 + c]),
               (short)0, (short)0, (short)0, (short)0};
  __syncthreads();
  char* sb = (char*)&stg[w][0];
  unsigned sbase = (unsigned)(uintptr_t)sb;
  f32x4 z4 = {0.f, 0.f, 0.f, 0.f};
#pragma unroll
  for (int g = 0; g < 4; g++) {
    float p0_, p1_, p2_, p3_;
    {
      int jl0 = w * 64 + g * 16 + 4 * gr;
#pragma unroll
      for (int r = 0; r < 4; r++) {
        int jloc = jl0 + r;
        int j = jb * 256 + jloc;
        float d0 = pix - jsx[jloc], d1 = piy - jsy[jloc], d2 = piz - jsz[jloc];
        float mk = (ui == jsu[jloc]) ? 1.f : 0.f;
        float inv = 1.f / (1.f + d0 * d0 + d1 * d1 + d2 * d2);
        float zv = zp[((long)((i & 255) << 8) + jloc) * 16 + c];
        float cbv = cb[j * 16 + c];
        float pv = mk * (d0 * w0c + d1 * w1c + d2 * w2c + inv * wic + wmc) + zv + cbv + cac;
        if (r == 0) p0_ = pv; else if (r == 1) p1_ = pv; else if (r == 2) p2_ = pv; else p3_ = pv;
      }
    }
    char* wp = sb + g * 640 + c * 32 + gr * 8;
    unsigned ra = sbase + (unsigned)(g * 640 + c * 8 + gr * 128);
    *(uint2*)wp = make_uint2(bfpack(fmaxf(p0_, 0.f), fmaxf(p1_, 0.f)),
                             bfpack(fmaxf(p2_, 0.f), fmaxf(p3_, 0.f)));
    s16x4 tr0;
    asm volatile("s_waitcnt lgkmcnt(0)\n\tds_read_b64_tr_b16 %0, %1\n\ts_waitcnt lgkmcnt(0)"
                 : "=v"(tr0) : "v"(ra) : "memory");
    s16x8 a8 = {tr0[0], tr0[1], tr0[2], tr0[3], (short)0, (short)0, (short)0, (short)0};
    f32x4 h1 = __builtin_amdgcn_mfma_f32_16x16x32_bf16(a8, bw0, z4, 0, 0, 0);
    *(uint2*)wp = make_uint2(bfpack(fmaxf(h1[0], 0.f), fmaxf(h1[1], 0.f)),
                             bfpack(fmaxf(h1[2], 0.f), fmaxf(h1[3], 0.f)));
    s16x4 tr1;
    asm volatile("s_waitcnt lgkmcnt(0)\n\tds_read_b64_tr_b16 %0, %1\n\ts_waitcnt lgkmcnt(0)"
                 : "=v"(tr1) : "v"(ra) : "memory");
    s16x8 a8b = {tr1[0], tr1[1], tr1[2], tr1[3], (short)0, (short)0, (short)0, (short)0};
    f32x4 h2 = __builtin_amdgcn_mfma_f32_16x16x32_bf16(a8b, bw1, z4, 0, 0, 0);
    *(uint2*)wp = make_uint2(bfpack(fmaxf(h2[0], 0.f), fmaxf(h2[1], 0.f)),
                             bfpack(fmaxf(h2[2], 0.f), fmaxf(h2[3], 0.f)));
    s16x4 tr2;
    asm volatile("s_waitcnt lgkmcnt(0)\n\tds_read_b64_tr_b16 %0, %1\n\ts_waitcnt lgkmcnt(0)"
                 : "=v"(tr2) : "v"(ra) : "memory");
    s16x8 a8c = {tr2[0], tr2[1], tr2[2], tr2[3], (short)0, (short)0, (short)0, (short)0};
    f32x4 h3 = __builtin_amdgcn_mfma_f32_16x16x32_bf16(a8c, bw2, z4, 0, 0, 0);
    float f0 = p0_ + h3[0], f1 = p1_ + h3[1], f2 = p2_ + h3[2], f3 = p3_ + h3[3];
    {
      int jl0 = w * 64 + g * 16 + 4 * gr;
      long pb = ((long)i * 768 + (long)(jb * 256 + jl0)) * 16 + c;
      pair_out[pb] = f0;
      pair_out[pb + 16] = f1;
      pair_out[pb + 32] = f2;
      pair_out[pb + 48] = f3;
    }
    *(float4*)&pfs[w][g * 264 + c * 16 + 4 * gr] = make_float4(f0, f1, f2, f3);
  }
  asm volatile("s_waitcnt lgkmcnt(0)" ::: "memory");
  int qb = i >> 5;
  int j = jb * 256 + t;
  unsigned jw = (unsigned)(j - (qb * 32 - 48));
  if (jw < 128u) {
    int gt = (t >> 4) & 3, jr = t & 15;
    float v[16];
#pragma unroll
    for (int cc = 0; cc < 16; cc++) v[cc] = pfs[w][gt * 264 + cc * 16 + jr];
    float m = 0.f;
#pragma unroll
    for (int cc = 0; cc < 16; cc++) m += v[cc];
    m *= (1.f / 16.f);
    float vv = 0.f;
#pragma unroll
    for (int cc = 0; cc < 16; cc++) { float d = v[cc] - m; vv += d * d; }
    float rs = rsqrtf(vv * (1.f / 16.f) + 1e-5f);
    float nrm[16];
#pragma unroll
    for (int cc = 0; cc < 16; cc++) nrm[cc] = (v[cc] - m) * rs;
    int qi = i & 31;
#pragma unroll
    for (int bq = 0; bq < 3; bq++) {
      float o0 = kbs[bq * 4 + 0], o1 = kbs[bq * 4 + 1];
      float o2 = kbs[bq * 4 + 2], o3 = kbs[bq * 4 + 3];
#pragma unroll
      for (int k = 0; k < 16; k++) {
        float nv = nrm[k];
        float4 wv = *(float4*)&wgb[bq * 64 + k * 4];
        o0 += nv * wv.x; o1 += nv * wv.y; o2 += nv * wv.z; o3 += nv * wv.w;
      }
      long base = (long)(bq * 96 + qb * 4) * 4096 + (long)qi * 128 + jw;
      biasA[base] = o0;
      biasA[base + 4096] = o1;
      biasA[base + 2 * 4096] = o2;
      biasA[base + 3 * 4096] = o3;
    }
  }
}

// ---------------------------------------------------------------------------
// k_qkvg (layer 0 only): grid 384 (rb*8+bn), block 256
__global__ __launch_bounds__(256) void k_qkvg(
    const float* __restrict__ x, const float* __restrict__ lng,
    const float* __restrict__ lnb, const float* __restrict__ Wq,
    const float* __restrict__ Wk, const float* __restrict__ Wv,
    const float* __restrict__ Wg, float* __restrict__ qkvg) {
  __shared__ float As[128][18];
  __shared__ float Ws[128][66];
  int t = threadIdx.x;
  int rb = blockIdx.x >> 3, bn = blockIdx.x & 7;
  int r0 = rb * 16;
  const float* Wm = (bn < 2) ? Wq : (bn < 4) ? Wk : (bn < 6) ? Wv : Wg;
  int c0 = (bn & 1) * 64;
  int ncol0 = (bn >> 1) * 128 + c0;
#pragma unroll
  for (int m = 0; m < 8; m++) {
    int idx = t + 256 * m;
    int row = idx >> 4, c4 = (idx & 15) * 4;
    *(float4*)&Ws[row][c4] = *(const float4*)&Wm[row * 128 + c0 + c4];
  }
  {
    int rr = t >> 4, tt = t & 15;
    int row = r0 + rr;
    float4 x0 = *(const float4*)&x[row * 128 + tt * 8];
    float4 x1 = *(const float4*)&x[row * 128 + tt * 8 + 4];
    float ps = x0.x + x0.y + x0.z + x0.w + x1.x + x1.y + x1.z + x1.w;
    float pq = x0.x * x0.x + x0.y * x0.y + x0.z * x0.z + x0.w * x0.w +
               x1.x * x1.x + x1.y * x1.y + x1.z * x1.z + x1.w * x1.w;
#pragma unroll
    for (int o = 1; o < 16; o <<= 1) { ps += __shfl_xor(ps, o); pq += __shfl_xor(pq, o); }
    float m = ps * (1.f / 128.f);
    float rstd = rsqrtf(pq * (1.f / 128.f) - m * m + 1e-5f);
    float4 g0 = *(const float4*)&lng[tt * 8], g1 = *(const float4*)&lng[tt * 8 + 4];
    float4 b0 = *(const float4*)&lnb[tt * 8], b1 = *(const float4*)&lnb[tt * 8 + 4];
    As[tt * 8 + 0][rr] = (x0.x - m) * rstd * g0.x + b0.x;
    As[tt * 8 + 1][rr] = (x0.y - m) * rstd * g0.y + b0.y;
    As[tt * 8 + 2][rr] = (x0.z - m) * rstd * g0.z + b0.z;
    As[tt * 8 + 3][rr] = (x0.w - m) * rstd * g0.w + b0.w;
    As[tt * 8 + 4][rr] = (x1.x - m) * rstd * g1.x + b1.x;
    As[tt * 8 + 5][rr] = (x1.y - m) * rstd * g1.y + b1.y;
    As[tt * 8 + 6][rr] = (x1.z - m) * rstd * g1.z + b1.z;
    As[tt * 8 + 7][rr] = (x1.w - m) * rstd * g1.w + b1.w;
  }
  __syncthreads();
  int ty = t >> 5, tx = t & 31;
  float a00 = 0, a01 = 0, a10 = 0, a11 = 0;
#pragma unroll 8
  for (int k = 0; k < 128; k++) {
    float2 a2 = *(float2*)&As[k][ty * 2];
    float2 w2 = *(float2*)&Ws[k][tx * 2];
    a00 += a2.x * w2.x; a01 += a2.x * w2.y;
    a10 += a2.y * w2.x; a11 += a2.y * w2.y;
  }
  int row = r0 + ty * 2;
  float2 o0 = {a00, a01}, o1 = {a10, a11};
  *(float2*)&qkvg[row * 512 + ncol0 + tx * 2] = o0;
  *(float2*)&qkvg[(row + 1) * 512 + ncol0 + tx * 2] = o1;
}

// ---------------------------------------------------------------------------
// k_attn: grid 96, block 256
__global__ __launch_bounds__(256) void k_attn(
    const float* __restrict__ qkvg, const float* __restrict__ biasb,
    float* __restrict__ og) {
  int qb = blockIdx.x >> 2, h = blockIdx.x & 3, t = threadIdx.x;
  int i0 = qb * 32, lo = i0 - 48;
  __shared__ float qs[32][36];
  __shared__ float ks[128][36];
  __shared__ float vs[128][36];
  __shared__ float L[32][132];
#pragma unroll
  for (int m = 0; m < 4; m++) {
    int idx = t + 256 * m;
    int qi = idx >> 5, k4 = (idx & 31) * 4;
    int j = lo + k4;
    float4 bv;
    if (j >= 0 && j < 768) bv = *(const float4*)&biasb[(qb * 4 + h) * 4096 + qi * 128 + k4];
    else bv = make_float4(-1e30f, -1e30f, -1e30f, -1e30f);
    *(float4*)&L[qi][k4] = bv;
  }
  {
    int qi = t >> 3, dq = (t & 7) * 4;
    *(float4*)&qs[qi][dq] = *(const float4*)&qkvg[(i0 + qi) * 512 + h * 32 + dq];
  }
  {
    int kj = t >> 1, dh = (t & 1) * 16;
    int j = lo + kj;
    if (j >= 0 && j < 768) {
      const float4* sk = (const float4*)&qkvg[j * 512 + 128 + h * 32 + dh];
      const float4* sv = (const float4*)&qkvg[j * 512 + 256 + h * 32 + dh];
#pragma unroll
      for (int m = 0; m < 4; m++) {
        *(float4*)&ks[kj][dh + 4 * m] = sk[m];
        *(float4*)&vs[kj][dh + 4 * m] = sv[m];
      }
    } else {
      float4 zz = {0, 0, 0, 0};
#pragma unroll
      for (int m = 0; m < 4; m++) {
        *(float4*)&ks[kj][dh + 4 * m] = zz;
        *(float4*)&vs[kj][dh + 4 * m] = zz;
      }
    }
  }
  __syncthreads();
  const float scale = 0.17677669529663687f;
  {
    int qi = t & 31, kb = t >> 5;
    float4 qr[8];
#pragma unroll
    for (int m = 0; m < 8; m++) qr[m] = *(float4*)&qs[qi][m * 4];
#pragma unroll 2
    for (int kk = 0; kk < 16; kk++) {
      int kj = kb * 16 + kk;
      float acc = 0.f;
#pragma unroll
      for (int m = 0; m < 8; m++) {
        float4 kv = *(float4*)&ks[kj][m * 4];
        acc += qr[m].x * kv.x + qr[m].y * kv.y + qr[m].z * kv.z + qr[m].w * kv.w;
      }
      L[qi][kj] += acc * scale;
    }
  }
  __syncthreads();
  int qi = t >> 3, sg = t & 7;
  float mx = -1e30f;
#pragma unroll
  for (int k2 = 0; k2 < 16; k2++) mx = fmaxf(mx, L[qi][sg * 16 + k2]);
#pragma unroll
  for (int o = 1; o < 8; o <<= 1) mx = fmaxf(mx, __shfl_xor(mx, o));
  float sum = 0.f;
#pragma unroll
  for (int k2 = 0; k2 < 16; k2++) {
    int kj = sg * 16 + k2;
    float e = __expf(L[qi][kj] - mx);
    L[qi][kj] = e;
    sum += e;
  }
#pragma unroll
  for (int o = 1; o < 8; o <<= 1) sum += __shfl_xor(sum, o);
  float rden = 1.f / sum;
  __syncthreads();
  int d0 = (t & 7) * 4;
  float4 acc = {0, 0, 0, 0};
#pragma unroll 4
  for (int kj = 0; kj < 128; kj++) {
    float p = L[qi][kj];
    float4 v = *(const float4*)&vs[kj][d0];
    acc.x += p * v.x; acc.y += p * v.y; acc.z += p * v.z; acc.w += p * v.w;
  }
  int i = i0 + qi;
  float4 gr = *(const float4*)&qkvg[i * 512 + 384 + h * 32 + d0];
  float4 o4;
  o4.x = acc.x * rden * sigmoidf_(gr.x);
  o4.y = acc.y * rden * sigmoidf_(gr.y);
  o4.z = acc.z * rden * sigmoidf_(gr.z);
  o4.w = acc.w * rden * sigmoidf_(gr.w);
  *(float4*)&og[i * 128 + h * 32 + d0] = o4;
}

// ---------------------------------------------------------------------------
// k_fusedT<MODE>: x += og@Wo; a=LN(x); x += relu(a@Wt1)@Wt2; then
//  MODE 1: qkvg_next = LN_next(x) @ [Wq|Wk|Wv|Wg]
//  MODE 2: qout = relu(x@W_proj), a_out = mean (k_final fused)
// grid 256 (3 rows/block, 1/CU), block 384.
template <int MODE>
__global__ __launch_bounds__(384) void k_fusedT(
    const float* __restrict__ og, const float* __restrict__ Wo,
    const float* __restrict__ g2, const float* __restrict__ b2,
    const float* __restrict__ Wt1, const float* __restrict__ Wt2,
    float* __restrict__ x,
    const float* __restrict__ lng_n, const float* __restrict__ lnb_n,
    const float* __restrict__ Wq, const float* __restrict__ Wk,
    const float* __restrict__ Wv, const float* __restrict__ Wg,
    float* __restrict__ qkvg, const float* __restrict__ W_proj,
    float* __restrict__ out) {
  int t = threadIdx.x;
  int r0 = blockIdx.x * 3;
  __shared__ float osr[3][128];
  __shared__ float xns[3][128];
  __shared__ float asr[3][128];
  __shared__ float hs[3][512];
  __shared__ float part[4][3][128];
  __shared__ float red[12];
  {
    int rr = t >> 7, c = t & 127;
    osr[rr][c] = og[(r0 + rr) * 128 + c];
    xns[rr][c] = x[(r0 + rr) * 128 + c];
  }
  __syncthreads();
  // ---- GEMM1 (k-split 4) ----
  {
    int c4 = (t & 31) * 4, row = (t >> 5) % 3, q = t / 96;
    int k0 = q * 32;
    float a0 = 0.f, a1 = 0.f, a2 = 0.f, a3 = 0.f;
#pragma unroll 8
    for (int kk = 0; kk < 32; kk++) {
      int k = k0 + kk;
      float4 w = *(const float4*)&Wo[k * 128 + c4];
      float av = osr[row][k];
      a0 += av * w.x; a1 += av * w.y; a2 += av * w.z; a3 += av * w.w;
    }
    *(float4*)&part[q][row][c4] = make_float4(a0, a1, a2, a3);
  }
  __syncthreads();
  // ---- combine + LN ----
  {
    int rr = t >> 7, c = t & 127;
    float xv = xns[rr][c] + part[0][rr][c] + part[1][rr][c] + part[2][rr][c] + part[3][rr][c];
    float ps = xv, pq = xv * xv;
#pragma unroll
    for (int o = 1; o < 64; o <<= 1) { ps += __shfl_xor(ps, o); pq += __shfl_xor(pq, o); }
    int wv = t >> 6;
    if ((t & 63) == 0) { red[wv] = ps; red[6 + wv] = pq; }
    __syncthreads();
    float mean = (red[2 * rr] + red[2 * rr + 1]) * (1.f / 128.f);
    float var = (red[6 + 2 * rr] + red[6 + 2 * rr + 1]) * (1.f / 128.f) - mean * mean;
    float rstd = rsqrtf(var + 1e-5f);
    xns[rr][c] = xv;
    asr[rr][c] = (xv - mean) * rstd * g2[c] + b2[c];
  }
  __syncthreads();
  // ---- GEMM2: hs = relu(asr @ Wt1) ----
  {
    int c4 = (t & 127) * 4, row = t >> 7;
    float a0 = 0.f, a1 = 0.f, a2 = 0.f, a3 = 0.f;
#pragma unroll 8
    for (int k = 0; k < 128; k++) {
      float4 w = *(const float4*)&Wt1[k * 512 + c4];
      float av = asr[row][k];
      a0 += av * w.x; a1 += av * w.y; a2 += av * w.z; a3 += av * w.w;
    }
    *(float4*)&hs[row][c4] = make_float4(fmaxf(a0, 0.f), fmaxf(a1, 0.f),
                                         fmaxf(a2, 0.f), fmaxf(a3, 0.f));
  }
  __syncthreads();
  // ---- GEMM3 (k-split 4) ----
  {
    int c4 = (t & 31) * 4, row = (t >> 5) % 3, q = t / 96;
    int k0 = q * 128;
    float a0 = 0.f, a1 = 0.f, a2 = 0.f, a3 = 0.f;
#pragma unroll 8
    for (int kk = 0; kk < 128; kk++) {
      int k = k0 + kk;
      float4 w = *(const float4*)&Wt2[k * 128 + c4];
      float hv = hs[row][k];
      a0 += hv * w.x; a1 += hv * w.y; a2 += hv * w.z; a3 += hv * w.w;
    }
    *(float4*)&part[q][row][c4] = make_float4(a0, a1, a2, a3);
  }
  __syncthreads();
  // ---- final x + optional fused tails ----
  {
    int rr = t >> 7, c = t & 127;
    float xf = xns[rr][c] + part[0][rr][c] + part[1][rr][c] +
               part[2][rr][c] + part[3][rr][c];
    x[(r0 + rr) * 128 + c] = xf;
    xns[rr][c] = xf;
  }
  if (MODE == 1) {
    // LN with next layer's params
    __syncthreads();
    {
      int rr = t >> 7, c = t & 127;
      float xv = xns[rr][c];
      float ps = xv, pq = xv * xv;
#pragma unroll
      for (int o = 1; o < 64; o <<= 1) { ps += __shfl_xor(ps, o); pq += __shfl_xor(pq, o); }
      int wv = t >> 6;
      if ((t & 63) == 0) { red[wv] = ps; red[6 + wv] = pq; }
      __syncthreads();
      float mean = (red[2 * rr] + red[2 * rr + 1]) * (1.f / 128.f);
      float var = (red[6 + 2 * rr] + red[6 + 2 * rr + 1]) * (1.f / 128.f) - mean * mean;
      float rstd = rsqrtf(var + 1e-5f);
      asr[rr][c] = (xv - mean) * rstd * lng_n[c] + lnb_n[c];
    }
    __syncthreads();
    // qkvg_next[row][512]: col block chooses matrix
    {
      int c4 = (t & 127) * 4, row = t >> 7;
      int mtx = c4 >> 7, lc = c4 & 127;
      const float* Wm = (mtx == 0) ? Wq : (mtx == 1) ? Wk : (mtx == 2) ? Wv : Wg;
      float a0 = 0.f, a1 = 0.f, a2 = 0.f, a3 = 0.f;
#pragma unroll 8
      for (int k = 0; k < 128; k++) {
        float4 w = *(const float4*)&Wm[k * 128 + lc];
        float av = asr[row][k];
        a0 += av * w.x; a1 += av * w.y; a2 += av * w.z; a3 += av * w.w;
      }
      *(float4*)&qkvg[(r0 + row) * 512 + c4] = make_float4(a0, a1, a2, a3);
    }
  }
  if (MODE == 2) {
    __syncthreads();
    // qout = relu(x@W_proj); a_out = mean over 3 atoms. tk = blockIdx.x.
    int tk = blockIdx.x;
    float a0 = 0.f, a1 = 0.f, a2 = 0.f;
#pragma unroll 8
    for (int k = 0; k < 128; k++) {
      float w = W_proj[k * 384 + t];
      a0 += xns[0][k] * w; a1 += xns[1][k] * w; a2 += xns[2][k] * w;
    }
    a0 = fmaxf(a0, 0.f); a1 = fmaxf(a1, 0.f); a2 = fmaxf(a2, 0.f);
    out[98304 + (tk * 3 + 0) * 384 + t] = a0;
    out[98304 + (tk * 3 + 1) * 384 + t] = a1;
    out[98304 + (tk * 3 + 2) * 384 + t] = a2;
    out[tk * 384 + t] = (a0 + a1 + a2) * (1.f / 3.f);
  }
}

// ---------------------------------------------------------------------------
extern "C" void kernel_launch(void* const* d_in, const int* in_sizes, int n_in,
                              void* d_out, int out_size, void* d_ws, size_t ws_size,
                              hipStream_t stream) {
  const float* ref_pos  = (const float*)d_in[0];
  const int*   uid      = (const int*)d_in[1];
  const float* r        = (const float*)d_in[2];
  const float* s        = (const float*)d_in[3];
  const float* z        = (const float*)d_in[4];
  const float* W_pos    = (const float*)d_in[5];
  const float* Wpo      = (const float*)d_in[6];
  const float* Wisd     = (const float*)d_in[7];
  const float* Wmask    = (const float*)d_in[8];
  const float* Wca      = (const float*)d_in[9];
  const float* Wcb      = (const float*)d_in[10];
  const float* ln_s_g   = (const float*)d_in[11];
  const float* ln_s_b   = (const float*)d_in[12];
  const float* W_single = (const float*)d_in[13];
  const float* ln_z_g   = (const float*)d_in[14];
  const float* ln_z_b   = (const float*)d_in[15];
  const float* W_pair   = (const float*)d_in[16];
  const float* W_noisy  = (const float*)d_in[17];
  const float* W_mlp1   = (const float*)d_in[18];
  const float* W_mlp2   = (const float*)d_in[19];
  const float* W_mlp3   = (const float*)d_in[20];
  const float* at_ln_g  = (const float*)d_in[21];
  const float* at_ln_b  = (const float*)d_in[22];
  const float* at_Wq    = (const float*)d_in[23];
  const float* at_Wk    = (const float*)d_in[24];
  const float* at_Wv    = (const float*)d_in[25];
  const float* at_Wg    = (const float*)d_in[26];
  const float* at_lnp_g = (const float*)d_in[27];
  const float* at_lnp_b = (const float*)d_in[28];
  const float* at_Wb    = (const float*)d_in[29];
  const float* at_Wo    = (const float*)d_in[30];
  const float* at_ln2_g = (const float*)d_in[31];
  const float* at_ln2_b = (const float*)d_in[32];
  const float* at_Wt1   = (const float*)d_in[33];
  const float* at_Wt2   = (const float*)d_in[34];
  const float* W_proj   = (const float*)d_in[35];
  float* out = (float*)d_out;
  float* W = (float*)d_ws;
  float* x     = W;                 //   98304
  float* ca    = W + 98304;         //   12288
  float* cb    = W + 110592;        //   12288
  float* zp    = W + 122880;        // 1048576
  float* biasA = W + 1171456;       // 1179648
  float* qkvg  = W + 2351104;       //  393216
  float* og    = W + 2744320;       //   98304

  k_zp<<<4096, 256, 0, stream>>>(z, ln_z_g, ln_z_b, W_pair, zp);
  k_tokatoms<<<256, 128, 0, stream>>>(s, ln_s_g, ln_s_b, W_single, ref_pos, r,
                                      W_pos, W_noisy, Wca, Wcb,
                                      out + 393216, x, ca, cb);
  k_pairM<<<2304, 256, 0, stream>>>(ref_pos, uid, Wpo, Wisd, Wmask, W_mlp1, W_mlp2,
                                    W_mlp3, zp, ca, cb, at_lnp_g, at_lnp_b, at_Wb,
                                    out + 491520, biasA);
  k_qkvg<<<384, 256, 0, stream>>>(x, at_ln_g, at_ln_b, at_Wq, at_Wk, at_Wv, at_Wg, qkvg);
  // layer 0
  k_attn<<<96, 256, 0, stream>>>(qkvg, biasA, og);
  k_fusedT<1><<<256, 384, 0, stream>>>(og, at_Wo, at_ln2_g, at_ln2_b, at_Wt1, at_Wt2, x,
                                       at_ln_g + 128, at_ln_b + 128,
                                       at_Wq + 16384, at_Wk + 16384,
                                       at_Wv + 16384, at_Wg + 16384, qkvg,
                                       nullptr, nullptr);
  // layer 1
  k_attn<<<96, 256, 0, stream>>>(qkvg, biasA + 393216, og);
  k_fusedT<1><<<256, 384, 0, stream>>>(og, at_Wo + 16384, at_ln2_g + 128, at_ln2_b + 128,
                                       at_Wt1 + 65536, at_Wt2 + 65536, x,
                                       at_ln_g + 256, at_ln_b + 256,
                                       at_Wq + 32768, at_Wk + 32768,
                                       at_Wv + 32768, at_Wg + 32768, qkvg,
                                       nullptr, nullptr);
  // layer 2
  k_attn<<<96, 256, 0, stream>>>(qkvg, biasA + 786432, og);
  k_fusedT<2><<<256, 384, 0, stream>>>(og, at_Wo + 32768, at_ln2_g + 256, at_ln2_b + 256,
                                       at_Wt1 + 131072, at_Wt2 + 131072, x,
                                       nullptr, nullptr, nullptr, nullptr,
                                       nullptr, nullptr, nullptr, W_proj, out);
}